// Round 10
// baseline (481.647 us; speedup 1.0000x reference)
//
#include <hip/hip_runtime.h>

#define DD 128   // input feature dim D
#define HH 256   // hidden dim H
#define OO 128   // output dim O

// CSR bucket config
#define NBI 256
#define NBU 512

typedef unsigned short bf16_t;
typedef short bf16x8 __attribute__((ext_vector_type(8)));   // 8 bf16 = 4 VGPRs
typedef float f32x4 __attribute__((ext_vector_type(4)));

__device__ __forceinline__ float bf2f(bf16_t u) {
  union { unsigned int i; float f; } v; v.i = ((unsigned int)u) << 16; return v.f;
}
__device__ __forceinline__ bf16_t f2bf(float f) {
  union { float f; unsigned int i; } v; v.f = f;
  unsigned int r = v.i + 0x7FFFu + ((v.i >> 16) & 1u);  // RNE
  return (bf16_t)(r >> 16);
}

__device__ __forceinline__ void acc8(float* acc, uint4 u) {
  const unsigned* p = (const unsigned*)&u;
#pragma unroll
  for (int i = 0; i < 4; ++i) {
    union { unsigned v; float f; } lo, hi;
    lo.v = p[i] << 16;
    hi.v = p[i] & 0xffff0000u;
    acc[2 * i] += lo.f;
    acc[2 * i + 1] += hi.f;
  }
}
__device__ __forceinline__ void unpack8(float* o, uint4 u) {
  const unsigned* p = (const unsigned*)&u;
#pragma unroll
  for (int i = 0; i < 4; ++i) {
    union { unsigned v; float f; } lo, hi;
    lo.v = p[i] << 16;
    hi.v = p[i] & 0xffff0000u;
    o[2 * i] = lo.f;
    o[2 * i + 1] = hi.f;
  }
}
__device__ __forceinline__ uint4 pack8(const float* v) {
  uint4 o; unsigned* p = (unsigned*)&o;
#pragma unroll
  for (int i = 0; i < 4; ++i)
    p[i] = (unsigned)f2bf(v[2 * i]) | ((unsigned)f2bf(v[2 * i + 1]) << 16);
  return o;
}

// ---------------------------------------------------------------------------
__global__ void probe_k(float* __restrict__ out, int n, float v) {
  int i = blockIdx.x * blockDim.x + threadIdx.x;
  if (i < n) out[i] = v;
}

// ---------------- CSR build (bucketed, no per-node global atomics) ----------
__global__ __launch_bounds__(256) void hist_k(
    const int* __restrict__ src, const int* __restrict__ dst,
    int* __restrict__ hist_u, int* __restrict__ hist_i,
    int E, int Wi, int Wu) {
  __shared__ int hi[NBI], hu[NBU];
  int tid = threadIdx.x;
  for (int t = tid; t < NBI; t += 256) hi[t] = 0;
  for (int t = tid; t < NBU; t += 256) hu[t] = 0;
  __syncthreads();
  int base = blockIdx.x * 4096;
#pragma unroll
  for (int j = 0; j < 16; ++j) {
    int e = base + tid + j * 256;
    if (e < E) {
      atomicAdd(&hi[dst[e] / Wi], 1);
      atomicAdd(&hu[src[e] / Wu], 1);
    }
  }
  __syncthreads();
  for (int t = tid; t < NBI; t += 256) if (hi[t]) atomicAdd(hist_i + t, hi[t]);
  for (int t = tid; t < NBU; t += 256) if (hu[t]) atomicAdd(hist_u + t, hu[t]);
}

__global__ __launch_bounds__(512) void scan_small_pair_k(
    const int* __restrict__ hist_i, int* __restrict__ off_i, int* __restrict__ cur_i,
    const int* __restrict__ hist_u, int* __restrict__ off_u, int* __restrict__ cur_u) {
  __shared__ int lds[512];
  const int* hist = blockIdx.x ? hist_u : hist_i;
  int* off = blockIdx.x ? off_u : off_i;
  int* cur = blockIdx.x ? cur_u : cur_i;
  int n = blockIdx.x ? NBU : NBI;
  int t = threadIdx.x;
  int v = (t < n) ? hist[t] : 0;
  lds[t] = v; __syncthreads();
  for (int o = 1; o < 512; o <<= 1) {
    int tv = (t >= o) ? lds[t - o] : 0;
    __syncthreads(); lds[t] += tv; __syncthreads();
  }
  if (t < n) { int e = lds[t] - v; off[t] = e; cur[t] = e; }
}

__global__ __launch_bounds__(256) void bucket_append_k(
    const int* __restrict__ src, const int* __restrict__ dst, int E, int Wi, int Wu,
    int* __restrict__ cur_bi, int* __restrict__ cur_bu,
    unsigned int* __restrict__ ebuf_i, unsigned int* __restrict__ ebuf_u) {
  __shared__ int bi[NBI], bu[NBU];
  __shared__ uint2 es[4096];
  int tid = threadIdx.x;
  int base = blockIdx.x * 4096;
  int n = E - base; if (n > 4096) n = 4096;
  for (int t = tid; t < NBI; t += 256) bi[t] = 0;
  for (int t = tid; t < NBU; t += 256) bu[t] = 0;
  __syncthreads();
#pragma unroll
  for (int j = 0; j < 16; ++j) {
    int idx = tid + j * 256;
    if (idx < n) {
      int s = src[base + idx], d = dst[base + idx];
      es[idx] = make_uint2((unsigned)s, (unsigned)d);
      atomicAdd(&bi[d / Wi], 1);
      atomicAdd(&bu[s / Wu], 1);
    }
  }
  __syncthreads();
  for (int t = tid; t < NBI; t += 256) { int c = bi[t]; bi[t] = c ? atomicAdd(cur_bi + t, c) : 0; }
  for (int t = tid; t < NBU; t += 256) { int c = bu[t]; bu[t] = c ? atomicAdd(cur_bu + t, c) : 0; }
  __syncthreads();
#pragma unroll
  for (int j = 0; j < 16; ++j) {
    int idx = tid + j * 256;
    if (idx < n) {
      int s = (int)es[idx].x, d = (int)es[idx].y;
      int bI = d / Wi, bU = s / Wu;
      int pI = atomicAdd(&bi[bI], 1);
      int pU = atomicAdd(&bu[bU], 1);
      ebuf_i[pI] = ((unsigned)(d - bI * Wi) << 24) | (unsigned)s;
      ebuf_u[pU] = ((unsigned)(s - bU * Wu) << 24) | (unsigned)d;
    }
  }
}

__global__ __launch_bounds__(256) void bucket_fill2_k(
    const unsigned int* __restrict__ ebuf, const int* __restrict__ off,
    const int* __restrict__ endc, int* __restrict__ row,
    int* __restrict__ csr, int n, int W, int E) {
  int b = blockIdx.x;
  int d0 = b * W; if (d0 >= n) return;
  int cnt = n - d0; if (cnt > W) cnt = W;
  __shared__ int hist[320];
  __shared__ int cur[320];
  int tid = threadIdx.x;
  for (int t = tid; t < cnt; t += 256) hist[t] = 0;
  __syncthreads();
  int beg = off[b], e_end = endc[b];
  for (int e = beg + tid; e < e_end; e += 256)
    atomicAdd(&hist[ebuf[e] >> 24], 1);
  __syncthreads();
  if (tid < 64) {
    int lane = tid;
    int carry = beg;
    int nc = (cnt + 63) >> 6;
    for (int c = 0; c < nc; ++c) {
      int idx = (c << 6) + lane;
      int v = (idx < cnt) ? hist[idx] : 0;
      int x = v;
#pragma unroll
      for (int o = 1; o < 64; o <<= 1) { int t = __shfl_up(x, o); if (lane >= o) x += t; }
      if (idx < cnt) { int g = carry + x - v; row[d0 + idx] = g; cur[idx] = g; }
      carry += __shfl(x, 63);
    }
  }
  if (tid == 0 && d0 + cnt == n) row[n] = E;
  __syncthreads();
  for (int e = beg + tid; e < e_end; e += 256) {
    unsigned v = ebuf[e];
    int slot = atomicAdd(&cur[v >> 24], 1);
    csr[slot] = (int)(v & 0xFFFFFFu);
  }
}

// ---------------- dtype prep ----------------
__global__ void cvt_bf16_k(const float* __restrict__ in, bf16_t* __restrict__ out, int n4) {
  int i = blockIdx.x * blockDim.x + threadIdx.x;
  if (i < n4) {
    float4 v = ((const float4*)in)[i];
    ushort4 o; o.x = f2bf(v.x); o.y = f2bf(v.y); o.z = f2bf(v.z); o.w = f2bf(v.w);
    ((ushort4*)out)[i] = o;
  }
}

struct WBatch { const float* in[4]; bf16_t* out[4]; };
__global__ void twconv_batch_k(WBatch wb, int K, int N) {
  const float* __restrict__ in = wb.in[blockIdx.z];
  bf16_t* __restrict__ out = wb.out[blockIdx.z];
  __shared__ float t[32][33];
  int bx = blockIdx.x * 32, by = blockIdx.y * 32;
  int tx = threadIdx.x & 31, ty = threadIdx.x >> 5;  // 32x8
#pragma unroll
  for (int j = 0; j < 32; j += 8)
    t[ty + j][tx] = in[(size_t)(by + ty + j) * N + bx + tx];
  __syncthreads();
#pragma unroll
  for (int j = 0; j < 32; j += 8)
    out[(size_t)(bx + ty + j) * K + by + tx] = f2bf(t[tx][ty + j]);
}

// ---------------- gather-mean, D=128, 16 lanes/row, paired jobs ------------
struct GatherJob {
  const int* row; const int* csr;
  const bf16_t* X; bf16_t* agg; int n;
};

template<bool ADD>
__global__ void gather_mean16_k(GatherJob j0, GatherJob j1) {
  GatherJob j = blockIdx.y ? j1 : j0;
  int node = (int)(((long long)blockIdx.x * blockDim.x + threadIdx.x) >> 6);
  int lane = threadIdx.x & 63;
  if (node >= j.n) return;
  const int g = lane >> 4;
  const int l = lane & 15;
  int beg = j.row[node], end = j.row[node + 1];
  float acc[8] = {};
  for (int jj = beg; jj < end; jj += 64) {
    int cnt = min(64, end - jj);
    int my = (lane < cnt) ? j.csr[jj + lane] : 0;
    for (int k = 0; k < cnt; k += 4) {
      int idx = __shfl(my, k + g);
      if (k + g < cnt) {
        uint4 u = *(const uint4*)(j.X + (size_t)idx * 128 + l * 8);
        acc8(acc, u);
      }
    }
  }
#pragma unroll
  for (int m = 16; m < 64; m <<= 1)
#pragma unroll
    for (int i = 0; i < 8; ++i) acc[i] += __shfl_xor(acc[i], m);
  if (g == 0) {
    float inv = (end > beg) ? 1.0f / (float)(end - beg) : 0.0f;
    float v[8];
    if (ADD) {
      uint4 z = *(const uint4*)(j.agg + (size_t)node * 128 + l * 8);
      float zb[8]; unpack8(zb, z);
#pragma unroll
      for (int i = 0; i < 8; ++i) v[i] = acc[i] * inv + zb[i];
    } else {
#pragma unroll
      for (int i = 0; i < 8; ++i) v[i] = acc[i] * inv;
    }
    *(uint4*)(j.agg + (size_t)node * 128 + l * 8) = pack8(v);
  }
}

// ---------------- MFMA GEMM: LDS-free direct-fragment ----------------
// C = act( A1 @ W1 [+ A2 @ W2] [+ bias] ), A* bf16 [M,K] row-major,
// W*t bf16 [N,K] row-major. 128x128 tile, 4 waves (2x2 of 64x64).
// Each lane loads its MFMA fragments (16B contiguous) straight global->VGPR.
// No LDS, no barriers: latency hidden by ILP (K unrolled) + TLP.
struct GJob {
  int M;
  const bf16_t* A1; const bf16_t* A2;
  const bf16_t* W1t; const bf16_t* W2t;
  const float* bias;
  bf16_t* C; bf16_t* C2;
};

template<bool RELU, bool DUAL, bool BIAS, bool SPLIT, int KT>
__global__ __launch_bounds__(256) void mfma_gemm_k(GJob j0, GJob j1, int N) {
  GJob j = blockIdx.z ? j1 : j0;
  const size_t row0 = (size_t)blockIdx.y * 128;
  if (row0 >= (size_t)j.M) return;
  const int col0 = blockIdx.x * 128;
  const int tid = threadIdx.x;
  const int wave = tid >> 6, lane = tid & 63;
  const int wr = wave >> 1, wc = wave & 1;
  const int M = j.M;
  const int lrow = lane & 15;
  const int lk = (lane >> 4) * 8;   // element offset of this lane's 16B k-chunk

  // clamped A row per mi (tail rows read row M-1; results discarded at store)
  size_t arow[4];
#pragma unroll
  for (int mi = 0; mi < 4; ++mi) {
    size_t r = row0 + (size_t)(wr * 64 + mi * 16 + lrow);
    arow[mi] = (r < (size_t)M) ? r : (size_t)(M - 1);
  }
  size_t bcol[4];
#pragma unroll
  for (int ni = 0; ni < 4; ++ni)
    bcol[ni] = (size_t)(col0 + wc * 64 + ni * 16 + lrow);

  f32x4 acc[4][4] = {};

  for (int s = 0; s < (DUAL ? 2 : 1); ++s) {
    const bf16_t* __restrict__ Ap = (DUAL && s) ? j.A2 : j.A1;
    const bf16_t* __restrict__ Wp = (DUAL && s) ? j.W2t : j.W1t;
#pragma unroll
    for (int k0 = 0; k0 < KT; k0 += 32) {
      bf16x8 af[4], bfr[4];
#pragma unroll
      for (int mi = 0; mi < 4; ++mi)
        af[mi] = *(const bf16x8*)(Ap + arow[mi] * KT + k0 + lk);
#pragma unroll
      for (int ni = 0; ni < 4; ++ni)
        bfr[ni] = *(const bf16x8*)(Wp + bcol[ni] * KT + k0 + lk);
#pragma unroll
      for (int mi = 0; mi < 4; ++mi)
#pragma unroll
        for (int ni = 0; ni < 4; ++ni)
          acc[mi][ni] = __builtin_amdgcn_mfma_f32_16x16x32_bf16(af[mi], bfr[ni], acc[mi][ni], 0, 0, 0);
    }
  }

  const int crow = wr * 64 + (lane >> 4) * 4;
  int ccol = col0 + wc * 64 + lrow;
  bf16_t* Co = j.C;
  int stride = N;
  bool useBias = BIAS;
  if (SPLIT) {
    const int half = N >> 1;
    stride = half;
    if (col0 >= half) { Co = j.C2; ccol -= half; useBias = false; }
  }
#pragma unroll
  for (int mi = 0; mi < 4; ++mi) {
#pragma unroll
    for (int jj = 0; jj < 4; ++jj) {
      size_t r = row0 + crow + mi * 16 + jj;
      if (r < (size_t)M) {
#pragma unroll
        for (int ni = 0; ni < 4; ++ni) {
          float v = acc[mi][ni][jj];
          if (BIAS) { if (useBias) v += j.bias[ccol + ni * 16]; }
          if (RELU) v = fmaxf(v, 0.f);
          Co[r * stride + ccol + ni * 16] = f2bf(v);
        }
      }
    }
  }
}

// ---------------- decode: 16 lanes/label, 16B loads ----------------
__global__ void decode16_k(const int* __restrict__ ls, const int* __restrict__ ld,
                           const bf16_t* __restrict__ zu, const bf16_t* __restrict__ zi,
                           float* __restrict__ out, int L) {
  long long gid = (long long)blockIdx.x * blockDim.x + threadIdx.x;
  int w = (int)(gid >> 4);
  int l = (int)(gid & 15);
  if (w >= L) return;
  int su = ls[w], si = ld[w];
  uint4 a = *(const uint4*)(zu + (size_t)su * OO + l * 8);
  uint4 b = *(const uint4*)(zi + (size_t)si * OO + l * 8);
  const unsigned* pa = (const unsigned*)&a;
  const unsigned* pb = (const unsigned*)&b;
  float sum = 0.f;
#pragma unroll
  for (int i = 0; i < 4; ++i) {
    union { unsigned v; float f; } la, ha, lb, hb;
    la.v = pa[i] << 16;        ha.v = pa[i] & 0xffff0000u;
    lb.v = pb[i] << 16;        hb.v = pb[i] & 0xffff0000u;
    sum += la.f * lb.f + ha.f * hb.f;
  }
#pragma unroll
  for (int m = 1; m < 16; m <<= 1) sum += __shfl_xor(sum, m);
  if (l == 0) out[w] = sum;
}

// ---------------------------------------------------------------------------
extern "C" void kernel_launch(void* const* d_in, const int* in_sizes, int n_in,
                              void* d_out, int out_size, void* d_ws, size_t ws_size,
                              hipStream_t stream) {
  const float* x_user = (const float*)d_in[0];
  const float* x_item = (const float*)d_in[1];
  const int* edge_src = (const int*)d_in[2];
  const int* edge_dst = (const int*)d_in[3];
  const int* lbl_src  = (const int*)d_in[4];
  const int* lbl_dst  = (const int*)d_in[5];
  const float* wl1_ui = (const float*)d_in[6];
  const float* wr1_ui = (const float*)d_in[7];
  const float* b1_ui  = (const float*)d_in[8];
  const float* wl1_iu = (const float*)d_in[9];
  const float* wr1_iu = (const float*)d_in[10];
  const float* b1_iu  = (const float*)d_in[11];
  const float* wl2_ui = (const float*)d_in[12];
  const float* wr2_ui = (const float*)d_in[13];
  const float* b2_ui  = (const float*)d_in[14];
  const float* wl2_iu = (const float*)d_in[15];
  const float* wr2_iu = (const float*)d_in[16];
  const float* b2_iu  = (const float*)d_in[17];

  const int NU = in_sizes[0] / DD;
  const int NI = in_sizes[1] / DD;
  const int E  = in_sizes[2];
  const int L  = in_sizes[4];
  const int Wi = (NI + NBI - 1) / NBI;
  const int Wu = (NU + NBU - 1) / NBU;
  const int nEB = (E + 4095) / 4096;

  // ---- workspace layout ----
  size_t off = 0;
  auto take = [&](size_t bytes) { size_t o = off; off = (off + bytes + 255) & ~(size_t)255; return o; };
  char* base = (char*)d_ws;
  int* hist_i = (int*)(base + take(((size_t)NBI + NBU) * 4));  // zeroed together
  int* hist_u = hist_i + NBI;
  size_t zeroB = ((size_t)NBI + NBU) * 4;
  int* row_i = (int*)(base + take((size_t)(NI + 1) * 4));
  int* row_u = (int*)(base + take((size_t)(NU + 1) * 4));
  int* off_i = (int*)(base + take((size_t)NBI * 4));
  int* off_u = (int*)(base + take((size_t)NBU * 4));
  int* cur_bi = (int*)(base + take((size_t)NBI * 4));
  int* cur_bu = (int*)(base + take((size_t)NBU * 4));
  int* csr_i = (int*)(base + take((size_t)E * 4));
  int* csr_u = (int*)(base + take((size_t)E * 4));
  unsigned int* ebuf_i = (unsigned int*)(base + take((size_t)E * 4));
  unsigned int* ebuf_u = (unsigned int*)(base + take((size_t)E * 4));
  bf16_t* pool = (bf16_t*)(base + take((size_t)(NI + NU) * HH * 2));
  bf16_t* agg_i   = pool;                              // NI*DD
  bf16_t* agg_u   = agg_i + (size_t)NI * DD;           // NU*DD
  bf16_t* xb_item = agg_u + (size_t)NU * DD;           // NI*DD
  bf16_t* xb_user = xb_item + (size_t)NI * DD;         // NU*DD
  bf16_t* t_user  = pool;                              // NU*OO
  bf16_t* t_item  = t_user + (size_t)NU * OO;          // NI*OO
  bf16_t* h_item = (bf16_t*)(base + take((size_t)(NI + NU) * HH * 2));
  bf16_t* h_user = h_item + (size_t)NI * HH;
  bf16_t* z_item = (bf16_t*)(base + take((size_t)(NI + NU) * OO * 2));
  bf16_t* z_user = z_item + (size_t)NI * OO;
  bf16_t* Wt1[4];
  for (int w = 0; w < 4; ++w) Wt1[w] = (bf16_t*)(base + take((size_t)HH * DD * 2));
  bf16_t* Wcat_item = (bf16_t*)(base + take((size_t)2 * OO * HH * 2));
  bf16_t* Wcat_user = (bf16_t*)(base + take((size_t)2 * OO * HH * 2));
  size_t need = off;

  float* out = (float*)d_out;
  if (ws_size < need || Wi > 320 || Wu > 320) {
    probe_k<<<(L + 255) / 256, 256, 0, stream>>>(out, L, (float)(ws_size >> 20));
    return;
  }

  // ---- CSR build ----
  hipMemsetAsync(hist_i, 0, zeroB, stream);
  hist_k<<<nEB, 256, 0, stream>>>(edge_src, edge_dst, hist_u, hist_i, E, Wi, Wu);
  scan_small_pair_k<<<2, 512, 0, stream>>>(hist_i, off_i, cur_bi, hist_u, off_u, cur_bu);
  bucket_append_k<<<nEB, 256, 0, stream>>>(edge_src, edge_dst, E, Wi, Wu, cur_bi, cur_bu, ebuf_i, ebuf_u);
  bucket_fill2_k<<<NBI, 256, 0, stream>>>(ebuf_i, off_i, cur_bi, row_i, csr_i, NI, Wi, E);
  bucket_fill2_k<<<NBU, 256, 0, stream>>>(ebuf_u, off_u, cur_bu, row_u, csr_u, NU, Wu, E);

  // ---- dtype prep ----
  cvt_bf16_k<<<(NI * DD / 4 + 255) / 256, 256, 0, stream>>>(x_item, xb_item, NI * DD / 4);
  cvt_bf16_k<<<(NU * DD / 4 + 255) / 256, 256, 0, stream>>>(x_user, xb_user, NU * DD / 4);
  {
    WBatch w1;
    w1.in[0] = wl1_ui; w1.out[0] = Wt1[0];
    w1.in[1] = wr1_ui; w1.out[1] = Wt1[1];
    w1.in[2] = wl1_iu; w1.out[2] = Wt1[2];
    w1.in[3] = wr1_iu; w1.out[3] = Wt1[3];
    dim3 g1(HH / 32, DD / 32, 4);  // [D,H] -> [H,D]
    twconv_batch_k<<<g1, 256, 0, stream>>>(w1, DD, HH);
    WBatch w2;
    w2.in[0] = wr2_ui; w2.out[0] = Wcat_item;
    w2.in[1] = wl2_iu; w2.out[1] = Wcat_item + (size_t)OO * HH;
    w2.in[2] = wr2_iu; w2.out[2] = Wcat_user;
    w2.in[3] = wl2_ui; w2.out[3] = Wcat_user + (size_t)OO * HH;
    dim3 g2(OO / 32, HH / 32, 4);  // [H,O] -> [O,H]
    twconv_batch_k<<<g2, 256, 0, stream>>>(w2, HH, OO);
  }

  const int nbMax = ((NU > NI ? NU : NI) * 64 + 255) / 256;
  const int myMax = ((NU > NI ? NU : NI) + 127) / 128;

  // ---- layer 1: gather-mean (paired) + dual GEMM (paired) ----
  {
    GatherJob gi = { row_i, csr_i, xb_user, agg_i, NI };
    GatherJob gu = { row_u, csr_u, xb_item, agg_u, NU };
    gather_mean16_k<false><<<dim3(nbMax, 2), 256, 0, stream>>>(gi, gu);
  }
  {
    GJob ji = { NI, agg_i, xb_item, Wt1[0], Wt1[1], b1_ui, h_item, nullptr };
    GJob ju = { NU, agg_u, xb_user, Wt1[2], Wt1[3], b1_iu, h_user, nullptr };
    dim3 g(HH / 128, myMax, 2);
    mfma_gemm_k<true, true, true, false, DD><<<g, 256, 0, stream>>>(ji, ju, HH);
  }

  // ---- layer 2 (re-associated, merged split GEMMs, paired) ----
  {
    GJob ji = { NI, h_item, nullptr, Wcat_item, nullptr, b2_ui, z_item, t_item };
    GJob ju = { NU, h_user, nullptr, Wcat_user, nullptr, b2_iu, z_user, t_user };
    dim3 g(2, myMax, 2);
    mfma_gemm_k<false, false, true, true, HH><<<g, 256, 0, stream>>>(ji, ju, 2 * OO);
  }
  {
    GatherJob gi = { row_i, csr_i, t_user, z_item, NI };
    GatherJob gu = { row_u, csr_u, t_item, z_user, NU };
    gather_mean16_k<true><<<dim3(nbMax, 2), 256, 0, stream>>>(gi, gu);
  }

  // ---- decode ----
  decode16_k<<<(int)(((long long)L * 16 + 255) / 256), 256, 0, stream>>>(lbl_src, lbl_dst, z_user, z_item, out, L);
}

// Round 11
// 397.147 us; speedup vs baseline: 1.2128x; 1.2128x over previous
//
#include <hip/hip_runtime.h>

#define DD 128   // input feature dim D
#define HH 256   // hidden dim H
#define OO 128   // output dim O

// CSR bucket config
#define NBI 256
#define NBU 512

typedef unsigned short bf16_t;
typedef short bf16x8 __attribute__((ext_vector_type(8)));   // 8 bf16 = 4 VGPRs
typedef float f32x4 __attribute__((ext_vector_type(4)));

__device__ __forceinline__ float bf2f(bf16_t u) {
  union { unsigned int i; float f; } v; v.i = ((unsigned int)u) << 16; return v.f;
}
__device__ __forceinline__ bf16_t f2bf(float f) {
  union { float f; unsigned int i; } v; v.f = f;
  unsigned int r = v.i + 0x7FFFu + ((v.i >> 16) & 1u);  // RNE
  return (bf16_t)(r >> 16);
}

__device__ __forceinline__ void acc8(float* acc, uint4 u) {
  const unsigned* p = (const unsigned*)&u;
#pragma unroll
  for (int i = 0; i < 4; ++i) {
    union { unsigned v; float f; } lo, hi;
    lo.v = p[i] << 16;
    hi.v = p[i] & 0xffff0000u;
    acc[2 * i] += lo.f;
    acc[2 * i + 1] += hi.f;
  }
}
__device__ __forceinline__ void unpack8(float* o, uint4 u) {
  const unsigned* p = (const unsigned*)&u;
#pragma unroll
  for (int i = 0; i < 4; ++i) {
    union { unsigned v; float f; } lo, hi;
    lo.v = p[i] << 16;
    hi.v = p[i] & 0xffff0000u;
    o[2 * i] = lo.f;
    o[2 * i + 1] = hi.f;
  }
}
__device__ __forceinline__ uint4 pack8(const float* v) {
  uint4 o; unsigned* p = (unsigned*)&o;
#pragma unroll
  for (int i = 0; i < 4; ++i)
    p[i] = (unsigned)f2bf(v[2 * i]) | ((unsigned)f2bf(v[2 * i + 1]) << 16);
  return o;
}

// ---------------------------------------------------------------------------
__global__ void probe_k(float* __restrict__ out, int n, float v) {
  int i = blockIdx.x * blockDim.x + threadIdx.x;
  if (i < n) out[i] = v;
}

// ---------------- CSR build (bucketed, no per-node global atomics) ----------
__global__ __launch_bounds__(256) void hist_k(
    const int* __restrict__ src, const int* __restrict__ dst,
    int* __restrict__ hist_u, int* __restrict__ hist_i,
    int E, int Wi, int Wu) {
  __shared__ int hi[NBI], hu[NBU];
  int tid = threadIdx.x;
  for (int t = tid; t < NBI; t += 256) hi[t] = 0;
  for (int t = tid; t < NBU; t += 256) hu[t] = 0;
  __syncthreads();
  int base = blockIdx.x * 4096;
#pragma unroll
  for (int j = 0; j < 16; ++j) {
    int e = base + tid + j * 256;
    if (e < E) {
      atomicAdd(&hi[dst[e] / Wi], 1);
      atomicAdd(&hu[src[e] / Wu], 1);
    }
  }
  __syncthreads();
  for (int t = tid; t < NBI; t += 256) if (hi[t]) atomicAdd(hist_i + t, hi[t]);
  for (int t = tid; t < NBU; t += 256) if (hu[t]) atomicAdd(hist_u + t, hu[t]);
}

__global__ __launch_bounds__(512) void scan_small_pair_k(
    const int* __restrict__ hist_i, int* __restrict__ off_i, int* __restrict__ cur_i,
    const int* __restrict__ hist_u, int* __restrict__ off_u, int* __restrict__ cur_u) {
  __shared__ int lds[512];
  const int* hist = blockIdx.x ? hist_u : hist_i;
  int* off = blockIdx.x ? off_u : off_i;
  int* cur = blockIdx.x ? cur_u : cur_i;
  int n = blockIdx.x ? NBU : NBI;
  int t = threadIdx.x;
  int v = (t < n) ? hist[t] : 0;
  lds[t] = v; __syncthreads();
  for (int o = 1; o < 512; o <<= 1) {
    int tv = (t >= o) ? lds[t - o] : 0;
    __syncthreads(); lds[t] += tv; __syncthreads();
  }
  if (t < n) { int e = lds[t] - v; off[t] = e; cur[t] = e; }
}

__global__ __launch_bounds__(256) void bucket_append_k(
    const int* __restrict__ src, const int* __restrict__ dst, int E, int Wi, int Wu,
    int* __restrict__ cur_bi, int* __restrict__ cur_bu,
    unsigned int* __restrict__ ebuf_i, unsigned int* __restrict__ ebuf_u) {
  __shared__ int bi[NBI], bu[NBU];
  __shared__ uint2 es[4096];
  int tid = threadIdx.x;
  int base = blockIdx.x * 4096;
  int n = E - base; if (n > 4096) n = 4096;
  for (int t = tid; t < NBI; t += 256) bi[t] = 0;
  for (int t = tid; t < NBU; t += 256) bu[t] = 0;
  __syncthreads();
#pragma unroll
  for (int j = 0; j < 16; ++j) {
    int idx = tid + j * 256;
    if (idx < n) {
      int s = src[base + idx], d = dst[base + idx];
      es[idx] = make_uint2((unsigned)s, (unsigned)d);
      atomicAdd(&bi[d / Wi], 1);
      atomicAdd(&bu[s / Wu], 1);
    }
  }
  __syncthreads();
  for (int t = tid; t < NBI; t += 256) { int c = bi[t]; bi[t] = c ? atomicAdd(cur_bi + t, c) : 0; }
  for (int t = tid; t < NBU; t += 256) { int c = bu[t]; bu[t] = c ? atomicAdd(cur_bu + t, c) : 0; }
  __syncthreads();
#pragma unroll
  for (int j = 0; j < 16; ++j) {
    int idx = tid + j * 256;
    if (idx < n) {
      int s = (int)es[idx].x, d = (int)es[idx].y;
      int bI = d / Wi, bU = s / Wu;
      int pI = atomicAdd(&bi[bI], 1);
      int pU = atomicAdd(&bu[bU], 1);
      ebuf_i[pI] = ((unsigned)(d - bI * Wi) << 24) | (unsigned)s;
      ebuf_u[pU] = ((unsigned)(s - bU * Wu) << 24) | (unsigned)d;
    }
  }
}

__global__ __launch_bounds__(256) void bucket_fill2_k(
    const unsigned int* __restrict__ ebuf, const int* __restrict__ off,
    const int* __restrict__ endc, int* __restrict__ row,
    int* __restrict__ csr, int n, int W, int E) {
  int b = blockIdx.x;
  int d0 = b * W; if (d0 >= n) return;
  int cnt = n - d0; if (cnt > W) cnt = W;
  __shared__ int hist[320];
  __shared__ int cur[320];
  int tid = threadIdx.x;
  for (int t = tid; t < cnt; t += 256) hist[t] = 0;
  __syncthreads();
  int beg = off[b], e_end = endc[b];
  for (int e = beg + tid; e < e_end; e += 256)
    atomicAdd(&hist[ebuf[e] >> 24], 1);
  __syncthreads();
  if (tid < 64) {
    int lane = tid;
    int carry = beg;
    int nc = (cnt + 63) >> 6;
    for (int c = 0; c < nc; ++c) {
      int idx = (c << 6) + lane;
      int v = (idx < cnt) ? hist[idx] : 0;
      int x = v;
#pragma unroll
      for (int o = 1; o < 64; o <<= 1) { int t = __shfl_up(x, o); if (lane >= o) x += t; }
      if (idx < cnt) { int g = carry + x - v; row[d0 + idx] = g; cur[idx] = g; }
      carry += __shfl(x, 63);
    }
  }
  if (tid == 0 && d0 + cnt == n) row[n] = E;
  __syncthreads();
  for (int e = beg + tid; e < e_end; e += 256) {
    unsigned v = ebuf[e];
    int slot = atomicAdd(&cur[v >> 24], 1);
    csr[slot] = (int)(v & 0xFFFFFFu);
  }
}

// ---------------- dtype prep ----------------
__global__ void cvt_bf16_k(const float* __restrict__ in, bf16_t* __restrict__ out, int n4) {
  int i = blockIdx.x * blockDim.x + threadIdx.x;
  if (i < n4) {
    float4 v = ((const float4*)in)[i];
    ushort4 o; o.x = f2bf(v.x); o.y = f2bf(v.y); o.z = f2bf(v.z); o.w = f2bf(v.w);
    ((ushort4*)out)[i] = o;
  }
}

struct WBatch { const float* in[4]; bf16_t* out[4]; };
__global__ void twconv_batch_k(WBatch wb, int K, int N) {
  const float* __restrict__ in = wb.in[blockIdx.z];
  bf16_t* __restrict__ out = wb.out[blockIdx.z];
  __shared__ float t[32][33];
  int bx = blockIdx.x * 32, by = blockIdx.y * 32;
  int tx = threadIdx.x & 31, ty = threadIdx.x >> 5;  // 32x8
#pragma unroll
  for (int j = 0; j < 32; j += 8)
    t[ty + j][tx] = in[(size_t)(by + ty + j) * N + bx + tx];
  __syncthreads();
#pragma unroll
  for (int j = 0; j < 32; j += 8)
    out[(size_t)(bx + ty + j) * K + by + tx] = f2bf(t[tx][ty + j]);
}

// ---------------- gather-mean, D=128, 16 lanes/row, paired jobs ------------
struct GatherJob {
  const int* row; const int* csr;
  const bf16_t* X; bf16_t* agg; int n;
};

template<bool ADD>
__global__ void gather_mean16_k(GatherJob j0, GatherJob j1) {
  GatherJob j = blockIdx.y ? j1 : j0;
  int node = (int)(((long long)blockIdx.x * blockDim.x + threadIdx.x) >> 6);
  int lane = threadIdx.x & 63;
  if (node >= j.n) return;
  const int g = lane >> 4;
  const int l = lane & 15;
  int beg = j.row[node], end = j.row[node + 1];
  float acc[8] = {};
  for (int jj = beg; jj < end; jj += 64) {
    int cnt = min(64, end - jj);
    int my = (lane < cnt) ? j.csr[jj + lane] : 0;
    for (int k = 0; k < cnt; k += 4) {
      int idx = __shfl(my, k + g);
      if (k + g < cnt) {
        uint4 u = *(const uint4*)(j.X + (size_t)idx * 128 + l * 8);
        acc8(acc, u);
      }
    }
  }
#pragma unroll
  for (int m = 16; m < 64; m <<= 1)
#pragma unroll
    for (int i = 0; i < 8; ++i) acc[i] += __shfl_xor(acc[i], m);
  if (g == 0) {
    float inv = (end > beg) ? 1.0f / (float)(end - beg) : 0.0f;
    float v[8];
    if (ADD) {
      uint4 z = *(const uint4*)(j.agg + (size_t)node * 128 + l * 8);
      float zb[8]; unpack8(zb, z);
#pragma unroll
      for (int i = 0; i < 8; ++i) v[i] = acc[i] * inv + zb[i];
    } else {
#pragma unroll
      for (int i = 0; i < 8; ++i) v[i] = acc[i] * inv;
    }
    *(uint4*)(j.agg + (size_t)node * 128 + l * 8) = pack8(v);
  }
}

// ---------------- MFMA GEMM: full-K LDS staging, XOR-swizzled ----------------
// C = act( A1 @ W1 [+ A2 @ W2] [+ bias] ), A* bf16 [M,K] row-major,
// W*t bf16 [N,K] row-major. 128x128 tile, 4 waves (2x2 of 64x64).
// 2 stages x (16 global_load_lds -> barrier -> 4 ksteps x 16 MFMA).
// LDS 64KB (2 blocks/CU); 3 barriers/block total.
// Swizzle (rule #21, both-sides): 16B chunk c of row r stored at c^(r&7);
// global SOURCE pre-swizzled, LDS dest linear, ds_read applies same XOR.
struct GJob {
  int M;
  const bf16_t* A1; const bf16_t* A2;
  const bf16_t* W1t; const bf16_t* W2t;
  const float* bias;
  bf16_t* C; bf16_t* C2;
};

template<bool RELU, bool DUAL, bool BIAS, bool SPLIT, int KSTRIDE>
__global__ __launch_bounds__(256) void mfma_gemm_k(GJob j0, GJob j1, int N) {
  GJob j = blockIdx.z ? j1 : j0;
  const size_t row0 = (size_t)blockIdx.y * 128;
  if (row0 >= (size_t)j.M) return;
  const int col0 = blockIdx.x * 128;
  __shared__ __align__(16) bf16_t Als[128 * 128];   // 32KB, [row][128k] + chunk swizzle
  __shared__ __align__(16) bf16_t Bls[128 * 128];   // 32KB
  const int tid = threadIdx.x;
  const int wave = tid >> 6, lane = tid & 63;
  const int wr = wave >> 1, wc = wave & 1;
  const int M = j.M;
  const int l15 = lane & 15, l4 = lane >> 4;
  const int swz = l15 & 7;

  f32x4 acc[4][4] = {};

  auto STAGE = [&](int s) {
    const bf16_t* __restrict__ Ap = (DUAL && s) ? j.A2 : j.A1;
    const bf16_t* __restrict__ Wp = (DUAL && s) ? j.W2t : j.W1t;
    const int k0 = DUAL ? 0 : s * 128;     // elements
#pragma unroll
    for (int jj = 0; jj < 8; ++jj) {
      int i = tid + jj * 256;              // 16B slot index 0..2047
      int r = i >> 4;                      // tile row/col 0..127
      int cs = (i & 15) ^ (r & 7);         // swizzled source chunk
      size_t ar = row0 + r; if (ar >= (size_t)M) ar = M - 1;
      __builtin_amdgcn_global_load_lds(
          (const __attribute__((address_space(1))) void*)(Ap + ar * KSTRIDE + k0 + cs * 8),
          (__attribute__((address_space(3))) void*)(Als + i * 8), 16, 0, 0);
      __builtin_amdgcn_global_load_lds(
          (const __attribute__((address_space(1))) void*)(Wp + (size_t)(col0 + r) * KSTRIDE + k0 + cs * 8),
          (__attribute__((address_space(3))) void*)(Bls + i * 8), 16, 0, 0);
    }
  };

  auto COMPUTE = [&]() {
#pragma unroll
    for (int ks = 0; ks < 4; ++ks) {
      bf16x8 af[4], bfr[4];
#pragma unroll
      for (int mi = 0; mi < 4; ++mi) {
        int r = wr * 64 + mi * 16 + l15;
        int ch = (ks * 4 + l4) ^ swz;
        af[mi] = *(const bf16x8*)(Als + r * 128 + ch * 8);
      }
#pragma unroll
      for (int ni = 0; ni < 4; ++ni) {
        int r = wc * 64 + ni * 16 + l15;
        int ch = (ks * 4 + l4) ^ swz;
        bfr[ni] = *(const bf16x8*)(Bls + r * 128 + ch * 8);
      }
#pragma unroll
      for (int mi = 0; mi < 4; ++mi)
#pragma unroll
        for (int ni = 0; ni < 4; ++ni)
          acc[mi][ni] = __builtin_amdgcn_mfma_f32_16x16x32_bf16(af[mi], bfr[ni], acc[mi][ni], 0, 0, 0);
    }
  };

  STAGE(0);
  __syncthreads();          // drain stage 0
  COMPUTE();
  __syncthreads();          // all LDS reads done before overwrite
  STAGE(1);
  __syncthreads();          // drain stage 1
  COMPUTE();

  const int crow = wr * 64 + l4 * 4;
  int ccol = col0 + wc * 64 + l15;
  bf16_t* Co = j.C;
  int stride = N;
  bool useBias = BIAS;
  if (SPLIT) {
    const int half = N >> 1;
    stride = half;
    if (col0 >= half) { Co = j.C2; ccol -= half; useBias = false; }
  }
#pragma unroll
  for (int mi = 0; mi < 4; ++mi) {
#pragma unroll
    for (int jj = 0; jj < 4; ++jj) {
      size_t r = row0 + crow + mi * 16 + jj;
      if (r < (size_t)M) {
#pragma unroll
        for (int ni = 0; ni < 4; ++ni) {
          float v = acc[mi][ni][jj];
          if (BIAS) { if (useBias) v += j.bias[ccol + ni * 16]; }
          if (RELU) v = fmaxf(v, 0.f);
          Co[r * stride + ccol + ni * 16] = f2bf(v);
        }
      }
    }
  }
}

// ---------------- decode: 16 lanes/label, 16B loads ----------------
__global__ void decode16_k(const int* __restrict__ ls, const int* __restrict__ ld,
                           const bf16_t* __restrict__ zu, const bf16_t* __restrict__ zi,
                           float* __restrict__ out, int L) {
  long long gid = (long long)blockIdx.x * blockDim.x + threadIdx.x;
  int w = (int)(gid >> 4);
  int l = (int)(gid & 15);
  if (w >= L) return;
  int su = ls[w], si = ld[w];
  uint4 a = *(const uint4*)(zu + (size_t)su * OO + l * 8);
  uint4 b = *(const uint4*)(zi + (size_t)si * OO + l * 8);
  const unsigned* pa = (const unsigned*)&a;
  const unsigned* pb = (const unsigned*)&b;
  float sum = 0.f;
#pragma unroll
  for (int i = 0; i < 4; ++i) {
    union { unsigned v; float f; } la, ha, lb, hb;
    la.v = pa[i] << 16;        ha.v = pa[i] & 0xffff0000u;
    lb.v = pb[i] << 16;        hb.v = pb[i] & 0xffff0000u;
    sum += la.f * lb.f + ha.f * hb.f;
  }
#pragma unroll
  for (int m = 1; m < 16; m <<= 1) sum += __shfl_xor(sum, m);
  if (l == 0) out[w] = sum;
}

// ---------------------------------------------------------------------------
extern "C" void kernel_launch(void* const* d_in, const int* in_sizes, int n_in,
                              void* d_out, int out_size, void* d_ws, size_t ws_size,
                              hipStream_t stream) {
  const float* x_user = (const float*)d_in[0];
  const float* x_item = (const float*)d_in[1];
  const int* edge_src = (const int*)d_in[2];
  const int* edge_dst = (const int*)d_in[3];
  const int* lbl_src  = (const int*)d_in[4];
  const int* lbl_dst  = (const int*)d_in[5];
  const float* wl1_ui = (const float*)d_in[6];
  const float* wr1_ui = (const float*)d_in[7];
  const float* b1_ui  = (const float*)d_in[8];
  const float* wl1_iu = (const float*)d_in[9];
  const float* wr1_iu = (const float*)d_in[10];
  const float* b1_iu  = (const float*)d_in[11];
  const float* wl2_ui = (const float*)d_in[12];
  const float* wr2_ui = (const float*)d_in[13];
  const float* b2_ui  = (const float*)d_in[14];
  const float* wl2_iu = (const float*)d_in[15];
  const float* wr2_iu = (const float*)d_in[16];
  const float* b2_iu  = (const float*)d_in[17];

  const int NU = in_sizes[0] / DD;
  const int NI = in_sizes[1] / DD;
  const int E  = in_sizes[2];
  const int L  = in_sizes[4];
  const int Wi = (NI + NBI - 1) / NBI;
  const int Wu = (NU + NBU - 1) / NBU;
  const int nEB = (E + 4095) / 4096;

  // ---- workspace layout ----
  size_t off = 0;
  auto take = [&](size_t bytes) { size_t o = off; off = (off + bytes + 255) & ~(size_t)255; return o; };
  char* base = (char*)d_ws;
  int* hist_i = (int*)(base + take(((size_t)NBI + NBU) * 4));  // zeroed together
  int* hist_u = hist_i + NBI;
  size_t zeroB = ((size_t)NBI + NBU) * 4;
  int* row_i = (int*)(base + take((size_t)(NI + 1) * 4));
  int* row_u = (int*)(base + take((size_t)(NU + 1) * 4));
  int* off_i = (int*)(base + take((size_t)NBI * 4));
  int* off_u = (int*)(base + take((size_t)NBU * 4));
  int* cur_bi = (int*)(base + take((size_t)NBI * 4));
  int* cur_bu = (int*)(base + take((size_t)NBU * 4));
  int* csr_i = (int*)(base + take((size_t)E * 4));
  int* csr_u = (int*)(base + take((size_t)E * 4));
  unsigned int* ebuf_i = (unsigned int*)(base + take((size_t)E * 4));
  unsigned int* ebuf_u = (unsigned int*)(base + take((size_t)E * 4));
  bf16_t* pool = (bf16_t*)(base + take((size_t)(NI + NU) * HH * 2));
  bf16_t* agg_i   = pool;                              // NI*DD
  bf16_t* agg_u   = agg_i + (size_t)NI * DD;           // NU*DD
  bf16_t* xb_item = agg_u + (size_t)NU * DD;           // NI*DD
  bf16_t* xb_user = xb_item + (size_t)NI * DD;         // NU*DD
  bf16_t* t_user  = pool;                              // NU*OO
  bf16_t* t_item  = t_user + (size_t)NU * OO;          // NI*OO
  bf16_t* h_item = (bf16_t*)(base + take((size_t)(NI + NU) * HH * 2));
  bf16_t* h_user = h_item + (size_t)NI * HH;
  bf16_t* z_item = (bf16_t*)(base + take((size_t)(NI + NU) * OO * 2));
  bf16_t* z_user = z_item + (size_t)NI * OO;
  bf16_t* Wt1[4];
  for (int w = 0; w < 4; ++w) Wt1[w] = (bf16_t*)(base + take((size_t)HH * DD * 2));
  bf16_t* Wcat_item = (bf16_t*)(base + take((size_t)2 * OO * HH * 2));
  bf16_t* Wcat_user = (bf16_t*)(base + take((size_t)2 * OO * HH * 2));
  size_t need = off;

  float* out = (float*)d_out;
  if (ws_size < need || Wi > 320 || Wu > 320) {
    probe_k<<<(L + 255) / 256, 256, 0, stream>>>(out, L, (float)(ws_size >> 20));
    return;
  }

  // ---- CSR build ----
  hipMemsetAsync(hist_i, 0, zeroB, stream);
  hist_k<<<nEB, 256, 0, stream>>>(edge_src, edge_dst, hist_u, hist_i, E, Wi, Wu);
  scan_small_pair_k<<<2, 512, 0, stream>>>(hist_i, off_i, cur_bi, hist_u, off_u, cur_bu);
  bucket_append_k<<<nEB, 256, 0, stream>>>(edge_src, edge_dst, E, Wi, Wu, cur_bi, cur_bu, ebuf_i, ebuf_u);
  bucket_fill2_k<<<NBI, 256, 0, stream>>>(ebuf_i, off_i, cur_bi, row_i, csr_i, NI, Wi, E);
  bucket_fill2_k<<<NBU, 256, 0, stream>>>(ebuf_u, off_u, cur_bu, row_u, csr_u, NU, Wu, E);

  // ---- dtype prep ----
  cvt_bf16_k<<<(NI * DD / 4 + 255) / 256, 256, 0, stream>>>(x_item, xb_item, NI * DD / 4);
  cvt_bf16_k<<<(NU * DD / 4 + 255) / 256, 256, 0, stream>>>(x_user, xb_user, NU * DD / 4);
  {
    WBatch w1;
    w1.in[0] = wl1_ui; w1.out[0] = Wt1[0];
    w1.in[1] = wr1_ui; w1.out[1] = Wt1[1];
    w1.in[2] = wl1_iu; w1.out[2] = Wt1[2];
    w1.in[3] = wr1_iu; w1.out[3] = Wt1[3];
    dim3 g1(HH / 32, DD / 32, 4);  // [D,H] -> [H,D]
    twconv_batch_k<<<g1, 256, 0, stream>>>(w1, DD, HH);
    WBatch w2;
    w2.in[0] = wr2_ui; w2.out[0] = Wcat_item;
    w2.in[1] = wl2_iu; w2.out[1] = Wcat_item + (size_t)OO * HH;
    w2.in[2] = wr2_iu; w2.out[2] = Wcat_user;
    w2.in[3] = wl2_ui; w2.out[3] = Wcat_user + (size_t)OO * HH;
    dim3 g2(OO / 32, HH / 32, 4);  // [H,O] -> [O,H]
    twconv_batch_k<<<g2, 256, 0, stream>>>(w2, HH, OO);
  }

  const int nbMax = ((NU > NI ? NU : NI) * 64 + 255) / 256;
  const int myMax = ((NU > NI ? NU : NI) + 127) / 128;

  // ---- layer 1: gather-mean (paired) + dual GEMM (paired) ----
  {
    GatherJob gi = { row_i, csr_i, xb_user, agg_i, NI };
    GatherJob gu = { row_u, csr_u, xb_item, agg_u, NU };
    gather_mean16_k<false><<<dim3(nbMax, 2), 256, 0, stream>>>(gi, gu);
  }
  {
    GJob ji = { NI, agg_i, xb_item, Wt1[0], Wt1[1], b1_ui, h_item, nullptr };
    GJob ju = { NU, agg_u, xb_user, Wt1[2], Wt1[3], b1_iu, h_user, nullptr };
    dim3 g(HH / 128, myMax, 2);
    mfma_gemm_k<true, true, true, false, DD><<<g, 256, 0, stream>>>(ji, ju, HH);
  }

  // ---- layer 2 (re-associated, merged split GEMMs, paired) ----
  {
    GJob ji = { NI, h_item, nullptr, Wcat_item, nullptr, b2_ui, z_item, t_item };
    GJob ju = { NU, h_user, nullptr, Wcat_user, nullptr, b2_iu, z_user, t_user };
    dim3 g(2, myMax, 2);
    mfma_gemm_k<false, false, true, true, HH><<<g, 256, 0, stream>>>(ji, ju, 2 * OO);
  }
  {
    GatherJob gi = { row_i, csr_i, t_user, z_item, NI };
    GatherJob gu = { row_u, csr_u, t_item, z_user, NU };
    gather_mean16_k<true><<<dim3(nbMax, 2), 256, 0, stream>>>(gi, gu);
  }

  // ---- decode ----
  decode16_k<<<(int)(((long long)L * 16 + 255) / 256), 256, 0, stream>>>(lbl_src, lbl_dst, z_user, z_item, out, L);
}

// Round 12
// 397.131 us; speedup vs baseline: 1.2128x; 1.0000x over previous
//
#include <hip/hip_runtime.h>

#define DD 128   // input feature dim D
#define HH 256   // hidden dim H
#define OO 128   // output dim O

// CSR bucket config
#define NBI 256
#define NBU 512

typedef unsigned short bf16_t;
typedef short bf16x8 __attribute__((ext_vector_type(8)));   // 8 bf16 = 4 VGPRs
typedef float f32x4 __attribute__((ext_vector_type(4)));

__device__ __forceinline__ float bf2f(bf16_t u) {
  union { unsigned int i; float f; } v; v.i = ((unsigned int)u) << 16; return v.f;
}
__device__ __forceinline__ bf16_t f2bf(float f) {
  union { float f; unsigned int i; } v; v.f = f;
  unsigned int r = v.i + 0x7FFFu + ((v.i >> 16) & 1u);  // RNE
  return (bf16_t)(r >> 16);
}

__device__ __forceinline__ void acc8(float* acc, uint4 u) {
  const unsigned* p = (const unsigned*)&u;
#pragma unroll
  for (int i = 0; i < 4; ++i) {
    union { unsigned v; float f; } lo, hi;
    lo.v = p[i] << 16;
    hi.v = p[i] & 0xffff0000u;
    acc[2 * i] += lo.f;
    acc[2 * i + 1] += hi.f;
  }
}
__device__ __forceinline__ void unpack8(float* o, uint4 u) {
  const unsigned* p = (const unsigned*)&u;
#pragma unroll
  for (int i = 0; i < 4; ++i) {
    union { unsigned v; float f; } lo, hi;
    lo.v = p[i] << 16;
    hi.v = p[i] & 0xffff0000u;
    o[2 * i] = lo.f;
    o[2 * i + 1] = hi.f;
  }
}
__device__ __forceinline__ uint4 pack8(const float* v) {
  uint4 o; unsigned* p = (unsigned*)&o;
#pragma unroll
  for (int i = 0; i < 4; ++i)
    p[i] = (unsigned)f2bf(v[2 * i]) | ((unsigned)f2bf(v[2 * i + 1]) << 16);
  return o;
}

// ---------------------------------------------------------------------------
__global__ void probe_k(float* __restrict__ out, int n, float v) {
  int i = blockIdx.x * blockDim.x + threadIdx.x;
  if (i < n) out[i] = v;
}

// ---------------- CSR build (bucketed, no per-node global atomics) ----------
__global__ __launch_bounds__(256) void hist_k(
    const int* __restrict__ src, const int* __restrict__ dst,
    int* __restrict__ hist_u, int* __restrict__ hist_i,
    int E, int Wi, int Wu) {
  __shared__ int hi[NBI], hu[NBU];
  int tid = threadIdx.x;
  for (int t = tid; t < NBI; t += 256) hi[t] = 0;
  for (int t = tid; t < NBU; t += 256) hu[t] = 0;
  __syncthreads();
  int base = blockIdx.x * 4096;
#pragma unroll
  for (int j = 0; j < 16; ++j) {
    int e = base + tid + j * 256;
    if (e < E) {
      atomicAdd(&hi[dst[e] / Wi], 1);
      atomicAdd(&hu[src[e] / Wu], 1);
    }
  }
  __syncthreads();
  for (int t = tid; t < NBI; t += 256) if (hi[t]) atomicAdd(hist_i + t, hi[t]);
  for (int t = tid; t < NBU; t += 256) if (hu[t]) atomicAdd(hist_u + t, hu[t]);
}

__global__ __launch_bounds__(512) void scan_small_pair_k(
    const int* __restrict__ hist_i, int* __restrict__ off_i, int* __restrict__ cur_i,
    const int* __restrict__ hist_u, int* __restrict__ off_u, int* __restrict__ cur_u) {
  __shared__ int lds[512];
  const int* hist = blockIdx.x ? hist_u : hist_i;
  int* off = blockIdx.x ? off_u : off_i;
  int* cur = blockIdx.x ? cur_u : cur_i;
  int n = blockIdx.x ? NBU : NBI;
  int t = threadIdx.x;
  int v = (t < n) ? hist[t] : 0;
  lds[t] = v; __syncthreads();
  for (int o = 1; o < 512; o <<= 1) {
    int tv = (t >= o) ? lds[t - o] : 0;
    __syncthreads(); lds[t] += tv; __syncthreads();
  }
  if (t < n) { int e = lds[t] - v; off[t] = e; cur[t] = e; }
}

__global__ __launch_bounds__(256) void bucket_append_k(
    const int* __restrict__ src, const int* __restrict__ dst, int E, int Wi, int Wu,
    int* __restrict__ cur_bi, int* __restrict__ cur_bu,
    unsigned int* __restrict__ ebuf_i, unsigned int* __restrict__ ebuf_u) {
  __shared__ int bi[NBI], bu[NBU];
  __shared__ uint2 es[4096];
  int tid = threadIdx.x;
  int base = blockIdx.x * 4096;
  int n = E - base; if (n > 4096) n = 4096;
  for (int t = tid; t < NBI; t += 256) bi[t] = 0;
  for (int t = tid; t < NBU; t += 256) bu[t] = 0;
  __syncthreads();
#pragma unroll
  for (int j = 0; j < 16; ++j) {
    int idx = tid + j * 256;
    if (idx < n) {
      int s = src[base + idx], d = dst[base + idx];
      es[idx] = make_uint2((unsigned)s, (unsigned)d);
      atomicAdd(&bi[d / Wi], 1);
      atomicAdd(&bu[s / Wu], 1);
    }
  }
  __syncthreads();
  for (int t = tid; t < NBI; t += 256) { int c = bi[t]; bi[t] = c ? atomicAdd(cur_bi + t, c) : 0; }
  for (int t = tid; t < NBU; t += 256) { int c = bu[t]; bu[t] = c ? atomicAdd(cur_bu + t, c) : 0; }
  __syncthreads();
#pragma unroll
  for (int j = 0; j < 16; ++j) {
    int idx = tid + j * 256;
    if (idx < n) {
      int s = (int)es[idx].x, d = (int)es[idx].y;
      int bI = d / Wi, bU = s / Wu;
      int pI = atomicAdd(&bi[bI], 1);
      int pU = atomicAdd(&bu[bU], 1);
      ebuf_i[pI] = ((unsigned)(d - bI * Wi) << 24) | (unsigned)s;
      ebuf_u[pU] = ((unsigned)(s - bU * Wu) << 24) | (unsigned)d;
    }
  }
}

__global__ __launch_bounds__(256) void bucket_fill2_k(
    const unsigned int* __restrict__ ebuf, const int* __restrict__ off,
    const int* __restrict__ endc, int* __restrict__ row,
    int* __restrict__ csr, int n, int W, int E) {
  int b = blockIdx.x;
  int d0 = b * W; if (d0 >= n) return;
  int cnt = n - d0; if (cnt > W) cnt = W;
  __shared__ int hist[320];
  __shared__ int cur[320];
  int tid = threadIdx.x;
  for (int t = tid; t < cnt; t += 256) hist[t] = 0;
  __syncthreads();
  int beg = off[b], e_end = endc[b];
  for (int e = beg + tid; e < e_end; e += 256)
    atomicAdd(&hist[ebuf[e] >> 24], 1);
  __syncthreads();
  if (tid < 64) {
    int lane = tid;
    int carry = beg;
    int nc = (cnt + 63) >> 6;
    for (int c = 0; c < nc; ++c) {
      int idx = (c << 6) + lane;
      int v = (idx < cnt) ? hist[idx] : 0;
      int x = v;
#pragma unroll
      for (int o = 1; o < 64; o <<= 1) { int t = __shfl_up(x, o); if (lane >= o) x += t; }
      if (idx < cnt) { int g = carry + x - v; row[d0 + idx] = g; cur[idx] = g; }
      carry += __shfl(x, 63);
    }
  }
  if (tid == 0 && d0 + cnt == n) row[n] = E;
  __syncthreads();
  for (int e = beg + tid; e < e_end; e += 256) {
    unsigned v = ebuf[e];
    int slot = atomicAdd(&cur[v >> 24], 1);
    csr[slot] = (int)(v & 0xFFFFFFu);
  }
}

// ---------------- dtype prep ----------------
__global__ void cvt_bf16_k(const float* __restrict__ in, bf16_t* __restrict__ out, int n4) {
  int i = blockIdx.x * blockDim.x + threadIdx.x;
  if (i < n4) {
    float4 v = ((const float4*)in)[i];
    ushort4 o; o.x = f2bf(v.x); o.y = f2bf(v.y); o.z = f2bf(v.z); o.w = f2bf(v.w);
    ((ushort4*)out)[i] = o;
  }
}

struct WBatch { const float* in[4]; bf16_t* out[4]; };
__global__ void twconv_batch_k(WBatch wb, int K, int N) {
  const float* __restrict__ in = wb.in[blockIdx.z];
  bf16_t* __restrict__ out = wb.out[blockIdx.z];
  __shared__ float t[32][33];
  int bx = blockIdx.x * 32, by = blockIdx.y * 32;
  int tx = threadIdx.x & 31, ty = threadIdx.x >> 5;  // 32x8
#pragma unroll
  for (int j = 0; j < 32; j += 8)
    t[ty + j][tx] = in[(size_t)(by + ty + j) * N + bx + tx];
  __syncthreads();
#pragma unroll
  for (int j = 0; j < 32; j += 8)
    out[(size_t)(bx + ty + j) * K + by + tx] = f2bf(t[tx][ty + j]);
}

// ---------------- gather-mean, D=128, 16 lanes/row, paired jobs ------------
struct GatherJob {
  const int* row; const int* csr;
  const bf16_t* X; bf16_t* agg; int n;
};

template<bool ADD>
__global__ void gather_mean16_k(GatherJob j0, GatherJob j1) {
  GatherJob j = blockIdx.y ? j1 : j0;
  int node = (int)(((long long)blockIdx.x * blockDim.x + threadIdx.x) >> 6);
  int lane = threadIdx.x & 63;
  if (node >= j.n) return;
  const int g = lane >> 4;
  const int l = lane & 15;
  int beg = j.row[node], end = j.row[node + 1];
  float acc[8] = {};
  for (int jj = beg; jj < end; jj += 64) {
    int cnt = min(64, end - jj);
    int my = (lane < cnt) ? j.csr[jj + lane] : 0;
    for (int k = 0; k < cnt; k += 4) {
      int idx = __shfl(my, k + g);
      if (k + g < cnt) {
        uint4 u = *(const uint4*)(j.X + (size_t)idx * 128 + l * 8);
        acc8(acc, u);
      }
    }
  }
#pragma unroll
  for (int m = 16; m < 64; m <<= 1)
#pragma unroll
    for (int i = 0; i < 8; ++i) acc[i] += __shfl_xor(acc[i], m);
  if (g == 0) {
    float inv = (end > beg) ? 1.0f / (float)(end - beg) : 0.0f;
    float v[8];
    if (ADD) {
      uint4 z = *(const uint4*)(j.agg + (size_t)node * 128 + l * 8);
      float zb[8]; unpack8(zb, z);
#pragma unroll
      for (int i = 0; i < 8; ++i) v[i] = acc[i] * inv + zb[i];
    } else {
#pragma unroll
      for (int i = 0; i < 8; ++i) v[i] = acc[i] * inv;
    }
    *(uint4*)(j.agg + (size_t)node * 128 + l * 8) = pack8(v);
  }
}

// ---------------- FUSED two-layer MFMA GEMM ----------------
// Per 128-row node block:
//   h[128x256] = relu(agg@W1 + xb@W2 + b1)   (K=DD=128, h kept in LDS, bf16)
//   z[128x128] = h@Wc[:,0:128]   + b2        (K=HH=256)
//   t[128x128] = h@Wc[:,128:256]
// A-tiles staged once via global_load_lds (XOR-swizzled source, linear LDS);
// W fragments read direct from global (L2-hot, <=128KB). 2 barriers/block.
// 512 threads = 8 waves (2 row x 4 col), each wave owns 64x64 of 128x256.
struct FJob {
  int M;
  const bf16_t* Aagg; const bf16_t* Axb;
  const bf16_t* W1; const bf16_t* W2;    // [256][128] row-major (^T)
  const float* b1;
  const bf16_t* Wc;                      // [256][256] row-major (^T), z|t concat
  const float* b2;
  bf16_t* Cz; bf16_t* Ct;
};

__global__ __launch_bounds__(512) void fused_gemm_k(FJob j0, FJob j1, int nbi) {
  const int bx = blockIdx.x;
  FJob j = (bx < nbi) ? j0 : j1;
  const int rb = (bx < nbi) ? bx : bx - nbi;
  const size_t row0 = (size_t)rb * 128;
  __shared__ __align__(16) bf16_t Aag[128 * 128];   // 32KB
  __shared__ __align__(16) bf16_t Axb[128 * 128];   // 32KB
  __shared__ __align__(16) bf16_t Hls[128 * 256];   // 64KB
  const int tid = threadIdx.x;
  const int wave = tid >> 6, lane = tid & 63;
  const int wr = wave >> 2, wc = wave & 3;          // 2x4 waves
  const int l15 = lane & 15, l4 = lane >> 4;
  const int M = j.M;

  // ---- stage A tiles (one drain) ----
#pragma unroll
  for (int jj = 0; jj < 4; ++jj) {
    int i = tid + jj * 512;            // 16B slot 0..2047
    int r = i >> 4, c = i & 15;
    size_t ar = row0 + r; if (ar >= (size_t)M) ar = M - 1;
    int cs = c ^ (r & 7);              // pre-swizzled source chunk
    __builtin_amdgcn_global_load_lds(
        (const __attribute__((address_space(1))) void*)(j.Aagg + ar * 128 + cs * 8),
        (__attribute__((address_space(3))) void*)(Aag + i * 8), 16, 0, 0);
    __builtin_amdgcn_global_load_lds(
        (const __attribute__((address_space(1))) void*)(j.Axb + ar * 128 + cs * 8),
        (__attribute__((address_space(3))) void*)(Axb + i * 8), 16, 0, 0);
  }
  __syncthreads();

  f32x4 acc[4][4] = {};

  // ---- phase 1: h = relu(agg@W1 + xb@W2 + b1) ----
#pragma unroll
  for (int kk = 0; kk < 4; ++kk) {     // K = 128
    bf16x8 aa[4], ax[4], bl[4], br[4];
#pragma unroll
    for (int mi = 0; mi < 4; ++mi) {
      int ra = wr * 64 + mi * 16 + l15;
      int ch = (kk * 4 + l4) ^ (ra & 7);
      aa[mi] = *(const bf16x8*)(Aag + ra * 128 + ch * 8);
      ax[mi] = *(const bf16x8*)(Axb + ra * 128 + ch * 8);
    }
#pragma unroll
    for (int ni = 0; ni < 4; ++ni) {
      int c1 = wc * 64 + ni * 16 + l15;
      bl[ni] = *(const bf16x8*)(j.W1 + (size_t)c1 * 128 + kk * 32 + l4 * 8);
      br[ni] = *(const bf16x8*)(j.W2 + (size_t)c1 * 128 + kk * 32 + l4 * 8);
    }
#pragma unroll
    for (int mi = 0; mi < 4; ++mi)
#pragma unroll
      for (int ni = 0; ni < 4; ++ni) {
        acc[mi][ni] = __builtin_amdgcn_mfma_f32_16x16x32_bf16(aa[mi], bl[ni], acc[mi][ni], 0, 0, 0);
        acc[mi][ni] = __builtin_amdgcn_mfma_f32_16x16x32_bf16(ax[mi], br[ni], acc[mi][ni], 0, 0, 0);
      }
  }

  // h epilogue -> LDS (chunk-swizzled rows)
#pragma unroll
  for (int ni = 0; ni < 4; ++ni) {
    int col = wc * 64 + ni * 16 + l15;
    float b = j.b1[col];
#pragma unroll
    for (int mi = 0; mi < 4; ++mi)
#pragma unroll
      for (int q = 0; q < 4; ++q) {
        int r = wr * 64 + mi * 16 + l4 * 4 + q;
        float v = fmaxf(acc[mi][ni][q] + b, 0.f);
        Hls[r * 256 + (((col >> 3) ^ (r & 7)) << 3) + (col & 7)] = f2bf(v);
      }
  }
  __syncthreads();

  // ---- phase 2: z|t = h @ Wc ----
#pragma unroll
  for (int mi = 0; mi < 4; ++mi)
#pragma unroll
    for (int ni = 0; ni < 4; ++ni)
#pragma unroll
      for (int q = 0; q < 4; ++q) acc[mi][ni][q] = 0.f;

#pragma unroll
  for (int kk = 0; kk < 8; ++kk) {     // K = 256
    bf16x8 ah[4], bw[4];
#pragma unroll
    for (int mi = 0; mi < 4; ++mi) {
      int r2 = wr * 64 + mi * 16 + l15;
      int ch = (kk * 4 + l4) ^ (r2 & 7);
      ah[mi] = *(const bf16x8*)(Hls + r2 * 256 + ch * 8);
    }
#pragma unroll
    for (int ni = 0; ni < 4; ++ni) {
      int c2 = wc * 64 + ni * 16 + l15;
      bw[ni] = *(const bf16x8*)(j.Wc + (size_t)c2 * 256 + kk * 32 + l4 * 8);
    }
#pragma unroll
    for (int mi = 0; mi < 4; ++mi)
#pragma unroll
      for (int ni = 0; ni < 4; ++ni)
        acc[mi][ni] = __builtin_amdgcn_mfma_f32_16x16x32_bf16(ah[mi], bw[ni], acc[mi][ni], 0, 0, 0);
  }

  // ---- store z (cols 0..127, +bias) and t (cols 128..255) ----
#pragma unroll
  for (int ni = 0; ni < 4; ++ni) {
    int c2 = wc * 64 + ni * 16 + l15;
    bf16_t* Co; int cc; float bb;
    if (c2 < 128) { Co = j.Cz; cc = c2; bb = j.b2[cc]; }
    else          { Co = j.Ct; cc = c2 - 128; bb = 0.f; }
#pragma unroll
    for (int mi = 0; mi < 4; ++mi)
#pragma unroll
      for (int q = 0; q < 4; ++q) {
        size_t r = row0 + wr * 64 + mi * 16 + l4 * 4 + q;
        if (r < (size_t)M) Co[r * 128 + cc] = f2bf(acc[mi][ni][q] + bb);
      }
  }
}

// ---------------- decode: 16 lanes/label, 16B loads ----------------
__global__ void decode16_k(const int* __restrict__ ls, const int* __restrict__ ld,
                           const bf16_t* __restrict__ zu, const bf16_t* __restrict__ zi,
                           float* __restrict__ out, int L) {
  long long gid = (long long)blockIdx.x * blockDim.x + threadIdx.x;
  int w = (int)(gid >> 4);
  int l = (int)(gid & 15);
  if (w >= L) return;
  int su = ls[w], si = ld[w];
  uint4 a = *(const uint4*)(zu + (size_t)su * OO + l * 8);
  uint4 b = *(const uint4*)(zi + (size_t)si * OO + l * 8);
  const unsigned* pa = (const unsigned*)&a;
  const unsigned* pb = (const unsigned*)&b;
  float sum = 0.f;
#pragma unroll
  for (int i = 0; i < 4; ++i) {
    union { unsigned v; float f; } la, ha, lb, hb;
    la.v = pa[i] << 16;        ha.v = pa[i] & 0xffff0000u;
    lb.v = pb[i] << 16;        hb.v = pb[i] & 0xffff0000u;
    sum += la.f * lb.f + ha.f * hb.f;
  }
#pragma unroll
  for (int m = 1; m < 16; m <<= 1) sum += __shfl_xor(sum, m);
  if (l == 0) out[w] = sum;
}

// ---------------------------------------------------------------------------
extern "C" void kernel_launch(void* const* d_in, const int* in_sizes, int n_in,
                              void* d_out, int out_size, void* d_ws, size_t ws_size,
                              hipStream_t stream) {
  const float* x_user = (const float*)d_in[0];
  const float* x_item = (const float*)d_in[1];
  const int* edge_src = (const int*)d_in[2];
  const int* edge_dst = (const int*)d_in[3];
  const int* lbl_src  = (const int*)d_in[4];
  const int* lbl_dst  = (const int*)d_in[5];
  const float* wl1_ui = (const float*)d_in[6];
  const float* wr1_ui = (const float*)d_in[7];
  const float* b1_ui  = (const float*)d_in[8];
  const float* wl1_iu = (const float*)d_in[9];
  const float* wr1_iu = (const float*)d_in[10];
  const float* b1_iu  = (const float*)d_in[11];
  const float* wl2_ui = (const float*)d_in[12];
  const float* wr2_ui = (const float*)d_in[13];
  const float* b2_ui  = (const float*)d_in[14];
  const float* wl2_iu = (const float*)d_in[15];
  const float* wr2_iu = (const float*)d_in[16];
  const float* b2_iu  = (const float*)d_in[17];

  const int NU = in_sizes[0] / DD;
  const int NI = in_sizes[1] / DD;
  const int E  = in_sizes[2];
  const int L  = in_sizes[4];
  const int Wi = (NI + NBI - 1) / NBI;
  const int Wu = (NU + NBU - 1) / NBU;
  const int nEB = (E + 4095) / 4096;

  // ---- workspace layout ----
  size_t off = 0;
  auto take = [&](size_t bytes) { size_t o = off; off = (off + bytes + 255) & ~(size_t)255; return o; };
  char* base = (char*)d_ws;
  int* hist_i = (int*)(base + take(((size_t)NBI + NBU) * 4));  // zeroed together
  int* hist_u = hist_i + NBI;
  size_t zeroB = ((size_t)NBI + NBU) * 4;
  int* row_i = (int*)(base + take((size_t)(NI + 1) * 4));
  int* row_u = (int*)(base + take((size_t)(NU + 1) * 4));
  int* off_i = (int*)(base + take((size_t)NBI * 4));
  int* off_u = (int*)(base + take((size_t)NBU * 4));
  int* cur_bi = (int*)(base + take((size_t)NBI * 4));
  int* cur_bu = (int*)(base + take((size_t)NBU * 4));
  int* csr_i = (int*)(base + take((size_t)E * 4));
  int* csr_u = (int*)(base + take((size_t)E * 4));
  unsigned int* ebuf_i = (unsigned int*)(base + take((size_t)E * 4));
  unsigned int* ebuf_u = (unsigned int*)(base + take((size_t)E * 4));
  // pool holds agg + xb (all persistent through the fused GEMM)
  bf16_t* pool = (bf16_t*)(base + take((size_t)(NI + NU) * HH * 2));
  bf16_t* agg_i   = pool;                              // NI*DD
  bf16_t* agg_u   = agg_i + (size_t)NI * DD;           // NU*DD
  bf16_t* xb_item = agg_u + (size_t)NU * DD;           // NI*DD
  bf16_t* xb_user = xb_item + (size_t)NI * DD;         // NU*DD
  // t is written by the fused kernel while agg/xb are still live -> separate
  bf16_t* t_user = (bf16_t*)(base + take((size_t)(NI + NU) * OO * 2));
  bf16_t* t_item = t_user + (size_t)NU * OO;
  bf16_t* z_item = (bf16_t*)(base + take((size_t)(NI + NU) * OO * 2));
  bf16_t* z_user = z_item + (size_t)NI * OO;
  bf16_t* Wt1[4];
  for (int w = 0; w < 4; ++w) Wt1[w] = (bf16_t*)(base + take((size_t)HH * DD * 2));
  bf16_t* Wcat_item = (bf16_t*)(base + take((size_t)2 * OO * HH * 2));
  bf16_t* Wcat_user = (bf16_t*)(base + take((size_t)2 * OO * HH * 2));
  size_t need = off;

  float* out = (float*)d_out;
  if (ws_size < need || Wi > 320 || Wu > 320) {
    probe_k<<<(L + 255) / 256, 256, 0, stream>>>(out, L, (float)(ws_size >> 20));
    return;
  }

  // ---- CSR build ----
  hipMemsetAsync(hist_i, 0, zeroB, stream);
  hist_k<<<nEB, 256, 0, stream>>>(edge_src, edge_dst, hist_u, hist_i, E, Wi, Wu);
  scan_small_pair_k<<<2, 512, 0, stream>>>(hist_i, off_i, cur_bi, hist_u, off_u, cur_bu);
  bucket_append_k<<<nEB, 256, 0, stream>>>(edge_src, edge_dst, E, Wi, Wu, cur_bi, cur_bu, ebuf_i, ebuf_u);
  bucket_fill2_k<<<NBI, 256, 0, stream>>>(ebuf_i, off_i, cur_bi, row_i, csr_i, NI, Wi, E);
  bucket_fill2_k<<<NBU, 256, 0, stream>>>(ebuf_u, off_u, cur_bu, row_u, csr_u, NU, Wu, E);

  // ---- dtype prep ----
  cvt_bf16_k<<<(NI * DD / 4 + 255) / 256, 256, 0, stream>>>(x_item, xb_item, NI * DD / 4);
  cvt_bf16_k<<<(NU * DD / 4 + 255) / 256, 256, 0, stream>>>(x_user, xb_user, NU * DD / 4);
  {
    WBatch w1;
    w1.in[0] = wl1_ui; w1.out[0] = Wt1[0];
    w1.in[1] = wr1_ui; w1.out[1] = Wt1[1];
    w1.in[2] = wl1_iu; w1.out[2] = Wt1[2];
    w1.in[3] = wr1_iu; w1.out[3] = Wt1[3];
    dim3 g1(HH / 32, DD / 32, 4);  // [D,H] -> [H,D]
    twconv_batch_k<<<g1, 256, 0, stream>>>(w1, DD, HH);
    WBatch w2;
    w2.in[0] = wr2_ui; w2.out[0] = Wcat_item;                    // z_item part
    w2.in[1] = wl2_iu; w2.out[1] = Wcat_item + (size_t)OO * HH;  // t_item part
    w2.in[2] = wr2_iu; w2.out[2] = Wcat_user;                    // z_user part
    w2.in[3] = wl2_ui; w2.out[3] = Wcat_user + (size_t)OO * HH;  // t_user part
    dim3 g2(OO / 32, HH / 32, 4);  // [H,O] -> [O,H]
    twconv_batch_k<<<g2, 256, 0, stream>>>(w2, HH, OO);
  }

  const int nbMax = ((NU > NI ? NU : NI) * 64 + 255) / 256;
  const int nbi = (NI + 127) / 128, nbu = (NU + 127) / 128;

  // ---- layer 1 gather-mean (paired) ----
  {
    GatherJob gi = { row_i, csr_i, xb_user, agg_i, NI };
    GatherJob gu = { row_u, csr_u, xb_item, agg_u, NU };
    gather_mean16_k<false><<<dim3(nbMax, 2), 256, 0, stream>>>(gi, gu);
  }

  // ---- FUSED GEMM: h in LDS; writes z (biased) and t ----
  {
    FJob ji = { NI, agg_i, xb_item, Wt1[0], Wt1[1], b1_ui, Wcat_item, b2_ui, z_item, t_item };
    FJob ju = { NU, agg_u, xb_user, Wt1[2], Wt1[3], b1_iu, Wcat_user, b2_iu, z_user, t_user };
    fused_gemm_k<<<nbi + nbu, 512, 0, stream>>>(ji, ju, nbi);
  }

  // ---- layer 2 gather-add: z += mean(t[nbrs]) ----
  {
    GatherJob gi = { row_i, csr_i, t_user, z_item, NI };
    GatherJob gu = { row_u, csr_u, t_item, z_user, NU };
    gather_mean16_k<true><<<dim3(nbMax, 2), 256, 0, stream>>>(gi, gu);
  }

  // ---- decode ----
  decode16_k<<<(int)(((long long)L * 16 + 255) / 256), 256, 0, stream>>>(lbl_src, lbl_dst, z_user, z_item, out, L);
}

// Round 13
// 396.769 us; speedup vs baseline: 1.2139x; 1.0009x over previous
//
#include <hip/hip_runtime.h>

#define DD 128   // input feature dim D
#define HH 256   // hidden dim H
#define OO 128   // output dim O

// CSR bucket config
#define NBI 256
#define NBU 512

typedef unsigned short bf16_t;
typedef short bf16x8 __attribute__((ext_vector_type(8)));   // 8 bf16 = 4 VGPRs
typedef float f32x4 __attribute__((ext_vector_type(4)));

__device__ __forceinline__ float bf2f(bf16_t u) {
  union { unsigned int i; float f; } v; v.i = ((unsigned int)u) << 16; return v.f;
}
__device__ __forceinline__ bf16_t f2bf(float f) {
  union { float f; unsigned int i; } v; v.f = f;
  unsigned int r = v.i + 0x7FFFu + ((v.i >> 16) & 1u);  // RNE
  return (bf16_t)(r >> 16);
}

__device__ __forceinline__ void acc8(float* acc, uint4 u) {
  const unsigned* p = (const unsigned*)&u;
#pragma unroll
  for (int i = 0; i < 4; ++i) {
    union { unsigned v; float f; } lo, hi;
    lo.v = p[i] << 16;
    hi.v = p[i] & 0xffff0000u;
    acc[2 * i] += lo.f;
    acc[2 * i + 1] += hi.f;
  }
}
__device__ __forceinline__ void unpack8(float* o, uint4 u) {
  const unsigned* p = (const unsigned*)&u;
#pragma unroll
  for (int i = 0; i < 4; ++i) {
    union { unsigned v; float f; } lo, hi;
    lo.v = p[i] << 16;
    hi.v = p[i] & 0xffff0000u;
    o[2 * i] = lo.f;
    o[2 * i + 1] = hi.f;
  }
}
__device__ __forceinline__ uint4 pack8(const float* v) {
  uint4 o; unsigned* p = (unsigned*)&o;
#pragma unroll
  for (int i = 0; i < 4; ++i)
    p[i] = (unsigned)f2bf(v[2 * i]) | ((unsigned)f2bf(v[2 * i + 1]) << 16);
  return o;
}

// ---------------------------------------------------------------------------
__global__ void probe_k(float* __restrict__ out, int n, float v) {
  int i = blockIdx.x * blockDim.x + threadIdx.x;
  if (i < n) out[i] = v;
}

// ---------------- CSR build (bucketed, no per-node global atomics) ----------
__global__ __launch_bounds__(256) void hist_k(
    const int* __restrict__ src, const int* __restrict__ dst,
    int* __restrict__ hist_u, int* __restrict__ hist_i,
    int E, int Wi, int Wu) {
  __shared__ int hi[NBI], hu[NBU];
  int tid = threadIdx.x;
  for (int t = tid; t < NBI; t += 256) hi[t] = 0;
  for (int t = tid; t < NBU; t += 256) hu[t] = 0;
  __syncthreads();
  int base = blockIdx.x * 4096;
#pragma unroll
  for (int j = 0; j < 16; ++j) {
    int e = base + tid + j * 256;
    if (e < E) {
      atomicAdd(&hi[dst[e] / Wi], 1);
      atomicAdd(&hu[src[e] / Wu], 1);
    }
  }
  __syncthreads();
  for (int t = tid; t < NBI; t += 256) if (hi[t]) atomicAdd(hist_i + t, hi[t]);
  for (int t = tid; t < NBU; t += 256) if (hu[t]) atomicAdd(hist_u + t, hu[t]);
}

__global__ __launch_bounds__(512) void scan_small_pair_k(
    const int* __restrict__ hist_i, int* __restrict__ off_i, int* __restrict__ cur_i,
    const int* __restrict__ hist_u, int* __restrict__ off_u, int* __restrict__ cur_u) {
  __shared__ int lds[512];
  const int* hist = blockIdx.x ? hist_u : hist_i;
  int* off = blockIdx.x ? off_u : off_i;
  int* cur = blockIdx.x ? cur_u : cur_i;
  int n = blockIdx.x ? NBU : NBI;
  int t = threadIdx.x;
  int v = (t < n) ? hist[t] : 0;
  lds[t] = v; __syncthreads();
  for (int o = 1; o < 512; o <<= 1) {
    int tv = (t >= o) ? lds[t - o] : 0;
    __syncthreads(); lds[t] += tv; __syncthreads();
  }
  if (t < n) { int e = lds[t] - v; off[t] = e; cur[t] = e; }
}

__global__ __launch_bounds__(256) void bucket_append_k(
    const int* __restrict__ src, const int* __restrict__ dst, int E, int Wi, int Wu,
    int* __restrict__ cur_bi, int* __restrict__ cur_bu,
    unsigned int* __restrict__ ebuf_i, unsigned int* __restrict__ ebuf_u) {
  __shared__ int bi[NBI], bu[NBU];
  __shared__ uint2 es[4096];
  int tid = threadIdx.x;
  int base = blockIdx.x * 4096;
  int n = E - base; if (n > 4096) n = 4096;
  for (int t = tid; t < NBI; t += 256) bi[t] = 0;
  for (int t = tid; t < NBU; t += 256) bu[t] = 0;
  __syncthreads();
#pragma unroll
  for (int j = 0; j < 16; ++j) {
    int idx = tid + j * 256;
    if (idx < n) {
      int s = src[base + idx], d = dst[base + idx];
      es[idx] = make_uint2((unsigned)s, (unsigned)d);
      atomicAdd(&bi[d / Wi], 1);
      atomicAdd(&bu[s / Wu], 1);
    }
  }
  __syncthreads();
  for (int t = tid; t < NBI; t += 256) { int c = bi[t]; bi[t] = c ? atomicAdd(cur_bi + t, c) : 0; }
  for (int t = tid; t < NBU; t += 256) { int c = bu[t]; bu[t] = c ? atomicAdd(cur_bu + t, c) : 0; }
  __syncthreads();
#pragma unroll
  for (int j = 0; j < 16; ++j) {
    int idx = tid + j * 256;
    if (idx < n) {
      int s = (int)es[idx].x, d = (int)es[idx].y;
      int bI = d / Wi, bU = s / Wu;
      int pI = atomicAdd(&bi[bI], 1);
      int pU = atomicAdd(&bu[bU], 1);
      ebuf_i[pI] = ((unsigned)(d - bI * Wi) << 24) | (unsigned)s;
      ebuf_u[pU] = ((unsigned)(s - bU * Wu) << 24) | (unsigned)d;
    }
  }
}

__global__ __launch_bounds__(256) void bucket_fill2_k(
    const unsigned int* __restrict__ ebuf, const int* __restrict__ off,
    const int* __restrict__ endc, int* __restrict__ row,
    int* __restrict__ csr, int n, int W, int E) {
  int b = blockIdx.x;
  int d0 = b * W; if (d0 >= n) return;
  int cnt = n - d0; if (cnt > W) cnt = W;
  __shared__ int hist[320];
  __shared__ int cur[320];
  int tid = threadIdx.x;
  for (int t = tid; t < cnt; t += 256) hist[t] = 0;
  __syncthreads();
  int beg = off[b], e_end = endc[b];
  for (int e = beg + tid; e < e_end; e += 256)
    atomicAdd(&hist[ebuf[e] >> 24], 1);
  __syncthreads();
  if (tid < 64) {
    int lane = tid;
    int carry = beg;
    int nc = (cnt + 63) >> 6;
    for (int c = 0; c < nc; ++c) {
      int idx = (c << 6) + lane;
      int v = (idx < cnt) ? hist[idx] : 0;
      int x = v;
#pragma unroll
      for (int o = 1; o < 64; o <<= 1) { int t = __shfl_up(x, o); if (lane >= o) x += t; }
      if (idx < cnt) { int g = carry + x - v; row[d0 + idx] = g; cur[idx] = g; }
      carry += __shfl(x, 63);
    }
  }
  if (tid == 0 && d0 + cnt == n) row[n] = E;
  __syncthreads();
  for (int e = beg + tid; e < e_end; e += 256) {
    unsigned v = ebuf[e];
    int slot = atomicAdd(&cur[v >> 24], 1);
    csr[slot] = (int)(v & 0xFFFFFFu);
  }
}

// ---------------- dtype prep ----------------
__global__ void cvt_bf16_k(const float* __restrict__ in, bf16_t* __restrict__ out, int n4) {
  int i = blockIdx.x * blockDim.x + threadIdx.x;
  if (i < n4) {
    float4 v = ((const float4*)in)[i];
    ushort4 o; o.x = f2bf(v.x); o.y = f2bf(v.y); o.z = f2bf(v.z); o.w = f2bf(v.w);
    ((ushort4*)out)[i] = o;
  }
}

struct WBatch { const float* in[4]; bf16_t* out[4]; };
__global__ void twconv_batch_k(WBatch wb, int K, int N) {
  const float* __restrict__ in = wb.in[blockIdx.z];
  bf16_t* __restrict__ out = wb.out[blockIdx.z];
  __shared__ float t[32][33];
  int bx = blockIdx.x * 32, by = blockIdx.y * 32;
  int tx = threadIdx.x & 31, ty = threadIdx.x >> 5;  // 32x8
#pragma unroll
  for (int j = 0; j < 32; j += 8)
    t[ty + j][tx] = in[(size_t)(by + ty + j) * N + bx + tx];
  __syncthreads();
#pragma unroll
  for (int j = 0; j < 32; j += 8)
    out[(size_t)(bx + ty + j) * K + by + tx] = f2bf(t[tx][ty + j]);
}

// ---------------- gather-mean, D=128, 16 lanes/row, paired jobs ------------
struct GatherJob {
  const int* row; const int* csr;
  const bf16_t* X; bf16_t* agg; int n;
};

template<bool ADD>
__global__ void gather_mean16_k(GatherJob j0, GatherJob j1) {
  GatherJob j = blockIdx.y ? j1 : j0;
  int node = (int)(((long long)blockIdx.x * blockDim.x + threadIdx.x) >> 6);
  int lane = threadIdx.x & 63;
  if (node >= j.n) return;
  const int g = lane >> 4;
  const int l = lane & 15;
  int beg = j.row[node], end = j.row[node + 1];
  float acc[8] = {};
  for (int jj = beg; jj < end; jj += 64) {
    int cnt = min(64, end - jj);
    int my = (lane < cnt) ? j.csr[jj + lane] : 0;
    for (int k = 0; k < cnt; k += 4) {
      int idx = __shfl(my, k + g);
      if (k + g < cnt) {
        uint4 u = *(const uint4*)(j.X + (size_t)idx * 128 + l * 8);
        acc8(acc, u);
      }
    }
  }
#pragma unroll
  for (int m = 16; m < 64; m <<= 1)
#pragma unroll
    for (int i = 0; i < 8; ++i) acc[i] += __shfl_xor(acc[i], m);
  if (g == 0) {
    float inv = (end > beg) ? 1.0f / (float)(end - beg) : 0.0f;
    float v[8];
    if (ADD) {
      uint4 z = *(const uint4*)(j.agg + (size_t)node * 128 + l * 8);
      float zb[8]; unpack8(zb, z);
#pragma unroll
      for (int i = 0; i < 8; ++i) v[i] = acc[i] * inv + zb[i];
    } else {
#pragma unroll
      for (int i = 0; i < 8; ++i) v[i] = acc[i] * inv;
    }
    *(uint4*)(j.agg + (size_t)node * 128 + l * 8) = pack8(v);
  }
}

// ---------------- FUSED two-layer MFMA GEMM (64KB LDS: H overlays A) --------
// Per 128-row node block:
//   h[128x256] = relu(agg@W1 + xb@W2 + b1)   (K=128, h kept in LDS bf16)
//   z|t[128x256] = h @ Wc (+b2 on z half)    (K=256)
// LDS: union U[64KB]. A-tiles (Aag 32K | Axb 32K) live during phase 1;
// H (64K) overlays them after a barrier. 2 blocks/CU -> cross-block overlap.
struct FJob {
  int M;
  const bf16_t* Aagg; const bf16_t* Axb;
  const bf16_t* W1; const bf16_t* W2;    // [256][128] row-major (^T)
  const float* b1;
  const bf16_t* Wc;                      // [256][256] row-major (^T), z|t concat
  const float* b2;
  bf16_t* Cz; bf16_t* Ct;
};

__global__ __launch_bounds__(512) void fused_gemm_k(FJob j0, FJob j1, int nbi) {
  const int bx = blockIdx.x;
  FJob j = (bx < nbi) ? j0 : j1;
  const int rb = (bx < nbi) ? bx : bx - nbi;
  const size_t row0 = (size_t)rb * 128;
  __shared__ __align__(16) bf16_t U[128 * 256];     // 64KB union
  bf16_t* Aag = U;                                   // 128*128 (32KB)
  bf16_t* Axb = U + 128 * 128;                       // 128*128 (32KB)
  bf16_t* Hls = U;                                   // 128*256 (64KB), overlays A
  const int tid = threadIdx.x;
  const int wave = tid >> 6, lane = tid & 63;
  const int wr = wave >> 2, wc = wave & 3;          // 2x4 waves
  const int l15 = lane & 15, l4 = lane >> 4;
  const int M = j.M;

  // ---- stage A tiles (one drain) ----
#pragma unroll
  for (int jj = 0; jj < 4; ++jj) {
    int i = tid + jj * 512;            // 16B slot 0..2047
    int r = i >> 4, c = i & 15;
    size_t ar = row0 + r; if (ar >= (size_t)M) ar = M - 1;
    int cs = c ^ (r & 7);              // pre-swizzled source chunk
    __builtin_amdgcn_global_load_lds(
        (const __attribute__((address_space(1))) void*)(j.Aagg + ar * 128 + cs * 8),
        (__attribute__((address_space(3))) void*)(Aag + i * 8), 16, 0, 0);
    __builtin_amdgcn_global_load_lds(
        (const __attribute__((address_space(1))) void*)(j.Axb + ar * 128 + cs * 8),
        (__attribute__((address_space(3))) void*)(Axb + i * 8), 16, 0, 0);
  }
  __syncthreads();

  f32x4 acc[4][4] = {};

  // ---- phase 1: h = relu(agg@W1 + xb@W2 + b1) ----
#pragma unroll
  for (int kk = 0; kk < 4; ++kk) {     // K = 128
    bf16x8 aa[4], ax[4], bl[4], br[4];
#pragma unroll
    for (int mi = 0; mi < 4; ++mi) {
      int ra = wr * 64 + mi * 16 + l15;
      int ch = (kk * 4 + l4) ^ (ra & 7);
      aa[mi] = *(const bf16x8*)(Aag + ra * 128 + ch * 8);
      ax[mi] = *(const bf16x8*)(Axb + ra * 128 + ch * 8);
    }
#pragma unroll
    for (int ni = 0; ni < 4; ++ni) {
      int c1 = wc * 64 + ni * 16 + l15;
      bl[ni] = *(const bf16x8*)(j.W1 + (size_t)c1 * 128 + kk * 32 + l4 * 8);
      br[ni] = *(const bf16x8*)(j.W2 + (size_t)c1 * 128 + kk * 32 + l4 * 8);
    }
#pragma unroll
    for (int mi = 0; mi < 4; ++mi)
#pragma unroll
      for (int ni = 0; ni < 4; ++ni)
        acc[mi][ni] = __builtin_amdgcn_mfma_f32_16x16x32_bf16(aa[mi], bl[ni], acc[mi][ni], 0, 0, 0);
#pragma unroll
    for (int mi = 0; mi < 4; ++mi)
#pragma unroll
      for (int ni = 0; ni < 4; ++ni)
        acc[mi][ni] = __builtin_amdgcn_mfma_f32_16x16x32_bf16(ax[mi], br[ni], acc[mi][ni], 0, 0, 0);
  }
  __syncthreads();   // all phase-1 LDS reads done before H overlays A

  // h epilogue -> LDS (chunk-swizzled rows)
#pragma unroll
  for (int ni = 0; ni < 4; ++ni) {
    int col = wc * 64 + ni * 16 + l15;
    float b = j.b1[col];
#pragma unroll
    for (int mi = 0; mi < 4; ++mi)
#pragma unroll
      for (int q = 0; q < 4; ++q) {
        int r = wr * 64 + mi * 16 + l4 * 4 + q;
        float v = fmaxf(acc[mi][ni][q] + b, 0.f);
        Hls[r * 256 + (((col >> 3) ^ (r & 7)) << 3) + (col & 7)] = f2bf(v);
      }
  }
  __syncthreads();

  // ---- phase 2: z|t = h @ Wc ----
#pragma unroll
  for (int mi = 0; mi < 4; ++mi)
#pragma unroll
    for (int ni = 0; ni < 4; ++ni)
#pragma unroll
      for (int q = 0; q < 4; ++q) acc[mi][ni][q] = 0.f;

#pragma unroll
  for (int kk = 0; kk < 8; ++kk) {     // K = 256
    bf16x8 ah[4], bw[4];
#pragma unroll
    for (int mi = 0; mi < 4; ++mi) {
      int r2 = wr * 64 + mi * 16 + l15;
      int ch = (kk * 4 + l4) ^ (r2 & 7);
      ah[mi] = *(const bf16x8*)(Hls + r2 * 256 + ch * 8);
    }
#pragma unroll
    for (int ni = 0; ni < 4; ++ni) {
      int c2 = wc * 64 + ni * 16 + l15;
      bw[ni] = *(const bf16x8*)(j.Wc + (size_t)c2 * 256 + kk * 32 + l4 * 8);
    }
#pragma unroll
    for (int mi = 0; mi < 4; ++mi)
#pragma unroll
      for (int ni = 0; ni < 4; ++ni)
        acc[mi][ni] = __builtin_amdgcn_mfma_f32_16x16x32_bf16(ah[mi], bw[ni], acc[mi][ni], 0, 0, 0);
  }

  // ---- store z (cols 0..127, +bias) and t (cols 128..255) ----
#pragma unroll
  for (int ni = 0; ni < 4; ++ni) {
    int c2 = wc * 64 + ni * 16 + l15;
    bf16_t* Co; int cc; float bb;
    if (c2 < 128) { Co = j.Cz; cc = c2; bb = j.b2[cc]; }
    else          { Co = j.Ct; cc = c2 - 128; bb = 0.f; }
#pragma unroll
    for (int mi = 0; mi < 4; ++mi)
#pragma unroll
      for (int q = 0; q < 4; ++q) {
        size_t r = row0 + wr * 64 + mi * 16 + l4 * 4 + q;
        if (r < (size_t)M) Co[r * 128 + cc] = f2bf(acc[mi][ni][q] + bb);
      }
  }
}

// ---------------- decode: 16 lanes/label, 16B loads ----------------
__global__ void decode16_k(const int* __restrict__ ls, const int* __restrict__ ld,
                           const bf16_t* __restrict__ zu, const bf16_t* __restrict__ zi,
                           float* __restrict__ out, int L) {
  long long gid = (long long)blockIdx.x * blockDim.x + threadIdx.x;
  int w = (int)(gid >> 4);
  int l = (int)(gid & 15);
  if (w >= L) return;
  int su = ls[w], si = ld[w];
  uint4 a = *(const uint4*)(zu + (size_t)su * OO + l * 8);
  uint4 b = *(const uint4*)(zi + (size_t)si * OO + l * 8);
  const unsigned* pa = (const unsigned*)&a;
  const unsigned* pb = (const unsigned*)&b;
  float sum = 0.f;
#pragma unroll
  for (int i = 0; i < 4; ++i) {
    union { unsigned v; float f; } la, ha, lb, hb;
    la.v = pa[i] << 16;        ha.v = pa[i] & 0xffff0000u;
    lb.v = pb[i] << 16;        hb.v = pb[i] & 0xffff0000u;
    sum += la.f * lb.f + ha.f * hb.f;
  }
#pragma unroll
  for (int m = 1; m < 16; m <<= 1) sum += __shfl_xor(sum, m);
  if (l == 0) out[w] = sum;
}

// ---------------------------------------------------------------------------
extern "C" void kernel_launch(void* const* d_in, const int* in_sizes, int n_in,
                              void* d_out, int out_size, void* d_ws, size_t ws_size,
                              hipStream_t stream) {
  const float* x_user = (const float*)d_in[0];
  const float* x_item = (const float*)d_in[1];
  const int* edge_src = (const int*)d_in[2];
  const int* edge_dst = (const int*)d_in[3];
  const int* lbl_src  = (const int*)d_in[4];
  const int* lbl_dst  = (const int*)d_in[5];
  const float* wl1_ui = (const float*)d_in[6];
  const float* wr1_ui = (const float*)d_in[7];
  const float* b1_ui  = (const float*)d_in[8];
  const float* wl1_iu = (const float*)d_in[9];
  const float* wr1_iu = (const float*)d_in[10];
  const float* b1_iu  = (const float*)d_in[11];
  const float* wl2_ui = (const float*)d_in[12];
  const float* wr2_ui = (const float*)d_in[13];
  const float* b2_ui  = (const float*)d_in[14];
  const float* wl2_iu = (const float*)d_in[15];
  const float* wr2_iu = (const float*)d_in[16];
  const float* b2_iu  = (const float*)d_in[17];

  const int NU = in_sizes[0] / DD;
  const int NI = in_sizes[1] / DD;
  const int E  = in_sizes[2];
  const int L  = in_sizes[4];
  const int Wi = (NI + NBI - 1) / NBI;
  const int Wu = (NU + NBU - 1) / NBU;
  const int nEB = (E + 4095) / 4096;

  // ---- workspace layout ----
  size_t off = 0;
  auto take = [&](size_t bytes) { size_t o = off; off = (off + bytes + 255) & ~(size_t)255; return o; };
  char* base = (char*)d_ws;
  int* hist_i = (int*)(base + take(((size_t)NBI + NBU) * 4));  // zeroed together
  int* hist_u = hist_i + NBI;
  size_t zeroB = ((size_t)NBI + NBU) * 4;
  int* row_i = (int*)(base + take((size_t)(NI + 1) * 4));
  int* row_u = (int*)(base + take((size_t)(NU + 1) * 4));
  int* off_i = (int*)(base + take((size_t)NBI * 4));
  int* off_u = (int*)(base + take((size_t)NBU * 4));
  int* cur_bi = (int*)(base + take((size_t)NBI * 4));
  int* cur_bu = (int*)(base + take((size_t)NBU * 4));
  int* csr_i = (int*)(base + take((size_t)E * 4));
  int* csr_u = (int*)(base + take((size_t)E * 4));
  unsigned int* ebuf_i = (unsigned int*)(base + take((size_t)E * 4));
  unsigned int* ebuf_u = (unsigned int*)(base + take((size_t)E * 4));
  // pool holds agg + xb (all persistent through the fused GEMM)
  bf16_t* pool = (bf16_t*)(base + take((size_t)(NI + NU) * HH * 2));
  bf16_t* agg_i   = pool;                              // NI*DD
  bf16_t* agg_u   = agg_i + (size_t)NI * DD;           // NU*DD
  bf16_t* xb_item = agg_u + (size_t)NU * DD;           // NI*DD
  bf16_t* xb_user = xb_item + (size_t)NI * DD;         // NU*DD
  // t is written by the fused kernel while agg/xb are still live -> separate
  bf16_t* t_user = (bf16_t*)(base + take((size_t)(NI + NU) * OO * 2));
  bf16_t* t_item = t_user + (size_t)NU * OO;
  bf16_t* z_item = (bf16_t*)(base + take((size_t)(NI + NU) * OO * 2));
  bf16_t* z_user = z_item + (size_t)NI * OO;
  bf16_t* Wt1[4];
  for (int w = 0; w < 4; ++w) Wt1[w] = (bf16_t*)(base + take((size_t)HH * DD * 2));
  bf16_t* Wcat_item = (bf16_t*)(base + take((size_t)2 * OO * HH * 2));
  bf16_t* Wcat_user = (bf16_t*)(base + take((size_t)2 * OO * HH * 2));
  size_t need = off;

  float* out = (float*)d_out;
  if (ws_size < need || Wi > 320 || Wu > 320) {
    probe_k<<<(L + 255) / 256, 256, 0, stream>>>(out, L, (float)(ws_size >> 20));
    return;
  }

  // ---- CSR build ----
  hipMemsetAsync(hist_i, 0, zeroB, stream);
  hist_k<<<nEB, 256, 0, stream>>>(edge_src, edge_dst, hist_u, hist_i, E, Wi, Wu);
  scan_small_pair_k<<<2, 512, 0, stream>>>(hist_i, off_i, cur_bi, hist_u, off_u, cur_bu);
  bucket_append_k<<<nEB, 256, 0, stream>>>(edge_src, edge_dst, E, Wi, Wu, cur_bi, cur_bu, ebuf_i, ebuf_u);
  bucket_fill2_k<<<NBI, 256, 0, stream>>>(ebuf_i, off_i, cur_bi, row_i, csr_i, NI, Wi, E);
  bucket_fill2_k<<<NBU, 256, 0, stream>>>(ebuf_u, off_u, cur_bu, row_u, csr_u, NU, Wu, E);

  // ---- dtype prep ----
  cvt_bf16_k<<<(NI * DD / 4 + 255) / 256, 256, 0, stream>>>(x_item, xb_item, NI * DD / 4);
  cvt_bf16_k<<<(NU * DD / 4 + 255) / 256, 256, 0, stream>>>(x_user, xb_user, NU * DD / 4);
  {
    WBatch w1;
    w1.in[0] = wl1_ui; w1.out[0] = Wt1[0];
    w1.in[1] = wr1_ui; w1.out[1] = Wt1[1];
    w1.in[2] = wl1_iu; w1.out[2] = Wt1[2];
    w1.in[3] = wr1_iu; w1.out[3] = Wt1[3];
    dim3 g1(HH / 32, DD / 32, 4);  // [D,H] -> [H,D]
    twconv_batch_k<<<g1, 256, 0, stream>>>(w1, DD, HH);
    WBatch w2;
    w2.in[0] = wr2_ui; w2.out[0] = Wcat_item;                    // z_item part
    w2.in[1] = wl2_iu; w2.out[1] = Wcat_item + (size_t)OO * HH;  // t_item part
    w2.in[2] = wr2_iu; w2.out[2] = Wcat_user;                    // z_user part
    w2.in[3] = wl2_ui; w2.out[3] = Wcat_user + (size_t)OO * HH;  // t_user part
    dim3 g2(OO / 32, HH / 32, 4);  // [H,O] -> [O,H]
    twconv_batch_k<<<g2, 256, 0, stream>>>(w2, HH, OO);
  }

  const int nbMax = ((NU > NI ? NU : NI) * 64 + 255) / 256;
  const int nbi = (NI + 127) / 128, nbu = (NU + 127) / 128;

  // ---- layer 1 gather-mean (paired) ----
  {
    GatherJob gi = { row_i, csr_i, xb_user, agg_i, NI };
    GatherJob gu = { row_u, csr_u, xb_item, agg_u, NU };
    gather_mean16_k<false><<<dim3(nbMax, 2), 256, 0, stream>>>(gi, gu);
  }

  // ---- FUSED GEMM: h in LDS (overlaying A); writes z (biased) and t ----
  {
    FJob ji = { NI, agg_i, xb_item, Wt1[0], Wt1[1], b1_ui, Wcat_item, b2_ui, z_item, t_item };
    FJob ju = { NU, agg_u, xb_user, Wt1[2], Wt1[3], b1_iu, Wcat_user, b2_iu, z_user, t_user };
    fused_gemm_k<<<nbi + nbu, 512, 0, stream>>>(ji, ju, nbi);
  }

  // ---- layer 2 gather-add: z += mean(t[nbrs]) ----
  {
    GatherJob gi = { row_i, csr_i, t_user, z_item, NI };
    GatherJob gu = { row_u, csr_u, t_item, z_user, NU };
    gather_mean16_k<true><<<dim3(nbMax, 2), 256, 0, stream>>>(gi, gu);
  }

  // ---- decode ----
  decode16_k<<<(int)(((long long)L * 16 + 255) / 256), 256, 0, stream>>>(lbl_src, lbl_dst, z_user, z_item, out, L);
}

// Round 14
// 358.074 us; speedup vs baseline: 1.3451x; 1.1081x over previous
//
#include <hip/hip_runtime.h>

#define DD 128   // input feature dim D
#define HH 256   // hidden dim H
#define OO 128   // output dim O

// CSR bucket config
#define NBI 256
#define NBU 512

typedef unsigned short bf16_t;
typedef short bf16x8 __attribute__((ext_vector_type(8)));   // 8 bf16 = 4 VGPRs
typedef float f32x4 __attribute__((ext_vector_type(4)));

__device__ __forceinline__ float bf2f(bf16_t u) {
  union { unsigned int i; float f; } v; v.i = ((unsigned int)u) << 16; return v.f;
}
__device__ __forceinline__ bf16_t f2bf(float f) {
  union { float f; unsigned int i; } v; v.f = f;
  unsigned int r = v.i + 0x7FFFu + ((v.i >> 16) & 1u);  // RNE
  return (bf16_t)(r >> 16);
}

__device__ __forceinline__ void acc8(float* acc, uint4 u) {
  const unsigned* p = (const unsigned*)&u;
#pragma unroll
  for (int i = 0; i < 4; ++i) {
    union { unsigned v; float f; } lo, hi;
    lo.v = p[i] << 16;
    hi.v = p[i] & 0xffff0000u;
    acc[2 * i] += lo.f;
    acc[2 * i + 1] += hi.f;
  }
}
__device__ __forceinline__ void unpack8(float* o, uint4 u) {
  const unsigned* p = (const unsigned*)&u;
#pragma unroll
  for (int i = 0; i < 4; ++i) {
    union { unsigned v; float f; } lo, hi;
    lo.v = p[i] << 16;
    hi.v = p[i] & 0xffff0000u;
    o[2 * i] = lo.f;
    o[2 * i + 1] = hi.f;
  }
}
__device__ __forceinline__ uint4 pack8(const float* v) {
  uint4 o; unsigned* p = (unsigned*)&o;
#pragma unroll
  for (int i = 0; i < 4; ++i)
    p[i] = (unsigned)f2bf(v[2 * i]) | ((unsigned)f2bf(v[2 * i + 1]) << 16);
  return o;
}

// ---------------------------------------------------------------------------
__global__ void probe_k(float* __restrict__ out, int n, float v) {
  int i = blockIdx.x * blockDim.x + threadIdx.x;
  if (i < n) out[i] = v;
}

// ---------------- CSR build (bucketed, no per-node global atomics) ----------
__global__ __launch_bounds__(256) void hist_k(
    const int* __restrict__ src, const int* __restrict__ dst,
    int* __restrict__ hist_u, int* __restrict__ hist_i,
    int E, int Wi, int Wu) {
  __shared__ int hi[NBI], hu[NBU];
  int tid = threadIdx.x;
  for (int t = tid; t < NBI; t += 256) hi[t] = 0;
  for (int t = tid; t < NBU; t += 256) hu[t] = 0;
  __syncthreads();
  int base = blockIdx.x * 4096;
#pragma unroll
  for (int j = 0; j < 16; ++j) {
    int e = base + tid + j * 256;
    if (e < E) {
      atomicAdd(&hi[dst[e] / Wi], 1);
      atomicAdd(&hu[src[e] / Wu], 1);
    }
  }
  __syncthreads();
  for (int t = tid; t < NBI; t += 256) if (hi[t]) atomicAdd(hist_i + t, hi[t]);
  for (int t = tid; t < NBU; t += 256) if (hu[t]) atomicAdd(hist_u + t, hu[t]);
}

__global__ __launch_bounds__(512) void scan_small_pair_k(
    const int* __restrict__ hist_i, int* __restrict__ off_i, int* __restrict__ cur_i,
    const int* __restrict__ hist_u, int* __restrict__ off_u, int* __restrict__ cur_u) {
  __shared__ int lds[512];
  const int* hist = blockIdx.x ? hist_u : hist_i;
  int* off = blockIdx.x ? off_u : off_i;
  int* cur = blockIdx.x ? cur_u : cur_i;
  int n = blockIdx.x ? NBU : NBI;
  int t = threadIdx.x;
  int v = (t < n) ? hist[t] : 0;
  lds[t] = v; __syncthreads();
  for (int o = 1; o < 512; o <<= 1) {
    int tv = (t >= o) ? lds[t - o] : 0;
    __syncthreads(); lds[t] += tv; __syncthreads();
  }
  if (t < n) { int e = lds[t] - v; off[t] = e; cur[t] = e; }
}

__global__ __launch_bounds__(256) void bucket_append_k(
    const int* __restrict__ src, const int* __restrict__ dst, int E, int Wi, int Wu,
    int* __restrict__ cur_bi, int* __restrict__ cur_bu,
    unsigned int* __restrict__ ebuf_i, unsigned int* __restrict__ ebuf_u) {
  __shared__ int bi[NBI], bu[NBU];
  __shared__ uint2 es[4096];
  int tid = threadIdx.x;
  int base = blockIdx.x * 4096;
  int n = E - base; if (n > 4096) n = 4096;
  for (int t = tid; t < NBI; t += 256) bi[t] = 0;
  for (int t = tid; t < NBU; t += 256) bu[t] = 0;
  __syncthreads();
#pragma unroll
  for (int j = 0; j < 16; ++j) {
    int idx = tid + j * 256;
    if (idx < n) {
      int s = src[base + idx], d = dst[base + idx];
      es[idx] = make_uint2((unsigned)s, (unsigned)d);
      atomicAdd(&bi[d / Wi], 1);
      atomicAdd(&bu[s / Wu], 1);
    }
  }
  __syncthreads();
  for (int t = tid; t < NBI; t += 256) { int c = bi[t]; bi[t] = c ? atomicAdd(cur_bi + t, c) : 0; }
  for (int t = tid; t < NBU; t += 256) { int c = bu[t]; bu[t] = c ? atomicAdd(cur_bu + t, c) : 0; }
  __syncthreads();
#pragma unroll
  for (int j = 0; j < 16; ++j) {
    int idx = tid + j * 256;
    if (idx < n) {
      int s = (int)es[idx].x, d = (int)es[idx].y;
      int bI = d / Wi, bU = s / Wu;
      int pI = atomicAdd(&bi[bI], 1);
      int pU = atomicAdd(&bu[bU], 1);
      ebuf_i[pI] = ((unsigned)(d - bI * Wi) << 24) | (unsigned)s;
      ebuf_u[pU] = ((unsigned)(s - bU * Wu) << 24) | (unsigned)d;
    }
  }
}

__global__ __launch_bounds__(256) void bucket_fill2_k(
    const unsigned int* __restrict__ ebuf, const int* __restrict__ off,
    const int* __restrict__ endc, int* __restrict__ row,
    int* __restrict__ csr, int n, int W, int E) {
  int b = blockIdx.x;
  int d0 = b * W; if (d0 >= n) return;
  int cnt = n - d0; if (cnt > W) cnt = W;
  __shared__ int hist[320];
  __shared__ int cur[320];
  int tid = threadIdx.x;
  for (int t = tid; t < cnt; t += 256) hist[t] = 0;
  __syncthreads();
  int beg = off[b], e_end = endc[b];
  for (int e = beg + tid; e < e_end; e += 256)
    atomicAdd(&hist[ebuf[e] >> 24], 1);
  __syncthreads();
  if (tid < 64) {
    int lane = tid;
    int carry = beg;
    int nc = (cnt + 63) >> 6;
    for (int c = 0; c < nc; ++c) {
      int idx = (c << 6) + lane;
      int v = (idx < cnt) ? hist[idx] : 0;
      int x = v;
#pragma unroll
      for (int o = 1; o < 64; o <<= 1) { int t = __shfl_up(x, o); if (lane >= o) x += t; }
      if (idx < cnt) { int g = carry + x - v; row[d0 + idx] = g; cur[idx] = g; }
      carry += __shfl(x, 63);
    }
  }
  if (tid == 0 && d0 + cnt == n) row[n] = E;
  __syncthreads();
  for (int e = beg + tid; e < e_end; e += 256) {
    unsigned v = ebuf[e];
    int slot = atomicAdd(&cur[v >> 24], 1);
    csr[slot] = (int)(v & 0xFFFFFFu);
  }
}

// ---------------- dtype prep ----------------
__global__ void cvt_bf16_k(const float* __restrict__ in, bf16_t* __restrict__ out, int n4) {
  int i = blockIdx.x * blockDim.x + threadIdx.x;
  if (i < n4) {
    float4 v = ((const float4*)in)[i];
    ushort4 o; o.x = f2bf(v.x); o.y = f2bf(v.y); o.z = f2bf(v.z); o.w = f2bf(v.w);
    ((ushort4*)out)[i] = o;
  }
}

struct WBatch { const float* in[4]; bf16_t* out[4]; };
__global__ void twconv_batch_k(WBatch wb, int K, int N) {
  const float* __restrict__ in = wb.in[blockIdx.z];
  bf16_t* __restrict__ out = wb.out[blockIdx.z];
  __shared__ float t[32][33];
  int bx = blockIdx.x * 32, by = blockIdx.y * 32;
  int tx = threadIdx.x & 31, ty = threadIdx.x >> 5;  // 32x8
#pragma unroll
  for (int j = 0; j < 32; j += 8)
    t[ty + j][tx] = in[(size_t)(by + ty + j) * N + bx + tx];
  __syncthreads();
#pragma unroll
  for (int j = 0; j < 32; j += 8)
    out[(size_t)(bx + ty + j) * K + by + tx] = f2bf(t[tx][ty + j]);
}

// ---------------- gather-mean, D=128, 16 lanes/row, paired jobs ------------
struct GatherJob {
  const int* row; const int* csr;
  const bf16_t* X; bf16_t* agg; int n;
};

template<bool ADD>
__global__ void gather_mean16_k(GatherJob j0, GatherJob j1) {
  GatherJob j = blockIdx.y ? j1 : j0;
  int node = (int)(((long long)blockIdx.x * blockDim.x + threadIdx.x) >> 6);
  int lane = threadIdx.x & 63;
  if (node >= j.n) return;
  const int g = lane >> 4;
  const int l = lane & 15;
  int beg = j.row[node], end = j.row[node + 1];
  float acc[8] = {};
  for (int jj = beg; jj < end; jj += 64) {
    int cnt = min(64, end - jj);
    int my = (lane < cnt) ? j.csr[jj + lane] : 0;
    for (int k = 0; k < cnt; k += 4) {
      int idx = __shfl(my, k + g);
      if (k + g < cnt) {
        uint4 u = *(const uint4*)(j.X + (size_t)idx * 128 + l * 8);
        acc8(acc, u);
      }
    }
  }
#pragma unroll
  for (int m = 16; m < 64; m <<= 1)
#pragma unroll
    for (int i = 0; i < 8; ++i) acc[i] += __shfl_xor(acc[i], m);
  if (g == 0) {
    float inv = (end > beg) ? 1.0f / (float)(end - beg) : 0.0f;
    float v[8];
    if (ADD) {
      uint4 z = *(const uint4*)(j.agg + (size_t)node * 128 + l * 8);
      float zb[8]; unpack8(zb, z);
#pragma unroll
      for (int i = 0; i < 8; ++i) v[i] = acc[i] * inv + zb[i];
    } else {
#pragma unroll
      for (int i = 0; i < 8; ++i) v[i] = acc[i] * inv;
    }
    *(uint4*)(j.agg + (size_t)node * 128 + l * 8) = pack8(v);
  }
}

// ---------------- FUSED two-layer GEMM: M=64 tile, 4 waves, 32KB LDS --------
// Swapped-operand MFMA (acc holds Dᵀ fragment: lane = row l15, cols l4*4+q)
// -> packed 8B H-writes and fully-coalesced z|t stores via LDS bounce.
// LDS union: A tiles (16K+16K) -> H (32K) -> ZT bounce (32K).
struct FJob {
  int M;
  const bf16_t* Aagg; const bf16_t* Axb;
  const bf16_t* W1; const bf16_t* W2;    // [256][128] row-major (^T)
  const float* b1;
  const bf16_t* Wc;                      // [256][256] row-major (^T), z|t concat
  const float* b2;
  bf16_t* Cz; bf16_t* Ct;
};

__global__ __launch_bounds__(256) void fused_gemm_k(FJob j0, FJob j1, int nbi) {
  const int bx = blockIdx.x;
  FJob j = (bx < nbi) ? j0 : j1;
  const int rb = (bx < nbi) ? bx : bx - nbi;
  const size_t row0 = (size_t)rb * 64;
  __shared__ __align__(16) bf16_t U[64 * 256];      // 32KB union
  bf16_t* Aag = U;                                   // 64*128 (16KB)
  bf16_t* Axb = U + 64 * 128;                        // 64*128 (16KB)
  bf16_t* Hls = U;                                   // 64*256 (32KB) overlay
  char* Ub = (char*)U;
  const int tid = threadIdx.x;
  const int wave = tid >> 6, lane = tid & 63;
  const int wc = wave;                               // 4 waves over N=256
  const int l15 = lane & 15, l4 = lane >> 4;
  const int M = j.M;

  // ---- stage A tiles (one drain) ----
#pragma unroll
  for (int jj = 0; jj < 4; ++jj) {
    int i = tid + jj * 256;            // 16B slot 0..1023
    int r = i >> 4, c = i & 15;
    size_t ar = row0 + r; if (ar >= (size_t)M) ar = M - 1;
    int cs = c ^ (r & 7);              // pre-swizzled source chunk
    __builtin_amdgcn_global_load_lds(
        (const __attribute__((address_space(1))) void*)(j.Aagg + ar * 128 + cs * 8),
        (__attribute__((address_space(3))) void*)(Aag + i * 8), 16, 0, 0);
    __builtin_amdgcn_global_load_lds(
        (const __attribute__((address_space(1))) void*)(j.Axb + ar * 128 + cs * 8),
        (__attribute__((address_space(3))) void*)(Axb + i * 8), 16, 0, 0);
  }
  __syncthreads();

  f32x4 acc[4][4] = {};

  // ---- phase 1: h = relu(agg@W1 + xb@W2 + b1), swapped operands ----
#pragma unroll
  for (int kk = 0; kk < 4; ++kk) {     // K = 128
    bf16x8 aa[4], ax[4], bl[4], br[4];
#pragma unroll
    for (int mi = 0; mi < 4; ++mi) {
      int ra = mi * 16 + l15;
      int ch = (kk * 4 + l4) ^ (ra & 7);
      aa[mi] = *(const bf16x8*)(Aag + ra * 128 + ch * 8);
      ax[mi] = *(const bf16x8*)(Axb + ra * 128 + ch * 8);
    }
#pragma unroll
    for (int ni = 0; ni < 4; ++ni) {
      int c1 = wc * 64 + ni * 16 + l15;
      bl[ni] = *(const bf16x8*)(j.W1 + (size_t)c1 * 128 + kk * 32 + l4 * 8);
      br[ni] = *(const bf16x8*)(j.W2 + (size_t)c1 * 128 + kk * 32 + l4 * 8);
    }
#pragma unroll
    for (int mi = 0; mi < 4; ++mi)
#pragma unroll
      for (int ni = 0; ni < 4; ++ni)
        acc[mi][ni] = __builtin_amdgcn_mfma_f32_16x16x32_bf16(bl[ni], aa[mi], acc[mi][ni], 0, 0, 0);
#pragma unroll
    for (int mi = 0; mi < 4; ++mi)
#pragma unroll
      for (int ni = 0; ni < 4; ++ni)
        acc[mi][ni] = __builtin_amdgcn_mfma_f32_16x16x32_bf16(br[ni], ax[mi], acc[mi][ni], 0, 0, 0);
  }
  __syncthreads();   // all phase-1 A reads done before H overlays A

  // ---- H epilogue: packed 8B ds_writes (lane: row l15+mi*16, cols c0..c0+3)
#pragma unroll
  for (int ni = 0; ni < 4; ++ni) {
    int c0 = wc * 64 + ni * 16 + l4 * 4;
    float4 bv = *(const float4*)(j.b1 + c0);
    const float* bp = (const float*)&bv;
#pragma unroll
    for (int mi = 0; mi < 4; ++mi) {
      int r = mi * 16 + l15;
      float v0 = fmaxf(acc[mi][ni][0] + bp[0], 0.f);
      float v1 = fmaxf(acc[mi][ni][1] + bp[1], 0.f);
      float v2 = fmaxf(acc[mi][ni][2] + bp[2], 0.f);
      float v3 = fmaxf(acc[mi][ni][3] + bp[3], 0.f);
      unsigned w0 = (unsigned)f2bf(v0) | ((unsigned)f2bf(v1) << 16);
      unsigned w1 = (unsigned)f2bf(v2) | ((unsigned)f2bf(v3) << 16);
      int p8 = (c0 >> 2) ^ ((r & 7) << 1);   // 8B-chunk swizzle (16B-consistent)
      *(uint2*)(Ub + r * 512 + p8 * 8) = make_uint2(w0, w1);
    }
  }
  __syncthreads();

  // ---- phase 2: z|t = h @ Wc, swapped operands ----
#pragma unroll
  for (int mi = 0; mi < 4; ++mi)
#pragma unroll
    for (int ni = 0; ni < 4; ++ni)
#pragma unroll
      for (int q = 0; q < 4; ++q) acc[mi][ni][q] = 0.f;

#pragma unroll
  for (int kk = 0; kk < 8; ++kk) {     // K = 256
    bf16x8 ah[4], bw[4];
#pragma unroll
    for (int mi = 0; mi < 4; ++mi) {
      int r2 = mi * 16 + l15;
      int ch = (kk * 4 + l4) ^ (r2 & 7);
      ah[mi] = *(const bf16x8*)(Hls + r2 * 256 + ch * 8);
    }
#pragma unroll
    for (int ni = 0; ni < 4; ++ni) {
      int c2 = wc * 64 + ni * 16 + l15;
      bw[ni] = *(const bf16x8*)(j.Wc + (size_t)c2 * 256 + kk * 32 + l4 * 8);
    }
#pragma unroll
    for (int mi = 0; mi < 4; ++mi)
#pragma unroll
      for (int ni = 0; ni < 4; ++ni)
        acc[mi][ni] = __builtin_amdgcn_mfma_f32_16x16x32_bf16(bw[ni], ah[mi], acc[mi][ni], 0, 0, 0);
  }
  __syncthreads();   // all H reads done before ZT overlays H

  // ---- ZT epilogue -> LDS (packed 8B, swizzled), bias on z half ----
#pragma unroll
  for (int ni = 0; ni < 4; ++ni) {
    int c0 = wc * 64 + ni * 16 + l4 * 4;     // 0..255; <128 = z (+bias)
    float b0 = 0.f, b1v = 0.f, b2v = 0.f, b3v = 0.f;
    if (c0 < 128) {
      float4 bv = *(const float4*)(j.b2 + c0);
      b0 = bv.x; b1v = bv.y; b2v = bv.z; b3v = bv.w;
    }
#pragma unroll
    for (int mi = 0; mi < 4; ++mi) {
      int r = mi * 16 + l15;
      unsigned w0 = (unsigned)f2bf(acc[mi][ni][0] + b0) | ((unsigned)f2bf(acc[mi][ni][1] + b1v) << 16);
      unsigned w1 = (unsigned)f2bf(acc[mi][ni][2] + b2v) | ((unsigned)f2bf(acc[mi][ni][3] + b3v) << 16);
      int p8 = (c0 >> 2) ^ ((r & 7) << 1);
      *(uint2*)(Ub + r * 512 + p8 * 8) = make_uint2(w0, w1);
    }
  }
  __syncthreads();

  // ---- coalesced copy-out: 16B/lane row-major ----
#pragma unroll
  for (int p = 0; p < 8; ++p) {
    int s = tid + p * 256;               // 0..2047
    int r = s >> 5, c16 = s & 31;        // 64 rows x 32 16B-chunks
    size_t gr = row0 + r;
    if (gr < (size_t)M) {
      uint4 v = *(const uint4*)(Ub + r * 512 + (c16 ^ (r & 7)) * 16);
      if (c16 < 16) *(uint4*)(j.Cz + gr * 128 + c16 * 8) = v;
      else          *(uint4*)(j.Ct + gr * 128 + (c16 - 16) * 8) = v;
    }
  }
}

// ---------------- decode: 16 lanes/label, 16B loads ----------------
__global__ void decode16_k(const int* __restrict__ ls, const int* __restrict__ ld,
                           const bf16_t* __restrict__ zu, const bf16_t* __restrict__ zi,
                           float* __restrict__ out, int L) {
  long long gid = (long long)blockIdx.x * blockDim.x + threadIdx.x;
  int w = (int)(gid >> 4);
  int l = (int)(gid & 15);
  if (w >= L) return;
  int su = ls[w], si = ld[w];
  uint4 a = *(const uint4*)(zu + (size_t)su * OO + l * 8);
  uint4 b = *(const uint4*)(zi + (size_t)si * OO + l * 8);
  const unsigned* pa = (const unsigned*)&a;
  const unsigned* pb = (const unsigned*)&b;
  float sum = 0.f;
#pragma unroll
  for (int i = 0; i < 4; ++i) {
    union { unsigned v; float f; } la, ha, lb, hb;
    la.v = pa[i] << 16;        ha.v = pa[i] & 0xffff0000u;
    lb.v = pb[i] << 16;        hb.v = pb[i] & 0xffff0000u;
    sum += la.f * lb.f + ha.f * hb.f;
  }
#pragma unroll
  for (int m = 1; m < 16; m <<= 1) sum += __shfl_xor(sum, m);
  if (l == 0) out[w] = sum;
}

// ---------------------------------------------------------------------------
extern "C" void kernel_launch(void* const* d_in, const int* in_sizes, int n_in,
                              void* d_out, int out_size, void* d_ws, size_t ws_size,
                              hipStream_t stream) {
  const float* x_user = (const float*)d_in[0];
  const float* x_item = (const float*)d_in[1];
  const int* edge_src = (const int*)d_in[2];
  const int* edge_dst = (const int*)d_in[3];
  const int* lbl_src  = (const int*)d_in[4];
  const int* lbl_dst  = (const int*)d_in[5];
  const float* wl1_ui = (const float*)d_in[6];
  const float* wr1_ui = (const float*)d_in[7];
  const float* b1_ui  = (const float*)d_in[8];
  const float* wl1_iu = (const float*)d_in[9];
  const float* wr1_iu = (const float*)d_in[10];
  const float* b1_iu  = (const float*)d_in[11];
  const float* wl2_ui = (const float*)d_in[12];
  const float* wr2_ui = (const float*)d_in[13];
  const float* b2_ui  = (const float*)d_in[14];
  const float* wl2_iu = (const float*)d_in[15];
  const float* wr2_iu = (const float*)d_in[16];
  const float* b2_iu  = (const float*)d_in[17];

  const int NU = in_sizes[0] / DD;
  const int NI = in_sizes[1] / DD;
  const int E  = in_sizes[2];
  const int L  = in_sizes[4];
  const int Wi = (NI + NBI - 1) / NBI;
  const int Wu = (NU + NBU - 1) / NBU;
  const int nEB = (E + 4095) / 4096;

  // ---- workspace layout ----
  size_t off = 0;
  auto take = [&](size_t bytes) { size_t o = off; off = (off + bytes + 255) & ~(size_t)255; return o; };
  char* base = (char*)d_ws;
  int* hist_i = (int*)(base + take(((size_t)NBI + NBU) * 4));  // zeroed together
  int* hist_u = hist_i + NBI;
  size_t zeroB = ((size_t)NBI + NBU) * 4;
  int* row_i = (int*)(base + take((size_t)(NI + 1) * 4));
  int* row_u = (int*)(base + take((size_t)(NU + 1) * 4));
  int* off_i = (int*)(base + take((size_t)NBI * 4));
  int* off_u = (int*)(base + take((size_t)NBU * 4));
  int* cur_bi = (int*)(base + take((size_t)NBI * 4));
  int* cur_bu = (int*)(base + take((size_t)NBU * 4));
  int* csr_i = (int*)(base + take((size_t)E * 4));
  int* csr_u = (int*)(base + take((size_t)E * 4));
  unsigned int* ebuf_i = (unsigned int*)(base + take((size_t)E * 4));
  unsigned int* ebuf_u = (unsigned int*)(base + take((size_t)E * 4));
  // pool holds agg + xb (all persistent through the fused GEMM)
  bf16_t* pool = (bf16_t*)(base + take((size_t)(NI + NU) * HH * 2));
  bf16_t* agg_i   = pool;                              // NI*DD
  bf16_t* agg_u   = agg_i + (size_t)NI * DD;           // NU*DD
  bf16_t* xb_item = agg_u + (size_t)NU * DD;           // NI*DD
  bf16_t* xb_user = xb_item + (size_t)NI * DD;         // NU*DD
  // t is written by the fused kernel while agg/xb are still live -> separate
  bf16_t* t_user = (bf16_t*)(base + take((size_t)(NI + NU) * OO * 2));
  bf16_t* t_item = t_user + (size_t)NU * OO;
  bf16_t* z_item = (bf16_t*)(base + take((size_t)(NI + NU) * OO * 2));
  bf16_t* z_user = z_item + (size_t)NI * OO;
  bf16_t* Wt1[4];
  for (int w = 0; w < 4; ++w) Wt1[w] = (bf16_t*)(base + take((size_t)HH * DD * 2));
  bf16_t* Wcat_item = (bf16_t*)(base + take((size_t)2 * OO * HH * 2));
  bf16_t* Wcat_user = (bf16_t*)(base + take((size_t)2 * OO * HH * 2));
  size_t need = off;

  float* out = (float*)d_out;
  if (ws_size < need || Wi > 320 || Wu > 320) {
    probe_k<<<(L + 255) / 256, 256, 0, stream>>>(out, L, (float)(ws_size >> 20));
    return;
  }

  // ---- CSR build ----
  hipMemsetAsync(hist_i, 0, zeroB, stream);
  hist_k<<<nEB, 256, 0, stream>>>(edge_src, edge_dst, hist_u, hist_i, E, Wi, Wu);
  scan_small_pair_k<<<2, 512, 0, stream>>>(hist_i, off_i, cur_bi, hist_u, off_u, cur_bu);
  bucket_append_k<<<nEB, 256, 0, stream>>>(edge_src, edge_dst, E, Wi, Wu, cur_bi, cur_bu, ebuf_i, ebuf_u);
  bucket_fill2_k<<<NBI, 256, 0, stream>>>(ebuf_i, off_i, cur_bi, row_i, csr_i, NI, Wi, E);
  bucket_fill2_k<<<NBU, 256, 0, stream>>>(ebuf_u, off_u, cur_bu, row_u, csr_u, NU, Wu, E);

  // ---- dtype prep ----
  cvt_bf16_k<<<(NI * DD / 4 + 255) / 256, 256, 0, stream>>>(x_item, xb_item, NI * DD / 4);
  cvt_bf16_k<<<(NU * DD / 4 + 255) / 256, 256, 0, stream>>>(x_user, xb_user, NU * DD / 4);
  {
    WBatch w1;
    w1.in[0] = wl1_ui; w1.out[0] = Wt1[0];
    w1.in[1] = wr1_ui; w1.out[1] = Wt1[1];
    w1.in[2] = wl1_iu; w1.out[2] = Wt1[2];
    w1.in[3] = wr1_iu; w1.out[3] = Wt1[3];
    dim3 g1(HH / 32, DD / 32, 4);  // [D,H] -> [H,D]
    twconv_batch_k<<<g1, 256, 0, stream>>>(w1, DD, HH);
    WBatch w2;
    w2.in[0] = wr2_ui; w2.out[0] = Wcat_item;                    // z_item part
    w2.in[1] = wl2_iu; w2.out[1] = Wcat_item + (size_t)OO * HH;  // t_item part
    w2.in[2] = wr2_iu; w2.out[2] = Wcat_user;                    // z_user part
    w2.in[3] = wl2_ui; w2.out[3] = Wcat_user + (size_t)OO * HH;  // t_user part
    dim3 g2(OO / 32, HH / 32, 4);  // [H,O] -> [O,H]
    twconv_batch_k<<<g2, 256, 0, stream>>>(w2, HH, OO);
  }

  const int nbMax = ((NU > NI ? NU : NI) * 64 + 255) / 256;
  const int nbi64 = (NI + 63) / 64, nbu64 = (NU + 63) / 64;

  // ---- layer 1 gather-mean (paired) ----
  {
    GatherJob gi = { row_i, csr_i, xb_user, agg_i, NI };
    GatherJob gu = { row_u, csr_u, xb_item, agg_u, NU };
    gather_mean16_k<false><<<dim3(nbMax, 2), 256, 0, stream>>>(gi, gu);
  }

  // ---- FUSED GEMM (M=64 tiles, 4 waves, 32KB LDS) ----
  {
    FJob ji = { NI, agg_i, xb_item, Wt1[0], Wt1[1], b1_ui, Wcat_item, b2_ui, z_item, t_item };
    FJob ju = { NU, agg_u, xb_user, Wt1[2], Wt1[3], b1_iu, Wcat_user, b2_iu, z_user, t_user };
    fused_gemm_k<<<nbi64 + nbu64, 256, 0, stream>>>(ji, ju, nbi64);
  }

  // ---- layer 2 gather-add: z += mean(t[nbrs]) ----
  {
    GatherJob gi = { row_i, csr_i, t_user, z_item, NI };
    GatherJob gu = { row_u, csr_u, t_item, z_user, NU };
    gather_mean16_k<true><<<dim3(nbMax, 2), 256, 0, stream>>>(gi, gu);
  }

  // ---- decode ----
  decode16_k<<<(int)(((long long)L * 16 + 255) / 256), 256, 0, stream>>>(lbl_src, lbl_dst, z_user, z_item, out, L);
}

// Round 15
// 327.402 us; speedup vs baseline: 1.4711x; 1.0937x over previous
//
#include <hip/hip_runtime.h>

#define DD 128   // input feature dim D
#define HH 256   // hidden dim H
#define OO 128   // output dim O

// CSR bucket config
#define NBI 256
#define NBU 512

typedef unsigned short bf16_t;
typedef short bf16x8 __attribute__((ext_vector_type(8)));   // 8 bf16 = 4 VGPRs
typedef float f32x4 __attribute__((ext_vector_type(4)));

__device__ __forceinline__ float bf2f(bf16_t u) {
  union { unsigned int i; float f; } v; v.i = ((unsigned int)u) << 16; return v.f;
}
__device__ __forceinline__ bf16_t f2bf(float f) {
  union { float f; unsigned int i; } v; v.f = f;
  unsigned int r = v.i + 0x7FFFu + ((v.i >> 16) & 1u);  // RNE
  return (bf16_t)(r >> 16);
}

__device__ __forceinline__ void acc8(float* acc, uint4 u) {
  const unsigned* p = (const unsigned*)&u;
#pragma unroll
  for (int i = 0; i < 4; ++i) {
    union { unsigned v; float f; } lo, hi;
    lo.v = p[i] << 16;
    hi.v = p[i] & 0xffff0000u;
    acc[2 * i] += lo.f;
    acc[2 * i + 1] += hi.f;
  }
}
__device__ __forceinline__ void unpack8(float* o, uint4 u) {
  const unsigned* p = (const unsigned*)&u;
#pragma unroll
  for (int i = 0; i < 4; ++i) {
    union { unsigned v; float f; } lo, hi;
    lo.v = p[i] << 16;
    hi.v = p[i] & 0xffff0000u;
    o[2 * i] = lo.f;
    o[2 * i + 1] = hi.f;
  }
}
__device__ __forceinline__ uint4 pack8(const float* v) {
  uint4 o; unsigned* p = (unsigned*)&o;
#pragma unroll
  for (int i = 0; i < 4; ++i)
    p[i] = (unsigned)f2bf(v[2 * i]) | ((unsigned)f2bf(v[2 * i + 1]) << 16);
  return o;
}

// ---------------------------------------------------------------------------
__global__ void probe_k(float* __restrict__ out, int n, float v) {
  int i = blockIdx.x * blockDim.x + threadIdx.x;
  if (i < n) out[i] = v;
}

// ---------------- CSR build (bucketed, no per-node global atomics) ----------
__global__ __launch_bounds__(256) void hist_k(
    const int* __restrict__ src, const int* __restrict__ dst,
    int* __restrict__ hist_u, int* __restrict__ hist_i,
    int E, int Wi, int Wu) {
  __shared__ int hi[NBI], hu[NBU];
  int tid = threadIdx.x;
  for (int t = tid; t < NBI; t += 256) hi[t] = 0;
  for (int t = tid; t < NBU; t += 256) hu[t] = 0;
  __syncthreads();
  int base = blockIdx.x * 4096;
#pragma unroll
  for (int j = 0; j < 16; ++j) {
    int e = base + tid + j * 256;
    if (e < E) {
      atomicAdd(&hi[dst[e] / Wi], 1);
      atomicAdd(&hu[src[e] / Wu], 1);
    }
  }
  __syncthreads();
  for (int t = tid; t < NBI; t += 256) if (hi[t]) atomicAdd(hist_i + t, hi[t]);
  for (int t = tid; t < NBU; t += 256) if (hu[t]) atomicAdd(hist_u + t, hu[t]);
}

__global__ __launch_bounds__(512) void scan_small_pair_k(
    const int* __restrict__ hist_i, int* __restrict__ off_i, int* __restrict__ cur_i,
    const int* __restrict__ hist_u, int* __restrict__ off_u, int* __restrict__ cur_u) {
  __shared__ int lds[512];
  const int* hist = blockIdx.x ? hist_u : hist_i;
  int* off = blockIdx.x ? off_u : off_i;
  int* cur = blockIdx.x ? cur_u : cur_i;
  int n = blockIdx.x ? NBU : NBI;
  int t = threadIdx.x;
  int v = (t < n) ? hist[t] : 0;
  lds[t] = v; __syncthreads();
  for (int o = 1; o < 512; o <<= 1) {
    int tv = (t >= o) ? lds[t - o] : 0;
    __syncthreads(); lds[t] += tv; __syncthreads();
  }
  if (t < n) { int e = lds[t] - v; off[t] = e; cur[t] = e; }
}

__global__ __launch_bounds__(256) void bucket_append_k(
    const int* __restrict__ src, const int* __restrict__ dst, int E, int Wi, int Wu,
    int* __restrict__ cur_bi, int* __restrict__ cur_bu,
    unsigned int* __restrict__ ebuf_i, unsigned int* __restrict__ ebuf_u) {
  __shared__ int bi[NBI], bu[NBU];
  __shared__ uint2 es[4096];
  int tid = threadIdx.x;
  int base = blockIdx.x * 4096;
  int n = E - base; if (n > 4096) n = 4096;
  for (int t = tid; t < NBI; t += 256) bi[t] = 0;
  for (int t = tid; t < NBU; t += 256) bu[t] = 0;
  __syncthreads();
#pragma unroll
  for (int j = 0; j < 16; ++j) {
    int idx = tid + j * 256;
    if (idx < n) {
      int s = src[base + idx], d = dst[base + idx];
      es[idx] = make_uint2((unsigned)s, (unsigned)d);
      atomicAdd(&bi[d / Wi], 1);
      atomicAdd(&bu[s / Wu], 1);
    }
  }
  __syncthreads();
  for (int t = tid; t < NBI; t += 256) { int c = bi[t]; bi[t] = c ? atomicAdd(cur_bi + t, c) : 0; }
  for (int t = tid; t < NBU; t += 256) { int c = bu[t]; bu[t] = c ? atomicAdd(cur_bu + t, c) : 0; }
  __syncthreads();
#pragma unroll
  for (int j = 0; j < 16; ++j) {
    int idx = tid + j * 256;
    if (idx < n) {
      int s = (int)es[idx].x, d = (int)es[idx].y;
      int bI = d / Wi, bU = s / Wu;
      int pI = atomicAdd(&bi[bI], 1);
      int pU = atomicAdd(&bu[bU], 1);
      ebuf_i[pI] = ((unsigned)(d - bI * Wi) << 24) | (unsigned)s;
      ebuf_u[pU] = ((unsigned)(s - bU * Wu) << 24) | (unsigned)d;
    }
  }
}

__global__ __launch_bounds__(256) void bucket_fill2_k(
    const unsigned int* __restrict__ ebuf, const int* __restrict__ off,
    const int* __restrict__ endc, int* __restrict__ row,
    int* __restrict__ csr, int n, int W, int E) {
  int b = blockIdx.x;
  int d0 = b * W; if (d0 >= n) return;
  int cnt = n - d0; if (cnt > W) cnt = W;
  __shared__ int hist[320];
  __shared__ int cur[320];
  int tid = threadIdx.x;
  for (int t = tid; t < cnt; t += 256) hist[t] = 0;
  __syncthreads();
  int beg = off[b], e_end = endc[b];
  for (int e = beg + tid; e < e_end; e += 256)
    atomicAdd(&hist[ebuf[e] >> 24], 1);
  __syncthreads();
  if (tid < 64) {
    int lane = tid;
    int carry = beg;
    int nc = (cnt + 63) >> 6;
    for (int c = 0; c < nc; ++c) {
      int idx = (c << 6) + lane;
      int v = (idx < cnt) ? hist[idx] : 0;
      int x = v;
#pragma unroll
      for (int o = 1; o < 64; o <<= 1) { int t = __shfl_up(x, o); if (lane >= o) x += t; }
      if (idx < cnt) { int g = carry + x - v; row[d0 + idx] = g; cur[idx] = g; }
      carry += __shfl(x, 63);
    }
  }
  if (tid == 0 && d0 + cnt == n) row[n] = E;
  __syncthreads();
  for (int e = beg + tid; e < e_end; e += 256) {
    unsigned v = ebuf[e];
    int slot = atomicAdd(&cur[v >> 24], 1);
    csr[slot] = (int)(v & 0xFFFFFFu);
  }
}

// ---------------- dtype prep ----------------
__global__ void cvt_bf16_k(const float* __restrict__ in, bf16_t* __restrict__ out, int n4) {
  int i = blockIdx.x * blockDim.x + threadIdx.x;
  if (i < n4) {
    float4 v = ((const float4*)in)[i];
    ushort4 o; o.x = f2bf(v.x); o.y = f2bf(v.y); o.z = f2bf(v.z); o.w = f2bf(v.w);
    ((ushort4*)out)[i] = o;
  }
}

struct WBatch { const float* in[4]; bf16_t* out[4]; };
__global__ void twconv_batch_k(WBatch wb, int K, int N) {
  const float* __restrict__ in = wb.in[blockIdx.z];
  bf16_t* __restrict__ out = wb.out[blockIdx.z];
  __shared__ float t[32][33];
  int bx = blockIdx.x * 32, by = blockIdx.y * 32;
  int tx = threadIdx.x & 31, ty = threadIdx.x >> 5;  // 32x8
#pragma unroll
  for (int j = 0; j < 32; j += 8)
    t[ty + j][tx] = in[(size_t)(by + ty + j) * N + bx + tx];
  __syncthreads();
#pragma unroll
  for (int j = 0; j < 32; j += 8)
    out[(size_t)(bx + ty + j) * K + by + tx] = f2bf(t[tx][ty + j]);
}

// ---------------- gather-mean, D=128, 16 lanes/row, paired jobs ------------
struct GatherJob {
  const int* row; const int* csr;
  const bf16_t* X; bf16_t* agg; int n;
};

template<bool ADD>
__global__ void gather_mean16_k(GatherJob j0, GatherJob j1) {
  GatherJob j = blockIdx.y ? j1 : j0;
  int node = (int)(((long long)blockIdx.x * blockDim.x + threadIdx.x) >> 6);
  int lane = threadIdx.x & 63;
  if (node >= j.n) return;
  const int g = lane >> 4;
  const int l = lane & 15;
  int beg = j.row[node], end = j.row[node + 1];
  float acc[8] = {};
  for (int jj = beg; jj < end; jj += 64) {
    int cnt = min(64, end - jj);
    int my = (lane < cnt) ? j.csr[jj + lane] : 0;
    for (int k = 0; k < cnt; k += 4) {
      int idx = __shfl(my, k + g);
      if (k + g < cnt) {
        uint4 u = *(const uint4*)(j.X + (size_t)idx * 128 + l * 8);
        acc8(acc, u);
      }
    }
  }
#pragma unroll
  for (int m = 16; m < 64; m <<= 1)
#pragma unroll
    for (int i = 0; i < 8; ++i) acc[i] += __shfl_xor(acc[i], m);
  if (g == 0) {
    float inv = (end > beg) ? 1.0f / (float)(end - beg) : 0.0f;
    float v[8];
    if (ADD) {
      uint4 z = *(const uint4*)(j.agg + (size_t)node * 128 + l * 8);
      float zb[8]; unpack8(zb, z);
#pragma unroll
      for (int i = 0; i < 8; ++i) v[i] = acc[i] * inv + zb[i];
    } else {
#pragma unroll
      for (int i = 0; i < 8; ++i) v[i] = acc[i] * inv;
    }
    *(uint4*)(j.agg + (size_t)node * 128 + l * 8) = pack8(v);
  }
}

// ---------------- FUSED pipelined two-layer GEMM (wave-specialized) ---------
// 512 thr = A-group (waves 0-3: W1,W2 in regs; produce H[t]) + B-group
// (waves 4-7: Wc in regs; consume H[t-1] -> z|t stores). Each block
// grid-strides ~9 row-tiles (M=64); W loaded ONCE per block. LDS 128KB:
// Ab[2] (agg|xb) + Hb[2] double buffers. One barrier per tile iteration.
struct FJob {
  int M;
  const bf16_t* Aagg; const bf16_t* Axb;
  const bf16_t* W1; const bf16_t* W2;    // [256][128] row-major (^T)
  const float* b1;
  const bf16_t* Wc;                      // [256][256] row-major (^T), z|t concat
  const float* b2;
  bf16_t* Cz; bf16_t* Ct;
};

__global__ __launch_bounds__(512, 2) void fused_pipe_k(FJob j0, FJob j1, int nbI, int nbU) {
  const int bx = blockIdx.x;
  const bool isU = bx >= nbI;
  FJob j = isU ? j1 : j0;
  const int lb = isU ? bx - nbI : bx;
  const int NBLK = isU ? nbU : nbI;
  const int M = j.M;
  const int tiles = (M + 63) >> 6;
  const int T = (tiles > lb) ? (tiles - lb + NBLK - 1) / NBLK : 0;

  __shared__ __align__(16) bf16_t Ab[2][64 * 256];  // 2 x (agg 64x128 | xb 64x128)
  __shared__ __align__(16) bf16_t Hb[2][64 * 256];  // 2 x H 64x256

  const int tid = threadIdx.x;
  const int wave = tid >> 6, lane = tid & 63;
  const int wc = wave & 3;
  const int l15 = lane & 15, l4 = lane >> 4;

  // stage helper: load A-tile `tt` (list index) into Ab[b]
  auto STAGE = [&](int tt, int b) {
    size_t row0 = (size_t)(lb + tt * NBLK) * 64;
#pragma unroll
    for (int jj = 0; jj < 2; ++jj) {
      int i = tid + jj * 512;            // 16B slot 0..1023
      int r = i >> 4, c = i & 15;
      size_t ar = row0 + r; if (ar >= (size_t)M) ar = M - 1;
      int cs = c ^ (r & 7);
      __builtin_amdgcn_global_load_lds(
          (const __attribute__((address_space(1))) void*)(j.Aagg + ar * 128 + cs * 8),
          (__attribute__((address_space(3))) void*)(&Ab[b][0] + i * 8), 16, 0, 0);
      __builtin_amdgcn_global_load_lds(
          (const __attribute__((address_space(1))) void*)(j.Axb + ar * 128 + cs * 8),
          (__attribute__((address_space(3))) void*)(&Ab[b][64 * 128] + i * 8), 16, 0, 0);
    }
  };

  if (T > 0) STAGE(0, 0);
  __syncthreads();

  if (wave < 4) {
    // ================= A-group: H producer =================
    bf16x8 wA1[4][4], wA2[4][4];
#pragma unroll
    for (int kk = 0; kk < 4; ++kk)
#pragma unroll
      for (int ni = 0; ni < 4; ++ni) {
        int c1 = wc * 64 + ni * 16 + l15;
        wA1[kk][ni] = *(const bf16x8*)(j.W1 + (size_t)c1 * 128 + kk * 32 + l4 * 8);
        wA2[kk][ni] = *(const bf16x8*)(j.W2 + (size_t)c1 * 128 + kk * 32 + l4 * 8);
      }
    float4 bias1[4];
#pragma unroll
    for (int ni = 0; ni < 4; ++ni)
      bias1[ni] = *(const float4*)(j.b1 + wc * 64 + ni * 16 + l4 * 4);

    for (int t = 0; t <= T; ++t) {
      if (t + 1 < T) STAGE(t + 1, (t + 1) & 1);
      if (t < T) {
        const bf16_t* Aag = &Ab[t & 1][0];
        const bf16_t* Axb = &Ab[t & 1][64 * 128];
        char* Ub = (char*)&Hb[t & 1][0];
        f32x4 acc[4][4] = {};
#pragma unroll
        for (int kk = 0; kk < 4; ++kk) {
          bf16x8 aa[4], ax[4];
#pragma unroll
          for (int mi = 0; mi < 4; ++mi) {
            int ra = mi * 16 + l15;
            int ch = (kk * 4 + l4) ^ (ra & 7);
            aa[mi] = *(const bf16x8*)(Aag + ra * 128 + ch * 8);
            ax[mi] = *(const bf16x8*)(Axb + ra * 128 + ch * 8);
          }
#pragma unroll
          for (int mi = 0; mi < 4; ++mi)
#pragma unroll
            for (int ni = 0; ni < 4; ++ni)
              acc[mi][ni] = __builtin_amdgcn_mfma_f32_16x16x32_bf16(wA1[kk][ni], aa[mi], acc[mi][ni], 0, 0, 0);
#pragma unroll
          for (int mi = 0; mi < 4; ++mi)
#pragma unroll
            for (int ni = 0; ni < 4; ++ni)
              acc[mi][ni] = __builtin_amdgcn_mfma_f32_16x16x32_bf16(wA2[kk][ni], ax[mi], acc[mi][ni], 0, 0, 0);
        }
        // H epilogue: packed 8B swizzled ds_writes
#pragma unroll
        for (int ni = 0; ni < 4; ++ni) {
          int c0 = wc * 64 + ni * 16 + l4 * 4;
          const float* bp = (const float*)&bias1[ni];
#pragma unroll
          for (int mi = 0; mi < 4; ++mi) {
            int r = mi * 16 + l15;
            float v0 = fmaxf(acc[mi][ni][0] + bp[0], 0.f);
            float v1 = fmaxf(acc[mi][ni][1] + bp[1], 0.f);
            float v2 = fmaxf(acc[mi][ni][2] + bp[2], 0.f);
            float v3 = fmaxf(acc[mi][ni][3] + bp[3], 0.f);
            unsigned w0 = (unsigned)f2bf(v0) | ((unsigned)f2bf(v1) << 16);
            unsigned w1 = (unsigned)f2bf(v2) | ((unsigned)f2bf(v3) << 16);
            int p8 = (c0 >> 2) ^ ((r & 7) << 1);
            *(uint2*)(Ub + r * 512 + p8 * 8) = make_uint2(w0, w1);
          }
        }
      }
      __syncthreads();
    }
  } else {
    // ================= B-group: z|t consumer =================
    bf16x8 wB[8][4];
#pragma unroll
    for (int kk = 0; kk < 8; ++kk)
#pragma unroll
      for (int ni = 0; ni < 4; ++ni) {
        int c2 = wc * 64 + ni * 16 + l15;
        wB[kk][ni] = *(const bf16x8*)(j.Wc + (size_t)c2 * 256 + kk * 32 + l4 * 8);
      }
    const bool isZ = (wc < 2);               // cols 0..127 -> z (+bias)
    float4 bias2[4];
#pragma unroll
    for (int ni = 0; ni < 4; ++ni) {
      int c0 = wc * 64 + ni * 16 + l4 * 4;
      bias2[ni] = isZ ? *(const float4*)(j.b2 + c0) : make_float4(0.f, 0.f, 0.f, 0.f);
    }
    bf16_t* Co = isZ ? j.Cz : j.Ct;
    const int ccbase = isZ ? wc * 64 : wc * 64 - 128;

    for (int t = 0; t <= T; ++t) {
      if (t + 1 < T) STAGE(t + 1, (t + 1) & 1);
      if (t >= 1) {
        const bf16_t* Hls = &Hb[(t - 1) & 1][0];
        size_t row0 = (size_t)(lb + (t - 1) * NBLK) * 64;
        f32x4 acc[4][4] = {};
#pragma unroll
        for (int kk = 0; kk < 8; ++kk) {
          bf16x8 ah[4];
#pragma unroll
          for (int mi = 0; mi < 4; ++mi) {
            int r2 = mi * 16 + l15;
            int ch = (kk * 4 + l4) ^ (r2 & 7);
            ah[mi] = *(const bf16x8*)(Hls + r2 * 256 + ch * 8);
          }
#pragma unroll
          for (int mi = 0; mi < 4; ++mi)
#pragma unroll
            for (int ni = 0; ni < 4; ++ni)
              acc[mi][ni] = __builtin_amdgcn_mfma_f32_16x16x32_bf16(wB[kk][ni], ah[mi], acc[mi][ni], 0, 0, 0);
        }
        // direct packed 8B stores (lines fully covered by the wave)
#pragma unroll
        for (int ni = 0; ni < 4; ++ni) {
          int cc = ccbase + ni * 16 + l4 * 4;
          const float* bp = (const float*)&bias2[ni];
#pragma unroll
          for (int mi = 0; mi < 4; ++mi) {
            size_t gr = row0 + mi * 16 + l15;
            if (gr < (size_t)M) {
              unsigned w0 = (unsigned)f2bf(acc[mi][ni][0] + bp[0]) | ((unsigned)f2bf(acc[mi][ni][1] + bp[1]) << 16);
              unsigned w1 = (unsigned)f2bf(acc[mi][ni][2] + bp[2]) | ((unsigned)f2bf(acc[mi][ni][3] + bp[3]) << 16);
              *(uint2*)(Co + gr * 128 + cc) = make_uint2(w0, w1);
            }
          }
        }
      }
      __syncthreads();
    }
  }
}

// ---------------- decode: 16 lanes/label, 16B loads ----------------
__global__ void decode16_k(const int* __restrict__ ls, const int* __restrict__ ld,
                           const bf16_t* __restrict__ zu, const bf16_t* __restrict__ zi,
                           float* __restrict__ out, int L) {
  long long gid = (long long)blockIdx.x * blockDim.x + threadIdx.x;
  int w = (int)(gid >> 4);
  int l = (int)(gid & 15);
  if (w >= L) return;
  int su = ls[w], si = ld[w];
  uint4 a = *(const uint4*)(zu + (size_t)su * OO + l * 8);
  uint4 b = *(const uint4*)(zi + (size_t)si * OO + l * 8);
  const unsigned* pa = (const unsigned*)&a;
  const unsigned* pb = (const unsigned*)&b;
  float sum = 0.f;
#pragma unroll
  for (int i = 0; i < 4; ++i) {
    union { unsigned v; float f; } la, ha, lb, hb;
    la.v = pa[i] << 16;        ha.v = pa[i] & 0xffff0000u;
    lb.v = pb[i] << 16;        hb.v = pb[i] & 0xffff0000u;
    sum += la.f * lb.f + ha.f * hb.f;
  }
#pragma unroll
  for (int m = 1; m < 16; m <<= 1) sum += __shfl_xor(sum, m);
  if (l == 0) out[w] = sum;
}

// ---------------------------------------------------------------------------
extern "C" void kernel_launch(void* const* d_in, const int* in_sizes, int n_in,
                              void* d_out, int out_size, void* d_ws, size_t ws_size,
                              hipStream_t stream) {
  const float* x_user = (const float*)d_in[0];
  const float* x_item = (const float*)d_in[1];
  const int* edge_src = (const int*)d_in[2];
  const int* edge_dst = (const int*)d_in[3];
  const int* lbl_src  = (const int*)d_in[4];
  const int* lbl_dst  = (const int*)d_in[5];
  const float* wl1_ui = (const float*)d_in[6];
  const float* wr1_ui = (const float*)d_in[7];
  const float* b1_ui  = (const float*)d_in[8];
  const float* wl1_iu = (const float*)d_in[9];
  const float* wr1_iu = (const float*)d_in[10];
  const float* b1_iu  = (const float*)d_in[11];
  const float* wl2_ui = (const float*)d_in[12];
  const float* wr2_ui = (const float*)d_in[13];
  const float* b2_ui  = (const float*)d_in[14];
  const float* wl2_iu = (const float*)d_in[15];
  const float* wr2_iu = (const float*)d_in[16];
  const float* b2_iu  = (const float*)d_in[17];

  const int NU = in_sizes[0] / DD;
  const int NI = in_sizes[1] / DD;
  const int E  = in_sizes[2];
  const int L  = in_sizes[4];
  const int Wi = (NI + NBI - 1) / NBI;
  const int Wu = (NU + NBU - 1) / NBU;
  const int nEB = (E + 4095) / 4096;

  // ---- workspace layout ----
  size_t off = 0;
  auto take = [&](size_t bytes) { size_t o = off; off = (off + bytes + 255) & ~(size_t)255; return o; };
  char* base = (char*)d_ws;
  int* hist_i = (int*)(base + take(((size_t)NBI + NBU) * 4));  // zeroed together
  int* hist_u = hist_i + NBI;
  size_t zeroB = ((size_t)NBI + NBU) * 4;
  int* row_i = (int*)(base + take((size_t)(NI + 1) * 4));
  int* row_u = (int*)(base + take((size_t)(NU + 1) * 4));
  int* off_i = (int*)(base + take((size_t)NBI * 4));
  int* off_u = (int*)(base + take((size_t)NBU * 4));
  int* cur_bi = (int*)(base + take((size_t)NBI * 4));
  int* cur_bu = (int*)(base + take((size_t)NBU * 4));
  int* csr_i = (int*)(base + take((size_t)E * 4));
  int* csr_u = (int*)(base + take((size_t)E * 4));
  unsigned int* ebuf_i = (unsigned int*)(base + take((size_t)E * 4));
  unsigned int* ebuf_u = (unsigned int*)(base + take((size_t)E * 4));
  // pool holds agg + xb (all persistent through the fused GEMM)
  bf16_t* pool = (bf16_t*)(base + take((size_t)(NI + NU) * HH * 2));
  bf16_t* agg_i   = pool;                              // NI*DD
  bf16_t* agg_u   = agg_i + (size_t)NI * DD;           // NU*DD
  bf16_t* xb_item = agg_u + (size_t)NU * DD;           // NI*DD
  bf16_t* xb_user = xb_item + (size_t)NI * DD;         // NU*DD
  // t is written by the fused kernel while agg/xb are still live -> separate
  bf16_t* t_user = (bf16_t*)(base + take((size_t)(NI + NU) * OO * 2));
  bf16_t* t_item = t_user + (size_t)NU * OO;
  bf16_t* z_item = (bf16_t*)(base + take((size_t)(NI + NU) * OO * 2));
  bf16_t* z_user = z_item + (size_t)NI * OO;
  bf16_t* Wt1[4];
  for (int w = 0; w < 4; ++w) Wt1[w] = (bf16_t*)(base + take((size_t)HH * DD * 2));
  bf16_t* Wcat_item = (bf16_t*)(base + take((size_t)2 * OO * HH * 2));
  bf16_t* Wcat_user = (bf16_t*)(base + take((size_t)2 * OO * HH * 2));
  size_t need = off;

  float* out = (float*)d_out;
  if (ws_size < need || Wi > 320 || Wu > 320) {
    probe_k<<<(L + 255) / 256, 256, 0, stream>>>(out, L, (float)(ws_size >> 20));
    return;
  }

  // ---- CSR build ----
  hipMemsetAsync(hist_i, 0, zeroB, stream);
  hist_k<<<nEB, 256, 0, stream>>>(edge_src, edge_dst, hist_u, hist_i, E, Wi, Wu);
  scan_small_pair_k<<<2, 512, 0, stream>>>(hist_i, off_i, cur_bi, hist_u, off_u, cur_bu);
  bucket_append_k<<<nEB, 256, 0, stream>>>(edge_src, edge_dst, E, Wi, Wu, cur_bi, cur_bu, ebuf_i, ebuf_u);
  bucket_fill2_k<<<NBI, 256, 0, stream>>>(ebuf_i, off_i, cur_bi, row_i, csr_i, NI, Wi, E);
  bucket_fill2_k<<<NBU, 256, 0, stream>>>(ebuf_u, off_u, cur_bu, row_u, csr_u, NU, Wu, E);

  // ---- dtype prep ----
  cvt_bf16_k<<<(NI * DD / 4 + 255) / 256, 256, 0, stream>>>(x_item, xb_item, NI * DD / 4);
  cvt_bf16_k<<<(NU * DD / 4 + 255) / 256, 256, 0, stream>>>(x_user, xb_user, NU * DD / 4);
  {
    WBatch w1;
    w1.in[0] = wl1_ui; w1.out[0] = Wt1[0];
    w1.in[1] = wr1_ui; w1.out[1] = Wt1[1];
    w1.in[2] = wl1_iu; w1.out[2] = Wt1[2];
    w1.in[3] = wr1_iu; w1.out[3] = Wt1[3];
    dim3 g1(HH / 32, DD / 32, 4);  // [D,H] -> [H,D]
    twconv_batch_k<<<g1, 256, 0, stream>>>(w1, DD, HH);
    WBatch w2;
    w2.in[0] = wr2_ui; w2.out[0] = Wcat_item;                    // z_item part
    w2.in[1] = wl2_iu; w2.out[1] = Wcat_item + (size_t)OO * HH;  // t_item part
    w2.in[2] = wr2_iu; w2.out[2] = Wcat_user;                    // z_user part
    w2.in[3] = wl2_ui; w2.out[3] = Wcat_user + (size_t)OO * HH;  // t_user part
    dim3 g2(OO / 32, HH / 32, 4);  // [H,O] -> [O,H]
    twconv_batch_k<<<g2, 256, 0, stream>>>(w2, HH, OO);
  }

  const int nbMax = ((NU > NI ? NU : NI) * 64 + 255) / 256;
  const int tiles_i = (NI + 63) / 64, tiles_u = (NU + 63) / 64;

  // ---- layer 1 gather-mean (paired) ----
  {
    GatherJob gi = { row_i, csr_i, xb_user, agg_i, NI };
    GatherJob gu = { row_u, csr_u, xb_item, agg_u, NU };
    gather_mean16_k<false><<<dim3(nbMax, 2), 256, 0, stream>>>(gi, gu);
  }

  // ---- FUSED pipelined GEMM (wave-specialized, W in regs) ----
  {
    int nbI = (int)((256LL * tiles_i) / (tiles_i + tiles_u));
    if (nbI < 1) nbI = 1;
    if (nbI > tiles_i) nbI = tiles_i;
    int nbU2 = 256 - nbI;
    if (nbU2 > tiles_u) nbU2 = tiles_u;
    FJob ji = { NI, agg_i, xb_item, Wt1[0], Wt1[1], b1_ui, Wcat_item, b2_ui, z_item, t_item };
    FJob ju = { NU, agg_u, xb_user, Wt1[2], Wt1[3], b1_iu, Wcat_user, b2_iu, z_user, t_user };
    fused_pipe_k<<<nbI + nbU2, 512, 0, stream>>>(ji, ju, nbI, nbU2);
  }

  // ---- layer 2 gather-add: z += mean(t[nbrs]) ----
  {
    GatherJob gi = { row_i, csr_i, t_user, z_item, NI };
    GatherJob gu = { row_u, csr_u, t_item, z_user, NU };
    gather_mean16_k<true><<<dim3(nbMax, 2), 256, 0, stream>>>(gi, gu);
  }

  // ---- decode ----
  decode16_k<<<(int)(((long long)L * 16 + 255) / 256), 256, 0, stream>>>(lbl_src, lbl_dst, z_user, z_item, out, L);
}

// Round 16
// 317.560 us; speedup vs baseline: 1.5167x; 1.0310x over previous
//
#include <hip/hip_runtime.h>

#define DD 128   // input feature dim D
#define HH 256   // hidden dim H
#define OO 128   // output dim O

// CSR bucket config
#define NBI 256
#define NBU 512

typedef unsigned short bf16_t;
typedef short bf16x8 __attribute__((ext_vector_type(8)));   // 8 bf16 = 4 VGPRs
typedef float f32x4 __attribute__((ext_vector_type(4)));

__device__ __forceinline__ float bf2f(bf16_t u) {
  union { unsigned int i; float f; } v; v.i = ((unsigned int)u) << 16; return v.f;
}
__device__ __forceinline__ bf16_t f2bf(float f) {
  union { float f; unsigned int i; } v; v.f = f;
  unsigned int r = v.i + 0x7FFFu + ((v.i >> 16) & 1u);  // RNE
  return (bf16_t)(r >> 16);
}

__device__ __forceinline__ void acc8(float* acc, uint4 u) {
  const unsigned* p = (const unsigned*)&u;
#pragma unroll
  for (int i = 0; i < 4; ++i) {
    union { unsigned v; float f; } lo, hi;
    lo.v = p[i] << 16;
    hi.v = p[i] & 0xffff0000u;
    acc[2 * i] += lo.f;
    acc[2 * i + 1] += hi.f;
  }
}
__device__ __forceinline__ void unpack8(float* o, uint4 u) {
  const unsigned* p = (const unsigned*)&u;
#pragma unroll
  for (int i = 0; i < 4; ++i) {
    union { unsigned v; float f; } lo, hi;
    lo.v = p[i] << 16;
    hi.v = p[i] & 0xffff0000u;
    o[2 * i] = lo.f;
    o[2 * i + 1] = hi.f;
  }
}
__device__ __forceinline__ uint4 pack8(const float* v) {
  uint4 o; unsigned* p = (unsigned*)&o;
#pragma unroll
  for (int i = 0; i < 4; ++i)
    p[i] = (unsigned)f2bf(v[2 * i]) | ((unsigned)f2bf(v[2 * i + 1]) << 16);
  return o;
}

// ---------------------------------------------------------------------------
__global__ void probe_k(float* __restrict__ out, int n, float v) {
  int i = blockIdx.x * blockDim.x + threadIdx.x;
  if (i < n) out[i] = v;
}

// ---------------- CSR build (bucketed, no per-node global atomics) ----------
__global__ __launch_bounds__(256) void hist_k(
    const int* __restrict__ src, const int* __restrict__ dst,
    int* __restrict__ hist_u, int* __restrict__ hist_i,
    int E, int Wi, int Wu) {
  __shared__ int hi[NBI], hu[NBU];
  int tid = threadIdx.x;
  for (int t = tid; t < NBI; t += 256) hi[t] = 0;
  for (int t = tid; t < NBU; t += 256) hu[t] = 0;
  __syncthreads();
  int base = blockIdx.x * 4096;
#pragma unroll
  for (int j = 0; j < 16; ++j) {
    int e = base + tid + j * 256;
    if (e < E) {
      atomicAdd(&hi[dst[e] / Wi], 1);
      atomicAdd(&hu[src[e] / Wu], 1);
    }
  }
  __syncthreads();
  for (int t = tid; t < NBI; t += 256) if (hi[t]) atomicAdd(hist_i + t, hi[t]);
  for (int t = tid; t < NBU; t += 256) if (hu[t]) atomicAdd(hist_u + t, hu[t]);
}

__global__ __launch_bounds__(512) void scan_small_pair_k(
    const int* __restrict__ hist_i, int* __restrict__ off_i, int* __restrict__ cur_i,
    const int* __restrict__ hist_u, int* __restrict__ off_u, int* __restrict__ cur_u) {
  __shared__ int lds[512];
  const int* hist = blockIdx.x ? hist_u : hist_i;
  int* off = blockIdx.x ? off_u : off_i;
  int* cur = blockIdx.x ? cur_u : cur_i;
  int n = blockIdx.x ? NBU : NBI;
  int t = threadIdx.x;
  int v = (t < n) ? hist[t] : 0;
  lds[t] = v; __syncthreads();
  for (int o = 1; o < 512; o <<= 1) {
    int tv = (t >= o) ? lds[t - o] : 0;
    __syncthreads(); lds[t] += tv; __syncthreads();
  }
  if (t < n) { int e = lds[t] - v; off[t] = e; cur[t] = e; }
}

__global__ __launch_bounds__(256) void bucket_append_k(
    const int* __restrict__ src, const int* __restrict__ dst, int E, int Wi, int Wu,
    int* __restrict__ cur_bi, int* __restrict__ cur_bu,
    unsigned int* __restrict__ ebuf_i, unsigned int* __restrict__ ebuf_u) {
  __shared__ int bi[NBI], bu[NBU];
  __shared__ uint2 es[4096];
  int tid = threadIdx.x;
  int base = blockIdx.x * 4096;
  int n = E - base; if (n > 4096) n = 4096;
  for (int t = tid; t < NBI; t += 256) bi[t] = 0;
  for (int t = tid; t < NBU; t += 256) bu[t] = 0;
  __syncthreads();
#pragma unroll
  for (int j = 0; j < 16; ++j) {
    int idx = tid + j * 256;
    if (idx < n) {
      int s = src[base + idx], d = dst[base + idx];
      es[idx] = make_uint2((unsigned)s, (unsigned)d);
      atomicAdd(&bi[d / Wi], 1);
      atomicAdd(&bu[s / Wu], 1);
    }
  }
  __syncthreads();
  for (int t = tid; t < NBI; t += 256) { int c = bi[t]; bi[t] = c ? atomicAdd(cur_bi + t, c) : 0; }
  for (int t = tid; t < NBU; t += 256) { int c = bu[t]; bu[t] = c ? atomicAdd(cur_bu + t, c) : 0; }
  __syncthreads();
#pragma unroll
  for (int j = 0; j < 16; ++j) {
    int idx = tid + j * 256;
    if (idx < n) {
      int s = (int)es[idx].x, d = (int)es[idx].y;
      int bI = d / Wi, bU = s / Wu;
      int pI = atomicAdd(&bi[bI], 1);
      int pU = atomicAdd(&bu[bU], 1);
      ebuf_i[pI] = ((unsigned)(d - bI * Wi) << 24) | (unsigned)s;
      ebuf_u[pU] = ((unsigned)(s - bU * Wu) << 24) | (unsigned)d;
    }
  }
}

__global__ __launch_bounds__(256) void bucket_fill2_k(
    const unsigned int* __restrict__ ebuf, const int* __restrict__ off,
    const int* __restrict__ endc, int* __restrict__ row,
    int* __restrict__ csr, int n, int W, int E) {
  int b = blockIdx.x;
  int d0 = b * W; if (d0 >= n) return;
  int cnt = n - d0; if (cnt > W) cnt = W;
  __shared__ int hist[320];
  __shared__ int cur[320];
  int tid = threadIdx.x;
  for (int t = tid; t < cnt; t += 256) hist[t] = 0;
  __syncthreads();
  int beg = off[b], e_end = endc[b];
  for (int e = beg + tid; e < e_end; e += 256)
    atomicAdd(&hist[ebuf[e] >> 24], 1);
  __syncthreads();
  if (tid < 64) {
    int lane = tid;
    int carry = beg;
    int nc = (cnt + 63) >> 6;
    for (int c = 0; c < nc; ++c) {
      int idx = (c << 6) + lane;
      int v = (idx < cnt) ? hist[idx] : 0;
      int x = v;
#pragma unroll
      for (int o = 1; o < 64; o <<= 1) { int t = __shfl_up(x, o); if (lane >= o) x += t; }
      if (idx < cnt) { int g = carry + x - v; row[d0 + idx] = g; cur[idx] = g; }
      carry += __shfl(x, 63);
    }
  }
  if (tid == 0 && d0 + cnt == n) row[n] = E;
  __syncthreads();
  for (int e = beg + tid; e < e_end; e += 256) {
    unsigned v = ebuf[e];
    int slot = atomicAdd(&cur[v >> 24], 1);
    csr[slot] = (int)(v & 0xFFFFFFu);
  }
}

// ---------------- dtype prep ----------------
__global__ void cvt_bf16_k(const float* __restrict__ in, bf16_t* __restrict__ out, int n4) {
  int i = blockIdx.x * blockDim.x + threadIdx.x;
  if (i < n4) {
    float4 v = ((const float4*)in)[i];
    ushort4 o; o.x = f2bf(v.x); o.y = f2bf(v.y); o.z = f2bf(v.z); o.w = f2bf(v.w);
    ((ushort4*)out)[i] = o;
  }
}

struct WBatch { const float* in[4]; bf16_t* out[4]; };
__global__ void twconv_batch_k(WBatch wb, int K, int N) {
  const float* __restrict__ in = wb.in[blockIdx.z];
  bf16_t* __restrict__ out = wb.out[blockIdx.z];
  __shared__ float t[32][33];
  int bx = blockIdx.x * 32, by = blockIdx.y * 32;
  int tx = threadIdx.x & 31, ty = threadIdx.x >> 5;  // 32x8
#pragma unroll
  for (int j = 0; j < 32; j += 8)
    t[ty + j][tx] = in[(size_t)(by + ty + j) * N + bx + tx];
  __syncthreads();
#pragma unroll
  for (int j = 0; j < 32; j += 8)
    out[(size_t)(bx + ty + j) * K + by + tx] = f2bf(t[tx][ty + j]);
}

// ---------------- gather-mean, D=128, 16 lanes/row, paired jobs ------------
// 32-bit byte offsets (tables < 4GB) -> SGPR-base + voffset loads; 8 rows in flight.
struct GatherJob {
  const int* row; const int* csr;
  const bf16_t* X; bf16_t* agg; int n;
};

template<bool ADD>
__global__ void gather_mean16_k(GatherJob j0, GatherJob j1) {
  GatherJob j = blockIdx.y ? j1 : j0;
  int node = (int)((blockIdx.x * 256u + threadIdx.x) >> 6);
  int lane = threadIdx.x & 63;
  if (node >= j.n) return;
  const int g = lane >> 4;
  const unsigned lb = (unsigned)(lane & 15) << 4;   // lane byte offset in row
  int beg = j.row[node], end = j.row[node + 1];
  float acc[8] = {};
  const char* __restrict__ Xb = (const char*)j.X;
  for (int jj = beg; jj < end; jj += 64) {
    int cnt = min(64, end - jj);
    int my = (lane < cnt) ? j.csr[jj + lane] : 0;
    int k = 0;
    for (; k + 8 <= cnt; k += 8) {
      unsigned o0 = ((unsigned)__shfl(my, k + g) << 8) + lb;
      unsigned o1 = ((unsigned)__shfl(my, k + 4 + g) << 8) + lb;
      uint4 u0 = *(const uint4*)(Xb + o0);
      uint4 u1 = *(const uint4*)(Xb + o1);
      acc8(acc, u0);
      acc8(acc, u1);
    }
    for (; k < cnt; k += 4) {
      int idx = __shfl(my, k + g);
      if (k + g < cnt) {
        unsigned o = ((unsigned)idx << 8) + lb;
        uint4 u = *(const uint4*)(Xb + o);
        acc8(acc, u);
      }
    }
  }
#pragma unroll
  for (int m = 16; m < 64; m <<= 1)
#pragma unroll
    for (int i = 0; i < 8; ++i) acc[i] += __shfl_xor(acc[i], m);
  if (g == 0) {
    float inv = (end > beg) ? 1.0f / (float)(end - beg) : 0.0f;
    float v[8];
    char* __restrict__ Ab = (char*)j.agg;
    unsigned oo = ((unsigned)node << 8) + lb;
    if (ADD) {
      uint4 z = *(const uint4*)(Ab + oo);
      float zb[8]; unpack8(zb, z);
#pragma unroll
      for (int i = 0; i < 8; ++i) v[i] = acc[i] * inv + zb[i];
    } else {
#pragma unroll
      for (int i = 0; i < 8; ++i) v[i] = acc[i] * inv;
    }
    *(uint4*)(Ab + oo) = pack8(v);
  }
}

// ---------------- FUSED pipelined two-layer GEMM (wave-specialized) ---------
struct FJob {
  int M;
  const bf16_t* Aagg; const bf16_t* Axb;
  const bf16_t* W1; const bf16_t* W2;    // [256][128] row-major (^T)
  const float* b1;
  const bf16_t* Wc;                      // [256][256] row-major (^T), z|t concat
  const float* b2;
  bf16_t* Cz; bf16_t* Ct;
};

__global__ __launch_bounds__(512, 2) void fused_pipe_k(FJob j0, FJob j1, int nbI, int nbU) {
  const int bx = blockIdx.x;
  const bool isU = bx >= nbI;
  FJob j = isU ? j1 : j0;
  const int lb = isU ? bx - nbI : bx;
  const int NBLK = isU ? nbU : nbI;
  const int M = j.M;
  const int tiles = (M + 63) >> 6;
  const int T = (tiles > lb) ? (tiles - lb + NBLK - 1) / NBLK : 0;

  __shared__ __align__(16) bf16_t Ab[2][64 * 256];  // 2 x (agg 64x128 | xb 64x128)
  __shared__ __align__(16) bf16_t Hb[2][64 * 256];  // 2 x H 64x256

  const int tid = threadIdx.x;
  const int wave = tid >> 6, lane = tid & 63;
  const int wc = wave & 3;
  const int l15 = lane & 15, l4 = lane >> 4;

  auto STAGE = [&](int tt, int b) {
    size_t row0 = (size_t)(lb + tt * NBLK) * 64;
#pragma unroll
    for (int jj = 0; jj < 2; ++jj) {
      int i = tid + jj * 512;            // 16B slot 0..1023
      int r = i >> 4, c = i & 15;
      size_t ar = row0 + r; if (ar >= (size_t)M) ar = M - 1;
      int cs = c ^ (r & 7);
      __builtin_amdgcn_global_load_lds(
          (const __attribute__((address_space(1))) void*)(j.Aagg + ar * 128 + cs * 8),
          (__attribute__((address_space(3))) void*)(&Ab[b][0] + i * 8), 16, 0, 0);
      __builtin_amdgcn_global_load_lds(
          (const __attribute__((address_space(1))) void*)(j.Axb + ar * 128 + cs * 8),
          (__attribute__((address_space(3))) void*)(&Ab[b][64 * 128] + i * 8), 16, 0, 0);
    }
  };

  if (T > 0) STAGE(0, 0);
  __syncthreads();

  if (wave < 4) {
    // ================= A-group: H producer =================
    bf16x8 wA1[4][4], wA2[4][4];
#pragma unroll
    for (int kk = 0; kk < 4; ++kk)
#pragma unroll
      for (int ni = 0; ni < 4; ++ni) {
        int c1 = wc * 64 + ni * 16 + l15;
        wA1[kk][ni] = *(const bf16x8*)(j.W1 + (size_t)c1 * 128 + kk * 32 + l4 * 8);
        wA2[kk][ni] = *(const bf16x8*)(j.W2 + (size_t)c1 * 128 + kk * 32 + l4 * 8);
      }
    float4 bias1[4];
#pragma unroll
    for (int ni = 0; ni < 4; ++ni)
      bias1[ni] = *(const float4*)(j.b1 + wc * 64 + ni * 16 + l4 * 4);

    for (int t = 0; t <= T; ++t) {
      if (t + 1 < T) STAGE(t + 1, (t + 1) & 1);
      if (t < T) {
        const bf16_t* Aag = &Ab[t & 1][0];
        const bf16_t* Axb = &Ab[t & 1][64 * 128];
        char* Ub = (char*)&Hb[t & 1][0];
        f32x4 acc[4][4] = {};
#pragma unroll
        for (int kk = 0; kk < 4; ++kk) {
          bf16x8 aa[4], ax[4];
#pragma unroll
          for (int mi = 0; mi < 4; ++mi) {
            int ra = mi * 16 + l15;
            int ch = (kk * 4 + l4) ^ (ra & 7);
            aa[mi] = *(const bf16x8*)(Aag + ra * 128 + ch * 8);
            ax[mi] = *(const bf16x8*)(Axb + ra * 128 + ch * 8);
          }
#pragma unroll
          for (int mi = 0; mi < 4; ++mi)
#pragma unroll
            for (int ni = 0; ni < 4; ++ni)
              acc[mi][ni] = __builtin_amdgcn_mfma_f32_16x16x32_bf16(wA1[kk][ni], aa[mi], acc[mi][ni], 0, 0, 0);
#pragma unroll
          for (int mi = 0; mi < 4; ++mi)
#pragma unroll
            for (int ni = 0; ni < 4; ++ni)
              acc[mi][ni] = __builtin_amdgcn_mfma_f32_16x16x32_bf16(wA2[kk][ni], ax[mi], acc[mi][ni], 0, 0, 0);
        }
#pragma unroll
        for (int ni = 0; ni < 4; ++ni) {
          int c0 = wc * 64 + ni * 16 + l4 * 4;
          const float* bp = (const float*)&bias1[ni];
#pragma unroll
          for (int mi = 0; mi < 4; ++mi) {
            int r = mi * 16 + l15;
            float v0 = fmaxf(acc[mi][ni][0] + bp[0], 0.f);
            float v1 = fmaxf(acc[mi][ni][1] + bp[1], 0.f);
            float v2 = fmaxf(acc[mi][ni][2] + bp[2], 0.f);
            float v3 = fmaxf(acc[mi][ni][3] + bp[3], 0.f);
            unsigned w0 = (unsigned)f2bf(v0) | ((unsigned)f2bf(v1) << 16);
            unsigned w1 = (unsigned)f2bf(v2) | ((unsigned)f2bf(v3) << 16);
            int p8 = (c0 >> 2) ^ ((r & 7) << 1);
            *(uint2*)(Ub + r * 512 + p8 * 8) = make_uint2(w0, w1);
          }
        }
      }
      __syncthreads();
    }
  } else {
    // ================= B-group: z|t consumer =================
    bf16x8 wB[8][4];
#pragma unroll
    for (int kk = 0; kk < 8; ++kk)
#pragma unroll
      for (int ni = 0; ni < 4; ++ni) {
        int c2 = wc * 64 + ni * 16 + l15;
        wB[kk][ni] = *(const bf16x8*)(j.Wc + (size_t)c2 * 256 + kk * 32 + l4 * 8);
      }
    const bool isZ = (wc < 2);               // cols 0..127 -> z (+bias)
    float4 bias2[4];
#pragma unroll
    for (int ni = 0; ni < 4; ++ni) {
      int c0 = wc * 64 + ni * 16 + l4 * 4;
      bias2[ni] = isZ ? *(const float4*)(j.b2 + c0) : make_float4(0.f, 0.f, 0.f, 0.f);
    }
    bf16_t* Co = isZ ? j.Cz : j.Ct;
    const int ccbase = isZ ? wc * 64 : wc * 64 - 128;

    for (int t = 0; t <= T; ++t) {
      if (t + 1 < T) STAGE(t + 1, (t + 1) & 1);
      if (t >= 1) {
        const bf16_t* Hls = &Hb[(t - 1) & 1][0];
        size_t row0 = (size_t)(lb + (t - 1) * NBLK) * 64;
        f32x4 acc[4][4] = {};
#pragma unroll
        for (int kk = 0; kk < 8; ++kk) {
          bf16x8 ah[4];
#pragma unroll
          for (int mi = 0; mi < 4; ++mi) {
            int r2 = mi * 16 + l15;
            int ch = (kk * 4 + l4) ^ (r2 & 7);
            ah[mi] = *(const bf16x8*)(Hls + r2 * 256 + ch * 8);
          }
#pragma unroll
          for (int mi = 0; mi < 4; ++mi)
#pragma unroll
            for (int ni = 0; ni < 4; ++ni)
              acc[mi][ni] = __builtin_amdgcn_mfma_f32_16x16x32_bf16(wB[kk][ni], ah[mi], acc[mi][ni], 0, 0, 0);
        }
#pragma unroll
        for (int ni = 0; ni < 4; ++ni) {
          int cc = ccbase + ni * 16 + l4 * 4;
          const float* bp = (const float*)&bias2[ni];
#pragma unroll
          for (int mi = 0; mi < 4; ++mi) {
            size_t gr = row0 + mi * 16 + l15;
            if (gr < (size_t)M) {
              unsigned w0 = (unsigned)f2bf(acc[mi][ni][0] + bp[0]) | ((unsigned)f2bf(acc[mi][ni][1] + bp[1]) << 16);
              unsigned w1 = (unsigned)f2bf(acc[mi][ni][2] + bp[2]) | ((unsigned)f2bf(acc[mi][ni][3] + bp[3]) << 16);
              *(uint2*)(Co + gr * 128 + cc) = make_uint2(w0, w1);
            }
          }
        }
      }
      __syncthreads();
    }
  }
}

// ---------------- decode: 16 lanes/label, 16B loads, 32-bit offsets ---------
__global__ void decode16_k(const int* __restrict__ ls, const int* __restrict__ ld,
                           const bf16_t* __restrict__ zu, const bf16_t* __restrict__ zi,
                           float* __restrict__ out, int L) {
  long long gid = (long long)blockIdx.x * blockDim.x + threadIdx.x;
  int w = (int)(gid >> 4);
  int l = (int)(gid & 15);
  if (w >= L) return;
  unsigned lb = (unsigned)l << 4;
  unsigned oa = ((unsigned)ls[w] << 8) + lb;
  unsigned ob = ((unsigned)ld[w] << 8) + lb;
  uint4 a = *(const uint4*)((const char*)zu + oa);
  uint4 b = *(const uint4*)((const char*)zi + ob);
  const unsigned* pa = (const unsigned*)&a;
  const unsigned* pb = (const unsigned*)&b;
  float sum = 0.f;
#pragma unroll
  for (int i = 0; i < 4; ++i) {
    union { unsigned v; float f; } la, ha, lb2, hb;
    la.v = pa[i] << 16;        ha.v = pa[i] & 0xffff0000u;
    lb2.v = pb[i] << 16;       hb.v = pb[i] & 0xffff0000u;
    sum += la.f * lb2.f + ha.f * hb.f;
  }
#pragma unroll
  for (int m = 1; m < 16; m <<= 1) sum += __shfl_xor(sum, m);
  if (l == 0) out[w] = sum;
}

// ---------------------------------------------------------------------------
extern "C" void kernel_launch(void* const* d_in, const int* in_sizes, int n_in,
                              void* d_out, int out_size, void* d_ws, size_t ws_size,
                              hipStream_t stream) {
  const float* x_user = (const float*)d_in[0];
  const float* x_item = (const float*)d_in[1];
  const int* edge_src = (const int*)d_in[2];
  const int* edge_dst = (const int*)d_in[3];
  const int* lbl_src  = (const int*)d_in[4];
  const int* lbl_dst  = (const int*)d_in[5];
  const float* wl1_ui = (const float*)d_in[6];
  const float* wr1_ui = (const float*)d_in[7];
  const float* b1_ui  = (const float*)d_in[8];
  const float* wl1_iu = (const float*)d_in[9];
  const float* wr1_iu = (const float*)d_in[10];
  const float* b1_iu  = (const float*)d_in[11];
  const float* wl2_ui = (const float*)d_in[12];
  const float* wr2_ui = (const float*)d_in[13];
  const float* b2_ui  = (const float*)d_in[14];
  const float* wl2_iu = (const float*)d_in[15];
  const float* wr2_iu = (const float*)d_in[16];
  const float* b2_iu  = (const float*)d_in[17];

  const int NU = in_sizes[0] / DD;
  const int NI = in_sizes[1] / DD;
  const int E  = in_sizes[2];
  const int L  = in_sizes[4];
  const int Wi = (NI + NBI - 1) / NBI;
  const int Wu = (NU + NBU - 1) / NBU;
  const int nEB = (E + 4095) / 4096;

  // ---- workspace layout ----
  size_t off = 0;
  auto take = [&](size_t bytes) { size_t o = off; off = (off + bytes + 255) & ~(size_t)255; return o; };
  char* base = (char*)d_ws;
  int* hist_i = (int*)(base + take(((size_t)NBI + NBU) * 4));  // zeroed together
  int* hist_u = hist_i + NBI;
  size_t zeroB = ((size_t)NBI + NBU) * 4;
  int* row_i = (int*)(base + take((size_t)(NI + 1) * 4));
  int* row_u = (int*)(base + take((size_t)(NU + 1) * 4));
  int* off_i = (int*)(base + take((size_t)NBI * 4));
  int* off_u = (int*)(base + take((size_t)NBU * 4));
  int* cur_bi = (int*)(base + take((size_t)NBI * 4));
  int* cur_bu = (int*)(base + take((size_t)NBU * 4));
  int* csr_i = (int*)(base + take((size_t)E * 4));
  int* csr_u = (int*)(base + take((size_t)E * 4));
  unsigned int* ebuf_i = (unsigned int*)(base + take((size_t)E * 4));
  unsigned int* ebuf_u = (unsigned int*)(base + take((size_t)E * 4));
  // pool holds agg + xb (all persistent through the fused GEMM)
  bf16_t* pool = (bf16_t*)(base + take((size_t)(NI + NU) * HH * 2));
  bf16_t* agg_i   = pool;                              // NI*DD
  bf16_t* agg_u   = agg_i + (size_t)NI * DD;           // NU*DD
  bf16_t* xb_item = agg_u + (size_t)NU * DD;           // NI*DD
  bf16_t* xb_user = xb_item + (size_t)NI * DD;         // NU*DD
  // t is written by the fused kernel while agg/xb are still live -> separate
  bf16_t* t_user = (bf16_t*)(base + take((size_t)(NI + NU) * OO * 2));
  bf16_t* t_item = t_user + (size_t)NU * OO;
  bf16_t* z_item = (bf16_t*)(base + take((size_t)(NI + NU) * OO * 2));
  bf16_t* z_user = z_item + (size_t)NI * OO;
  bf16_t* Wt1[4];
  for (int w = 0; w < 4; ++w) Wt1[w] = (bf16_t*)(base + take((size_t)HH * DD * 2));
  bf16_t* Wcat_item = (bf16_t*)(base + take((size_t)2 * OO * HH * 2));
  bf16_t* Wcat_user = (bf16_t*)(base + take((size_t)2 * OO * HH * 2));
  size_t need = off;

  float* out = (float*)d_out;
  if (ws_size < need || Wi > 320 || Wu > 320) {
    probe_k<<<(L + 255) / 256, 256, 0, stream>>>(out, L, (float)(ws_size >> 20));
    return;
  }

  // ---- CSR build ----
  hipMemsetAsync(hist_i, 0, zeroB, stream);
  hist_k<<<nEB, 256, 0, stream>>>(edge_src, edge_dst, hist_u, hist_i, E, Wi, Wu);
  scan_small_pair_k<<<2, 512, 0, stream>>>(hist_i, off_i, cur_bi, hist_u, off_u, cur_bu);
  bucket_append_k<<<nEB, 256, 0, stream>>>(edge_src, edge_dst, E, Wi, Wu, cur_bi, cur_bu, ebuf_i, ebuf_u);
  bucket_fill2_k<<<NBI, 256, 0, stream>>>(ebuf_i, off_i, cur_bi, row_i, csr_i, NI, Wi, E);
  bucket_fill2_k<<<NBU, 256, 0, stream>>>(ebuf_u, off_u, cur_bu, row_u, csr_u, NU, Wu, E);

  // ---- dtype prep ----
  cvt_bf16_k<<<(NI * DD / 4 + 255) / 256, 256, 0, stream>>>(x_item, xb_item, NI * DD / 4);
  cvt_bf16_k<<<(NU * DD / 4 + 255) / 256, 256, 0, stream>>>(x_user, xb_user, NU * DD / 4);
  {
    WBatch w1;
    w1.in[0] = wl1_ui; w1.out[0] = Wt1[0];
    w1.in[1] = wr1_ui; w1.out[1] = Wt1[1];
    w1.in[2] = wl1_iu; w1.out[2] = Wt1[2];
    w1.in[3] = wr1_iu; w1.out[3] = Wt1[3];
    dim3 g1(HH / 32, DD / 32, 4);  // [D,H] -> [H,D]
    twconv_batch_k<<<g1, 256, 0, stream>>>(w1, DD, HH);
    WBatch w2;
    w2.in[0] = wr2_ui; w2.out[0] = Wcat_item;                    // z_item part
    w2.in[1] = wl2_iu; w2.out[1] = Wcat_item + (size_t)OO * HH;  // t_item part
    w2.in[2] = wr2_iu; w2.out[2] = Wcat_user;                    // z_user part
    w2.in[3] = wl2_ui; w2.out[3] = Wcat_user + (size_t)OO * HH;  // t_user part
    dim3 g2(OO / 32, HH / 32, 4);  // [H,O] -> [O,H]
    twconv_batch_k<<<g2, 256, 0, stream>>>(w2, HH, OO);
  }

  const int nbMax = ((NU > NI ? NU : NI) * 64 + 255) / 256;
  const int tiles_i = (NI + 63) / 64, tiles_u = (NU + 63) / 64;

  // ---- layer 1 gather-mean (paired) ----
  {
    GatherJob gi = { row_i, csr_i, xb_user, agg_i, NI };
    GatherJob gu = { row_u, csr_u, xb_item, agg_u, NU };
    gather_mean16_k<false><<<dim3(nbMax, 2), 256, 0, stream>>>(gi, gu);
  }

  // ---- FUSED pipelined GEMM (wave-specialized, W in regs) ----
  {
    int nbI = (int)((256LL * tiles_i) / (tiles_i + tiles_u));
    if (nbI < 1) nbI = 1;
    if (nbI > tiles_i) nbI = tiles_i;
    int nbU2 = 256 - nbI;
    if (nbU2 > tiles_u) nbU2 = tiles_u;
    FJob ji = { NI, agg_i, xb_item, Wt1[0], Wt1[1], b1_ui, Wcat_item, b2_ui, z_item, t_item };
    FJob ju = { NU, agg_u, xb_user, Wt1[2], Wt1[3], b1_iu, Wcat_user, b2_iu, z_user, t_user };
    fused_pipe_k<<<nbI + nbU2, 512, 0, stream>>>(ji, ju, nbI, nbU2);
  }

  // ---- layer 2 gather-add: z += mean(t[nbrs]) ----
  {
    GatherJob gi = { row_i, csr_i, t_user, z_item, NI };
    GatherJob gu = { row_u, csr_u, t_item, z_user, NU };
    gather_mean16_k<true><<<dim3(nbMax, 2), 256, 0, stream>>>(gi, gu);
  }

  // ---- decode ----
  decode16_k<<<(int)(((long long)L * 16 + 255) / 256), 256, 0, stream>>>(lbl_src, lbl_dst, z_user, z_item, out, L);
}

// Round 17
// 313.025 us; speedup vs baseline: 1.5387x; 1.0145x over previous
//
#include <hip/hip_runtime.h>

#define DD 128   // input feature dim D
#define HH 256   // hidden dim H
#define OO 128   // output dim O

// CSR bucket config
#define NBI 256
#define NBU 512

typedef unsigned short bf16_t;
typedef short bf16x8 __attribute__((ext_vector_type(8)));   // 8 bf16 = 4 VGPRs
typedef float f32x4 __attribute__((ext_vector_type(4)));

__device__ __forceinline__ float bf2f(bf16_t u) {
  union { unsigned int i; float f; } v; v.i = ((unsigned int)u) << 16; return v.f;
}
__device__ __forceinline__ bf16_t f2bf(float f) {
  union { float f; unsigned int i; } v; v.f = f;
  unsigned int r = v.i + 0x7FFFu + ((v.i >> 16) & 1u);  // RNE
  return (bf16_t)(r >> 16);
}

__device__ __forceinline__ void acc8(float* acc, uint4 u) {
  const unsigned* p = (const unsigned*)&u;
#pragma unroll
  for (int i = 0; i < 4; ++i) {
    union { unsigned v; float f; } lo, hi;
    lo.v = p[i] << 16;
    hi.v = p[i] & 0xffff0000u;
    acc[2 * i] += lo.f;
    acc[2 * i + 1] += hi.f;
  }
}
__device__ __forceinline__ void unpack8(float* o, uint4 u) {
  const unsigned* p = (const unsigned*)&u;
#pragma unroll
  for (int i = 0; i < 4; ++i) {
    union { unsigned v; float f; } lo, hi;
    lo.v = p[i] << 16;
    hi.v = p[i] & 0xffff0000u;
    o[2 * i] = lo.f;
    o[2 * i + 1] = hi.f;
  }
}
__device__ __forceinline__ uint4 pack8(const float* v) {
  uint4 o; unsigned* p = (unsigned*)&o;
#pragma unroll
  for (int i = 0; i < 4; ++i)
    p[i] = (unsigned)f2bf(v[2 * i]) | ((unsigned)f2bf(v[2 * i + 1]) << 16);
  return o;
}

// ---------------------------------------------------------------------------
__global__ void probe_k(float* __restrict__ out, int n, float v) {
  int i = blockIdx.x * blockDim.x + threadIdx.x;
  if (i < n) out[i] = v;
}

// ---------------- CSR build (bucketed, no per-node global atomics) ----------
__global__ __launch_bounds__(256) void hist_k(
    const int* __restrict__ src, const int* __restrict__ dst,
    int* __restrict__ hist_u, int* __restrict__ hist_i,
    int E, int Wi, int Wu) {
  __shared__ int hi[NBI], hu[NBU];
  int tid = threadIdx.x;
  for (int t = tid; t < NBI; t += 256) hi[t] = 0;
  for (int t = tid; t < NBU; t += 256) hu[t] = 0;
  __syncthreads();
  int base = blockIdx.x * 4096;
#pragma unroll
  for (int j = 0; j < 16; ++j) {
    int e = base + tid + j * 256;
    if (e < E) {
      atomicAdd(&hi[dst[e] / Wi], 1);
      atomicAdd(&hu[src[e] / Wu], 1);
    }
  }
  __syncthreads();
  for (int t = tid; t < NBI; t += 256) if (hi[t]) atomicAdd(hist_i + t, hi[t]);
  for (int t = tid; t < NBU; t += 256) if (hu[t]) atomicAdd(hist_u + t, hu[t]);
}

__global__ __launch_bounds__(512) void scan_small_pair_k(
    const int* __restrict__ hist_i, int* __restrict__ off_i, int* __restrict__ cur_i,
    const int* __restrict__ hist_u, int* __restrict__ off_u, int* __restrict__ cur_u) {
  __shared__ int lds[512];
  const int* hist = blockIdx.x ? hist_u : hist_i;
  int* off = blockIdx.x ? off_u : off_i;
  int* cur = blockIdx.x ? cur_u : cur_i;
  int n = blockIdx.x ? NBU : NBI;
  int t = threadIdx.x;
  int v = (t < n) ? hist[t] : 0;
  lds[t] = v; __syncthreads();
  for (int o = 1; o < 512; o <<= 1) {
    int tv = (t >= o) ? lds[t - o] : 0;
    __syncthreads(); lds[t] += tv; __syncthreads();
  }
  if (t < n) { int e = lds[t] - v; off[t] = e; cur[t] = e; }
}

__global__ __launch_bounds__(256) void bucket_append_k(
    const int* __restrict__ src, const int* __restrict__ dst, int E, int Wi, int Wu,
    int* __restrict__ cur_bi, int* __restrict__ cur_bu,
    unsigned int* __restrict__ ebuf_i, unsigned int* __restrict__ ebuf_u) {
  __shared__ int bi[NBI], bu[NBU];
  __shared__ uint2 es[4096];
  int tid = threadIdx.x;
  int base = blockIdx.x * 4096;
  int n = E - base; if (n > 4096) n = 4096;
  for (int t = tid; t < NBI; t += 256) bi[t] = 0;
  for (int t = tid; t < NBU; t += 256) bu[t] = 0;
  __syncthreads();
#pragma unroll
  for (int j = 0; j < 16; ++j) {
    int idx = tid + j * 256;
    if (idx < n) {
      int s = src[base + idx], d = dst[base + idx];
      es[idx] = make_uint2((unsigned)s, (unsigned)d);
      atomicAdd(&bi[d / Wi], 1);
      atomicAdd(&bu[s / Wu], 1);
    }
  }
  __syncthreads();
  for (int t = tid; t < NBI; t += 256) { int c = bi[t]; bi[t] = c ? atomicAdd(cur_bi + t, c) : 0; }
  for (int t = tid; t < NBU; t += 256) { int c = bu[t]; bu[t] = c ? atomicAdd(cur_bu + t, c) : 0; }
  __syncthreads();
#pragma unroll
  for (int j = 0; j < 16; ++j) {
    int idx = tid + j * 256;
    if (idx < n) {
      int s = (int)es[idx].x, d = (int)es[idx].y;
      int bI = d / Wi, bU = s / Wu;
      int pI = atomicAdd(&bi[bI], 1);
      int pU = atomicAdd(&bu[bU], 1);
      ebuf_i[pI] = ((unsigned)(d - bI * Wi) << 24) | (unsigned)s;
      ebuf_u[pU] = ((unsigned)(s - bU * Wu) << 24) | (unsigned)d;
    }
  }
}

__global__ __launch_bounds__(256) void bucket_fill2_k(
    const unsigned int* __restrict__ ebuf, const int* __restrict__ off,
    const int* __restrict__ endc, int* __restrict__ row,
    int* __restrict__ csr, int n, int W, int E) {
  int b = blockIdx.x;
  int d0 = b * W; if (d0 >= n) return;
  int cnt = n - d0; if (cnt > W) cnt = W;
  __shared__ int hist[320];
  __shared__ int cur[320];
  int tid = threadIdx.x;
  for (int t = tid; t < cnt; t += 256) hist[t] = 0;
  __syncthreads();
  int beg = off[b], e_end = endc[b];
  for (int e = beg + tid; e < e_end; e += 256)
    atomicAdd(&hist[ebuf[e] >> 24], 1);
  __syncthreads();
  if (tid < 64) {
    int lane = tid;
    int carry = beg;
    int nc = (cnt + 63) >> 6;
    for (int c = 0; c < nc; ++c) {
      int idx = (c << 6) + lane;
      int v = (idx < cnt) ? hist[idx] : 0;
      int x = v;
#pragma unroll
      for (int o = 1; o < 64; o <<= 1) { int t = __shfl_up(x, o); if (lane >= o) x += t; }
      if (idx < cnt) { int g = carry + x - v; row[d0 + idx] = g; cur[idx] = g; }
      carry += __shfl(x, 63);
    }
  }
  if (tid == 0 && d0 + cnt == n) row[n] = E;
  __syncthreads();
  for (int e = beg + tid; e < e_end; e += 256) {
    unsigned v = ebuf[e];
    int slot = atomicAdd(&cur[v >> 24], 1);
    csr[slot] = (int)(v & 0xFFFFFFu);
  }
}

// ---------------- dtype prep ----------------
__global__ void cvt_bf16_k(const float* __restrict__ in, bf16_t* __restrict__ out, int n4) {
  int i = blockIdx.x * blockDim.x + threadIdx.x;
  if (i < n4) {
    float4 v = ((const float4*)in)[i];
    ushort4 o; o.x = f2bf(v.x); o.y = f2bf(v.y); o.z = f2bf(v.z); o.w = f2bf(v.w);
    ((ushort4*)out)[i] = o;
  }
}

struct WBatch { const float* in[4]; bf16_t* out[4]; };
__global__ void twconv_batch_k(WBatch wb, int K, int N) {
  const float* __restrict__ in = wb.in[blockIdx.z];
  bf16_t* __restrict__ out = wb.out[blockIdx.z];
  __shared__ float t[32][33];
  int bx = blockIdx.x * 32, by = blockIdx.y * 32;
  int tx = threadIdx.x & 31, ty = threadIdx.x >> 5;  // 32x8
#pragma unroll
  for (int j = 0; j < 32; j += 8)
    t[ty + j][tx] = in[(size_t)(by + ty + j) * N + bx + tx];
  __syncthreads();
#pragma unroll
  for (int j = 0; j < 32; j += 8)
    out[(size_t)(bx + ty + j) * K + by + tx] = f2bf(t[tx][ty + j]);
}

// ---------------- gather-mean, D=128, 16 lanes/row, paired jobs ------------
// 32-bit byte offsets -> SGPR-base + voffset loads; up to 16 rows in flight.
struct GatherJob {
  const int* row; const int* csr;
  const bf16_t* X; bf16_t* agg; int n;
};

template<bool ADD>
__global__ void gather_mean16_k(GatherJob j0, GatherJob j1) {
  GatherJob j = blockIdx.y ? j1 : j0;
  int node = (int)((blockIdx.x * 256u + threadIdx.x) >> 6);
  int lane = threadIdx.x & 63;
  if (node >= j.n) return;
  const int g = lane >> 4;
  const unsigned lb = (unsigned)(lane & 15) << 4;   // lane byte offset in row
  int beg = j.row[node], end = j.row[node + 1];
  float acc[8] = {};
  const char* __restrict__ Xb = (const char*)j.X;
  for (int jj = beg; jj < end; jj += 64) {
    int cnt = min(64, end - jj);
    int my = (lane < cnt) ? j.csr[jj + lane] : 0;
    int k = 0;
    for (; k + 16 <= cnt; k += 16) {
      unsigned o0 = ((unsigned)__shfl(my, k + g) << 8) + lb;
      unsigned o1 = ((unsigned)__shfl(my, k + 4 + g) << 8) + lb;
      unsigned o2 = ((unsigned)__shfl(my, k + 8 + g) << 8) + lb;
      unsigned o3 = ((unsigned)__shfl(my, k + 12 + g) << 8) + lb;
      uint4 u0 = *(const uint4*)(Xb + o0);
      uint4 u1 = *(const uint4*)(Xb + o1);
      uint4 u2 = *(const uint4*)(Xb + o2);
      uint4 u3 = *(const uint4*)(Xb + o3);
      acc8(acc, u0);
      acc8(acc, u1);
      acc8(acc, u2);
      acc8(acc, u3);
    }
    for (; k + 8 <= cnt; k += 8) {
      unsigned o0 = ((unsigned)__shfl(my, k + g) << 8) + lb;
      unsigned o1 = ((unsigned)__shfl(my, k + 4 + g) << 8) + lb;
      uint4 u0 = *(const uint4*)(Xb + o0);
      uint4 u1 = *(const uint4*)(Xb + o1);
      acc8(acc, u0);
      acc8(acc, u1);
    }
    for (; k < cnt; k += 4) {
      int idx = __shfl(my, k + g);
      if (k + g < cnt) {
        unsigned o = ((unsigned)idx << 8) + lb;
        uint4 u = *(const uint4*)(Xb + o);
        acc8(acc, u);
      }
    }
  }
#pragma unroll
  for (int m = 16; m < 64; m <<= 1)
#pragma unroll
    for (int i = 0; i < 8; ++i) acc[i] += __shfl_xor(acc[i], m);
  if (g == 0) {
    float inv = (end > beg) ? 1.0f / (float)(end - beg) : 0.0f;
    float v[8];
    char* __restrict__ Ab = (char*)j.agg;
    unsigned oo = ((unsigned)node << 8) + lb;
    if (ADD) {
      uint4 z = *(const uint4*)(Ab + oo);
      float zb[8]; unpack8(zb, z);
#pragma unroll
      for (int i = 0; i < 8; ++i) v[i] = acc[i] * inv + zb[i];
    } else {
#pragma unroll
      for (int i = 0; i < 8; ++i) v[i] = acc[i] * inv;
    }
    *(uint4*)(Ab + oo) = pack8(v);
  }
}

// ---------------- FUSED pipelined two-layer GEMM (wave-specialized) ---------
// M=32 tiles, 64KB LDS -> 2 blocks/CU; cross-block overlap hides barriers.
struct FJob {
  int M;
  const bf16_t* Aagg; const bf16_t* Axb;
  const bf16_t* W1; const bf16_t* W2;    // [256][128] row-major (^T)
  const float* b1;
  const bf16_t* Wc;                      // [256][256] row-major (^T), z|t concat
  const float* b2;
  bf16_t* Cz; bf16_t* Ct;
};

__global__ __launch_bounds__(512, 2) void fused_pipe_k(FJob j0, FJob j1, int nbI, int nbU) {
  const int bx = blockIdx.x;
  const bool isU = bx >= nbI;
  FJob j = isU ? j1 : j0;
  const int lb = isU ? bx - nbI : bx;
  const int NBLK = isU ? nbU : nbI;
  const int M = j.M;
  const int tiles = (M + 31) >> 5;
  const int T = (tiles > lb) ? (tiles - lb + NBLK - 1) / NBLK : 0;

  __shared__ __align__(16) bf16_t Ab[2][32 * 256];  // 2 x (agg 32x128 | xb 32x128)
  __shared__ __align__(16) bf16_t Hb[2][32 * 256];  // 2 x H 32x256

  const int tid = threadIdx.x;
  const int wave = tid >> 6, lane = tid & 63;
  const int wc = wave & 3;
  const int l15 = lane & 15, l4 = lane >> 4;

  auto STAGE = [&](int tt, int b) {
    size_t row0 = (size_t)(lb + tt * NBLK) * 32;
    int i = tid;                         // 16B slot 0..511
    int r = i >> 4, c = i & 15;
    size_t ar = row0 + r; if (ar >= (size_t)M) ar = M - 1;
    int cs = c ^ (r & 7);
    __builtin_amdgcn_global_load_lds(
        (const __attribute__((address_space(1))) void*)(j.Aagg + ar * 128 + cs * 8),
        (__attribute__((address_space(3))) void*)(&Ab[b][0] + i * 8), 16, 0, 0);
    __builtin_amdgcn_global_load_lds(
        (const __attribute__((address_space(1))) void*)(j.Axb + ar * 128 + cs * 8),
        (__attribute__((address_space(3))) void*)(&Ab[b][32 * 128] + i * 8), 16, 0, 0);
  };

  if (T > 0) STAGE(0, 0);
  __syncthreads();

  if (wave < 4) {
    // ================= A-group: H producer =================
    bf16x8 wA1[4][4], wA2[4][4];
#pragma unroll
    for (int kk = 0; kk < 4; ++kk)
#pragma unroll
      for (int ni = 0; ni < 4; ++ni) {
        int c1 = wc * 64 + ni * 16 + l15;
        wA1[kk][ni] = *(const bf16x8*)(j.W1 + (size_t)c1 * 128 + kk * 32 + l4 * 8);
        wA2[kk][ni] = *(const bf16x8*)(j.W2 + (size_t)c1 * 128 + kk * 32 + l4 * 8);
      }
    float4 bias1[4];
#pragma unroll
    for (int ni = 0; ni < 4; ++ni)
      bias1[ni] = *(const float4*)(j.b1 + wc * 64 + ni * 16 + l4 * 4);

    for (int t = 0; t <= T; ++t) {
      if (t + 1 < T) STAGE(t + 1, (t + 1) & 1);
      if (t < T) {
        const bf16_t* Aag = &Ab[t & 1][0];
        const bf16_t* Axb = &Ab[t & 1][32 * 128];
        char* Ub = (char*)&Hb[t & 1][0];
        f32x4 acc[2][4] = {};
#pragma unroll
        for (int kk = 0; kk < 4; ++kk) {
          bf16x8 aa[2], ax[2];
#pragma unroll
          for (int mi = 0; mi < 2; ++mi) {
            int ra = mi * 16 + l15;
            int ch = (kk * 4 + l4) ^ (ra & 7);
            aa[mi] = *(const bf16x8*)(Aag + ra * 128 + ch * 8);
            ax[mi] = *(const bf16x8*)(Axb + ra * 128 + ch * 8);
          }
#pragma unroll
          for (int mi = 0; mi < 2; ++mi)
#pragma unroll
            for (int ni = 0; ni < 4; ++ni)
              acc[mi][ni] = __builtin_amdgcn_mfma_f32_16x16x32_bf16(wA1[kk][ni], aa[mi], acc[mi][ni], 0, 0, 0);
#pragma unroll
          for (int mi = 0; mi < 2; ++mi)
#pragma unroll
            for (int ni = 0; ni < 4; ++ni)
              acc[mi][ni] = __builtin_amdgcn_mfma_f32_16x16x32_bf16(wA2[kk][ni], ax[mi], acc[mi][ni], 0, 0, 0);
        }
#pragma unroll
        for (int ni = 0; ni < 4; ++ni) {
          int c0 = wc * 64 + ni * 16 + l4 * 4;
          const float* bp = (const float*)&bias1[ni];
#pragma unroll
          for (int mi = 0; mi < 2; ++mi) {
            int r = mi * 16 + l15;
            float v0 = fmaxf(acc[mi][ni][0] + bp[0], 0.f);
            float v1 = fmaxf(acc[mi][ni][1] + bp[1], 0.f);
            float v2 = fmaxf(acc[mi][ni][2] + bp[2], 0.f);
            float v3 = fmaxf(acc[mi][ni][3] + bp[3], 0.f);
            unsigned w0 = (unsigned)f2bf(v0) | ((unsigned)f2bf(v1) << 16);
            unsigned w1 = (unsigned)f2bf(v2) | ((unsigned)f2bf(v3) << 16);
            int p8 = (c0 >> 2) ^ ((r & 7) << 1);
            *(uint2*)(Ub + r * 512 + p8 * 8) = make_uint2(w0, w1);
          }
        }
      }
      __syncthreads();
    }
  } else {
    // ================= B-group: z|t consumer =================
    bf16x8 wB[8][4];
#pragma unroll
    for (int kk = 0; kk < 8; ++kk)
#pragma unroll
      for (int ni = 0; ni < 4; ++ni) {
        int c2 = wc * 64 + ni * 16 + l15;
        wB[kk][ni] = *(const bf16x8*)(j.Wc + (size_t)c2 * 256 + kk * 32 + l4 * 8);
      }
    const bool isZ = (wc < 2);               // cols 0..127 -> z (+bias)
    float4 bias2[4];
#pragma unroll
    for (int ni = 0; ni < 4; ++ni) {
      int c0 = wc * 64 + ni * 16 + l4 * 4;
      bias2[ni] = isZ ? *(const float4*)(j.b2 + c0) : make_float4(0.f, 0.f, 0.f, 0.f);
    }
    bf16_t* Co = isZ ? j.Cz : j.Ct;
    const int ccbase = isZ ? wc * 64 : wc * 64 - 128;

    for (int t = 0; t <= T; ++t) {
      if (t + 1 < T) STAGE(t + 1, (t + 1) & 1);
      if (t >= 1) {
        const bf16_t* Hls = &Hb[(t - 1) & 1][0];
        size_t row0 = (size_t)(lb + (t - 1) * NBLK) * 32;
        f32x4 acc[2][4] = {};
#pragma unroll
        for (int kk = 0; kk < 8; ++kk) {
          bf16x8 ah[2];
#pragma unroll
          for (int mi = 0; mi < 2; ++mi) {
            int r2 = mi * 16 + l15;
            int ch = (kk * 4 + l4) ^ (r2 & 7);
            ah[mi] = *(const bf16x8*)(Hls + r2 * 256 + ch * 8);
          }
#pragma unroll
          for (int mi = 0; mi < 2; ++mi)
#pragma unroll
            for (int ni = 0; ni < 4; ++ni)
              acc[mi][ni] = __builtin_amdgcn_mfma_f32_16x16x32_bf16(wB[kk][ni], ah[mi], acc[mi][ni], 0, 0, 0);
        }
#pragma unroll
        for (int ni = 0; ni < 4; ++ni) {
          int cc = ccbase + ni * 16 + l4 * 4;
          const float* bp = (const float*)&bias2[ni];
#pragma unroll
          for (int mi = 0; mi < 2; ++mi) {
            size_t gr = row0 + mi * 16 + l15;
            if (gr < (size_t)M) {
              unsigned w0 = (unsigned)f2bf(acc[mi][ni][0] + bp[0]) | ((unsigned)f2bf(acc[mi][ni][1] + bp[1]) << 16);
              unsigned w1 = (unsigned)f2bf(acc[mi][ni][2] + bp[2]) | ((unsigned)f2bf(acc[mi][ni][3] + bp[3]) << 16);
              *(uint2*)(Co + gr * 128 + cc) = make_uint2(w0, w1);
            }
          }
        }
      }
      __syncthreads();
    }
  }
}

// ---------------- decode: 16 lanes/label, 16B loads, 32-bit offsets ---------
__global__ void decode16_k(const int* __restrict__ ls, const int* __restrict__ ld,
                           const bf16_t* __restrict__ zu, const bf16_t* __restrict__ zi,
                           float* __restrict__ out, int L) {
  long long gid = (long long)blockIdx.x * blockDim.x + threadIdx.x;
  int w = (int)(gid >> 4);
  int l = (int)(gid & 15);
  if (w >= L) return;
  unsigned lb = (unsigned)l << 4;
  unsigned oa = ((unsigned)ls[w] << 8) + lb;
  unsigned ob = ((unsigned)ld[w] << 8) + lb;
  uint4 a = *(const uint4*)((const char*)zu + oa);
  uint4 b = *(const uint4*)((const char*)zi + ob);
  const unsigned* pa = (const unsigned*)&a;
  const unsigned* pb = (const unsigned*)&b;
  float sum = 0.f;
#pragma unroll
  for (int i = 0; i < 4; ++i) {
    union { unsigned v; float f; } la, ha, lb2, hb;
    la.v = pa[i] << 16;        ha.v = pa[i] & 0xffff0000u;
    lb2.v = pb[i] << 16;       hb.v = pb[i] & 0xffff0000u;
    sum += la.f * lb2.f + ha.f * hb.f;
  }
#pragma unroll
  for (int m = 1; m < 16; m <<= 1) sum += __shfl_xor(sum, m);
  if (l == 0) out[w] = sum;
}

// ---------------------------------------------------------------------------
extern "C" void kernel_launch(void* const* d_in, const int* in_sizes, int n_in,
                              void* d_out, int out_size, void* d_ws, size_t ws_size,
                              hipStream_t stream) {
  const float* x_user = (const float*)d_in[0];
  const float* x_item = (const float*)d_in[1];
  const int* edge_src = (const int*)d_in[2];
  const int* edge_dst = (const int*)d_in[3];
  const int* lbl_src  = (const int*)d_in[4];
  const int* lbl_dst  = (const int*)d_in[5];
  const float* wl1_ui = (const float*)d_in[6];
  const float* wr1_ui = (const float*)d_in[7];
  const float* b1_ui  = (const float*)d_in[8];
  const float* wl1_iu = (const float*)d_in[9];
  const float* wr1_iu = (const float*)d_in[10];
  const float* b1_iu  = (const float*)d_in[11];
  const float* wl2_ui = (const float*)d_in[12];
  const float* wr2_ui = (const float*)d_in[13];
  const float* b2_ui  = (const float*)d_in[14];
  const float* wl2_iu = (const float*)d_in[15];
  const float* wr2_iu = (const float*)d_in[16];
  const float* b2_iu  = (const float*)d_in[17];

  const int NU = in_sizes[0] / DD;
  const int NI = in_sizes[1] / DD;
  const int E  = in_sizes[2];
  const int L  = in_sizes[4];
  const int Wi = (NI + NBI - 1) / NBI;
  const int Wu = (NU + NBU - 1) / NBU;
  const int nEB = (E + 4095) / 4096;

  // ---- workspace layout ----
  size_t off = 0;
  auto take = [&](size_t bytes) { size_t o = off; off = (off + bytes + 255) & ~(size_t)255; return o; };
  char* base = (char*)d_ws;
  int* hist_i = (int*)(base + take(((size_t)NBI + NBU) * 4));  // zeroed together
  int* hist_u = hist_i + NBI;
  size_t zeroB = ((size_t)NBI + NBU) * 4;
  int* row_i = (int*)(base + take((size_t)(NI + 1) * 4));
  int* row_u = (int*)(base + take((size_t)(NU + 1) * 4));
  int* off_i = (int*)(base + take((size_t)NBI * 4));
  int* off_u = (int*)(base + take((size_t)NBU * 4));
  int* cur_bi = (int*)(base + take((size_t)NBI * 4));
  int* cur_bu = (int*)(base + take((size_t)NBU * 4));
  int* csr_i = (int*)(base + take((size_t)E * 4));
  int* csr_u = (int*)(base + take((size_t)E * 4));
  unsigned int* ebuf_i = (unsigned int*)(base + take((size_t)E * 4));
  unsigned int* ebuf_u = (unsigned int*)(base + take((size_t)E * 4));
  // pool holds agg + xb (all persistent through the fused GEMM)
  bf16_t* pool = (bf16_t*)(base + take((size_t)(NI + NU) * HH * 2));
  bf16_t* agg_i   = pool;                              // NI*DD
  bf16_t* agg_u   = agg_i + (size_t)NI * DD;           // NU*DD
  bf16_t* xb_item = agg_u + (size_t)NU * DD;           // NI*DD
  bf16_t* xb_user = xb_item + (size_t)NI * DD;         // NU*DD
  // t is written by the fused kernel while agg/xb are still live -> separate
  bf16_t* t_user = (bf16_t*)(base + take((size_t)(NI + NU) * OO * 2));
  bf16_t* t_item = t_user + (size_t)NU * OO;
  bf16_t* z_item = (bf16_t*)(base + take((size_t)(NI + NU) * OO * 2));
  bf16_t* z_user = z_item + (size_t)NI * OO;
  bf16_t* Wt1[4];
  for (int w = 0; w < 4; ++w) Wt1[w] = (bf16_t*)(base + take((size_t)HH * DD * 2));
  bf16_t* Wcat_item = (bf16_t*)(base + take((size_t)2 * OO * HH * 2));
  bf16_t* Wcat_user = (bf16_t*)(base + take((size_t)2 * OO * HH * 2));
  size_t need = off;

  float* out = (float*)d_out;
  if (ws_size < need || Wi > 320 || Wu > 320) {
    probe_k<<<(L + 255) / 256, 256, 0, stream>>>(out, L, (float)(ws_size >> 20));
    return;
  }

  // ---- CSR build ----
  hipMemsetAsync(hist_i, 0, zeroB, stream);
  hist_k<<<nEB, 256, 0, stream>>>(edge_src, edge_dst, hist_u, hist_i, E, Wi, Wu);
  scan_small_pair_k<<<2, 512, 0, stream>>>(hist_i, off_i, cur_bi, hist_u, off_u, cur_bu);
  bucket_append_k<<<nEB, 256, 0, stream>>>(edge_src, edge_dst, E, Wi, Wu, cur_bi, cur_bu, ebuf_i, ebuf_u);
  bucket_fill2_k<<<NBI, 256, 0, stream>>>(ebuf_i, off_i, cur_bi, row_i, csr_i, NI, Wi, E);
  bucket_fill2_k<<<NBU, 256, 0, stream>>>(ebuf_u, off_u, cur_bu, row_u, csr_u, NU, Wu, E);

  // ---- dtype prep ----
  cvt_bf16_k<<<(NI * DD / 4 + 255) / 256, 256, 0, stream>>>(x_item, xb_item, NI * DD / 4);
  cvt_bf16_k<<<(NU * DD / 4 + 255) / 256, 256, 0, stream>>>(x_user, xb_user, NU * DD / 4);
  {
    WBatch w1;
    w1.in[0] = wl1_ui; w1.out[0] = Wt1[0];
    w1.in[1] = wr1_ui; w1.out[1] = Wt1[1];
    w1.in[2] = wl1_iu; w1.out[2] = Wt1[2];
    w1.in[3] = wr1_iu; w1.out[3] = Wt1[3];
    dim3 g1(HH / 32, DD / 32, 4);  // [D,H] -> [H,D]
    twconv_batch_k<<<g1, 256, 0, stream>>>(w1, DD, HH);
    WBatch w2;
    w2.in[0] = wr2_ui; w2.out[0] = Wcat_item;                    // z_item part
    w2.in[1] = wl2_iu; w2.out[1] = Wcat_item + (size_t)OO * HH;  // t_item part
    w2.in[2] = wr2_iu; w2.out[2] = Wcat_user;                    // z_user part
    w2.in[3] = wl2_ui; w2.out[3] = Wcat_user + (size_t)OO * HH;  // t_user part
    dim3 g2(OO / 32, HH / 32, 4);  // [H,O] -> [O,H]
    twconv_batch_k<<<g2, 256, 0, stream>>>(w2, HH, OO);
  }

  const int nbMax = ((NU > NI ? NU : NI) * 64 + 255) / 256;
  const int tiles_i = (NI + 31) / 32, tiles_u = (NU + 31) / 32;

  // ---- layer 1 gather-mean (paired) ----
  {
    GatherJob gi = { row_i, csr_i, xb_user, agg_i, NI };
    GatherJob gu = { row_u, csr_u, xb_item, agg_u, NU };
    gather_mean16_k<false><<<dim3(nbMax, 2), 256, 0, stream>>>(gi, gu);
  }

  // ---- FUSED pipelined GEMM (wave-specialized, M=32 tiles, 2 blocks/CU) ----
  {
    int nbI = (int)((512LL * tiles_i) / (tiles_i + tiles_u));
    if (nbI < 1) nbI = 1;
    if (nbI > tiles_i) nbI = tiles_i;
    int nbU2 = 512 - nbI;
    if (nbU2 > tiles_u) nbU2 = tiles_u;
    FJob ji = { NI, agg_i, xb_item, Wt1[0], Wt1[1], b1_ui, Wcat_item, b2_ui, z_item, t_item };
    FJob ju = { NU, agg_u, xb_user, Wt1[2], Wt1[3], b1_iu, Wcat_user, b2_iu, z_user, t_user };
    fused_pipe_k<<<nbI + nbU2, 512, 0, stream>>>(ji, ju, nbI, nbU2);
  }

  // ---- layer 2 gather-add: z += mean(t[nbrs]) ----
  {
    GatherJob gi = { row_i, csr_i, t_user, z_item, NI };
    GatherJob gu = { row_u, csr_u, t_item, z_user, NU };
    gather_mean16_k<true><<<dim3(nbMax, 2), 256, 0, stream>>>(gi, gu);
  }

  // ---- decode ----
  decode16_k<<<(int)(((long long)L * 16 + 255) / 256), 256, 0, stream>>>(lbl_src, lbl_dst, z_user, z_item, out, L);
}